// Round 4
// baseline (1810.814 us; speedup 1.0000x reference)
//
#include <hip/hip_runtime.h>
#include <hip/hip_bf16.h>

// HeteroNet on MI355X — round 16.
// R12-R15: three phase-1 rewrites all pinned at 355-375us; VGPR stayed 44
// (compiler re-sank staged loads). Counters: no pipe >31% busy, Occupancy
// 43% (~14 waves/CU of 20 nominal) -> latency-bound with insufficient TLP.
// R16: k_readout4 256thr/(M32,N32) -> 512thr/(M32,N16): 8 waves/block,
// 4 blocks/CU (LDS 128KB), 32 waves/CU = occupancy cap. Same per-block work;
// per-wave work halved. launch_bounds(512,8) caps VGPR at 64 (fits: 44-ish).
// conv2/hproj/prep unchanged.

#define NLn 50000
#define NPn 150000
#define En  500000
#define NBL 1563   // ceil(NLn/32)
#define NBP 4688   // ceil(NPn/32)

typedef __attribute__((ext_vector_type(8))) short short8;
typedef __attribute__((ext_vector_type(4))) float float4v;

__device__ __forceinline__ float bf2f(unsigned short u){ return __uint_as_float(((unsigned)u) << 16); }
__device__ __forceinline__ float bflo(unsigned u){ return __uint_as_float(u << 16); }
__device__ __forceinline__ float bfhi(unsigned u){ return __uint_as_float(u & 0xffff0000u); }
__device__ __forceinline__ unsigned short f2bf(float f){
  __hip_bfloat16 h = __float2bfloat16(f);
  return *reinterpret_cast<unsigned short*>(&h);
}
// order-preserving float->uint; enc(v)>0 for all finite v, so 0 == "empty segment"
__device__ __forceinline__ unsigned encf(float f){
  unsigned u = __float_as_uint(f);
  return (u & 0x80000000u) ? ~u : (u | 0x80000000u);
}
__device__ __forceinline__ float tanh_fast(float x){
  return 1.f - 2.f/(__expf(2.f*x) + 1.f);
}

// ---- k_prep: zeros + embed + weight transforms + LUT, one launch ----
__global__ __launch_bounds__(256) void k_prep(
    unsigned* __restrict__ cntz, unsigned* __restrict__ mmaxz, unsigned* __restrict__ outz,
    const float* __restrict__ Xl, const float* __restrict__ Xp,
    const float* __restrict__ Wnode,
    unsigned short* __restrict__ xl0, unsigned short* __restrict__ xp0,
    const float* __restrict__ Wel, const float* __restrict__ W1, float* __restrict__ vvec,
    const float* __restrict__ W2, unsigned short* __restrict__ w2t,
    const float* __restrict__ Wm, unsigned short* __restrict__ wmt,
    const float* __restrict__ Ws, const float* __restrict__ Wn,
    unsigned short* __restrict__ wcat, unsigned short* __restrict__ w1t,
    const float* __restrict__ Wb, const float* __restrict__ bb,
    unsigned short* __restrict__ lut){
  int b = blockIdx.x, tid = threadIdx.x;
  if (b < 196){
    for (long i = (long)b*256 + tid; i < 200000; i += 196*256) cntz[i] = 0u;
  } else if (b < 324){
    mmaxz[(b-196)*256 + tid] = 0u;
  } else if (b < 580){
    outz[(b-324)*256 + tid] = 0u;
  } else if (b < 100580){
    int lb = b - 580;
    bool isL = lb < 25000;
    const float* X = isL ? Xl : Xp;
    unsigned short* out = isL ? xl0 : xp0;
    int gid = (isL ? lb : lb - 25000)*256 + tid;
    int n = gid >> 7, c = gid & 127;
    const float* xr = X + (size_t)n*44;
    float acc = 0.f;
    #pragma unroll
    for (int k=0;k<44;k++) acc += xr[k]*Wnode[k*128+c];
    out[(size_t)n*128 + c] = f2bf(acc);
  } else if (b < 100582){
    int j = (b-100580)*256 + tid;
    float s = 0.f;
    #pragma unroll
    for (int r=0;r<8;r++) s += Wel[r]*W1[(256+r)*512 + j];
    vvec[j] = s;
  } else if (b < 100838){
    int gid = (b-100582)*256 + tid;                    // 65536
    int n = gid >> 9, k = gid & 511;
    w2t[n*512 + k] = f2bf(W2[k*128 + n]);
  } else if (b < 100902){
    int gid = (b-100838)*256 + tid;                    // 16384
    int n = gid >> 7, k = gid & 127;
    wmt[n*128 + k] = f2bf(Wm[k*128 + n]);
  } else if (b < 101670){
    int gid = (b-100902)*256 + tid;                    // 196608
    int i = gid >> 15, rem = gid & 32767;
    int n = rem >> 8, k = rem & 255;
    float v = (k < 128) ? Ws[i*16384 + k*128 + n] : Wn[i*16384 + (k-128)*128 + n];
    wcat[gid] = f2bf(v);
  } else if (b < 102182){
    int gid = (b-101670)*256 + tid;                    // 131072
    int part = gid >> 16, rem = gid & 65535;
    int n = rem >> 7, k = rem & 127;
    w1t[gid] = f2bf(W1[(part*128 + k)*512 + n]);
  } else {
    int gid = (b-102182)*256 + tid;                    // 3145728
    int c = gid & 127, bin = (gid >> 7) & 4095, i = gid >> 19;
    float d = ((float)bin + 0.5f) * 0.001220703125f;   // *5/4096
    float s = bb[i*128 + c];
    #pragma unroll
    for (int j=0;j<8;j++){
      float a = (d - 0.7142857143f*(float)j) * 1.6f;
      s += __expf(-a*a) * Wb[i*1024 + j*128 + c];
    }
    lut[gid] = f2bf(s / (1.f + __expf(-s)));
  }
}

// ---- CSR construction ----
__global__ __launch_bounds__(256) void k_count(const int* __restrict__ esrc,
    const int* __restrict__ edst, unsigned* __restrict__ cntL, unsigned* __restrict__ cntP){
  int e = blockIdx.x*256 + threadIdx.x;
  if (e >= En) return;
  atomicAdd(&cntL[esrc[e]], 1u);
  atomicAdd(&cntP[edst[e]], 1u);
}
__global__ __launch_bounds__(256) void k_cs2(const unsigned* __restrict__ cntL,
    unsigned* __restrict__ rowptrL, unsigned* __restrict__ bsumL,
    const unsigned* __restrict__ cntP, unsigned* __restrict__ rowptrP,
    unsigned* __restrict__ bsumP){
  bool isL = blockIdx.x < 49;
  const unsigned* cnt = isL ? cntL : cntP;
  unsigned* rowptr = isL ? rowptrL : rowptrP;
  unsigned* bsum = isL ? bsumL : bsumP;
  int n = isL ? NLn : NPn;
  int lb = isL ? blockIdx.x : blockIdx.x - 49;
  __shared__ unsigned ts[256];
  int tid = threadIdx.x;
  int base = lb*1024 + tid*4;
  unsigned v[4], run = 0;
  #pragma unroll
  for (int j=0;j<4;j++){ v[j] = run; run += (base+j < n) ? cnt[base+j] : 0u; }
  ts[tid] = run; __syncthreads();
  for (int off=1; off<256; off<<=1){
    unsigned t = (tid>=off) ? ts[tid-off] : 0u; __syncthreads();
    ts[tid] += t; __syncthreads();
  }
  unsigned excl = ts[tid] - run;
  #pragma unroll
  for (int j=0;j<4;j++) if (base+j < n) rowptr[base+j] = excl + v[j];
  if (tid == 255) bsum[lb] = ts[255];
}
__global__ void k_sb2(unsigned* __restrict__ bsumL, unsigned* __restrict__ bsumP){
  unsigned* bsum = blockIdx.x ? bsumP : bsumL;
  int nc = blockIdx.x ? 147 : 49;
  __shared__ unsigned ts[256];
  int tid = threadIdx.x;
  unsigned x = (tid < nc) ? bsum[tid] : 0u;
  ts[tid] = x; __syncthreads();
  for (int off=1; off<256; off<<=1){
    unsigned t = (tid>=off) ? ts[tid-off] : 0u; __syncthreads();
    ts[tid] += t; __syncthreads();
  }
  if (tid < nc) bsum[tid] = ts[tid] - x;
}
__global__ __launch_bounds__(256) void k_ao2(
    unsigned* __restrict__ rowptrL, unsigned* __restrict__ cursorL,
    const unsigned* __restrict__ bsumL,
    unsigned* __restrict__ rowptrP, unsigned* __restrict__ cursorP,
    const unsigned* __restrict__ bsumP){
  bool isL = blockIdx.x < 196;
  unsigned* rowptr = isL ? rowptrL : rowptrP;
  unsigned* cursor = isL ? cursorL : cursorP;
  const unsigned* bsum = isL ? bsumL : bsumP;
  int n = isL ? NLn : NPn;
  int i = (isL ? blockIdx.x : blockIdx.x - 196)*256 + threadIdx.x;
  if (i < n){
    unsigned r = rowptr[i] + bsum[i>>10];
    rowptr[i] = r; cursor[i] = r;
  }
  if (i == 0) rowptr[n] = En;
}
__global__ __launch_bounds__(256) void k_place(const int* __restrict__ esrc,
    const int* __restrict__ edst, const float* __restrict__ ea,
    const int* __restrict__ lbatch, unsigned* __restrict__ curL,
    unsigned* __restrict__ curP, uint4* __restrict__ edgeL,
    int* __restrict__ idxL, int* __restrict__ idxP){
  int e = blockIdx.x*256 + threadIdx.x;
  if (e >= En) return;
  int s = esrc[e], d = edst[e];
  float dd = ea[e];
  int bin = (int)(dd * 819.2f);
  bin = (bin < 0) ? 0 : ((bin > 4095) ? 4095 : bin);
  unsigned pl = atomicAdd(&curL[s], 1u);
  uint4 er; er.x = (unsigned)s; er.y = (unsigned)d;
  er.z = __float_as_uint(dd); er.w = (unsigned)lbatch[s];
  edgeL[pl] = er;
  idxL[pl] = d | (bin << 18);
  unsigned pp = atomicAdd(&curP[d], 1u);
  idxP[pp] = s | (bin << 18);
}

// ---- fused dual-direction conv with silu-LUT (R10 unroll-4 inner loop) ----
#define EDGE_CAP 1024
__global__ __launch_bounds__(256) void k_conv2(
    const unsigned short* __restrict__ xp_in, const unsigned short* __restrict__ xl_in,
    unsigned short* __restrict__ xp_out, unsigned short* __restrict__ xl_out,
    unsigned short* __restrict__ xp_sum, unsigned short* __restrict__ xl_sum,
    const unsigned* __restrict__ rowptrP, const int* __restrict__ idxP,
    const unsigned* __restrict__ rowptrL, const int* __restrict__ idxL,
    const unsigned short* __restrict__ lut_lp,
    const unsigned short* __restrict__ wcat_lp, const float* __restrict__ bias_lp,
    const unsigned short* __restrict__ lut_pl,
    const unsigned short* __restrict__ wcat_pl, const float* __restrict__ bias_pl,
    int first){
  __shared__ unsigned short ab[32][264];   // [m][k]: k<128 x_dst, k>=128 agg (bf16)
  __shared__ unsigned short ob[32][136];   // epilogue bf16
  __shared__ int snb[EDGE_CAP];
  __shared__ unsigned rps[33];
  int tid = threadIdx.x, c = tid & 127, hh = tid >> 7;
  bool isP = blockIdx.x < NBP;
  const unsigned short* xdst_in = isP ? xp_in : xl_in;
  const unsigned short* xsrc_in = isP ? xl_in : xp_in;
  unsigned short* xout = isP ? xp_out : xl_out;
  unsigned short* xsum = isP ? xp_sum : xl_sum;
  const unsigned* rowptr = isP ? rowptrP : rowptrL;
  const int* eidx = isP ? idxP : idxL;
  const unsigned short* lut_i = isP ? lut_lp : lut_pl;
  const unsigned short* wcat = isP ? wcat_lp : wcat_pl;
  const float* bias = isP ? bias_lp : bias_pl;
  int ndst = isP ? NPn : NLn;
  int n0 = (isP ? blockIdx.x : (blockIdx.x - NBP)) * 32;

  if (tid < 33){
    int idx = n0 + tid; if (idx > ndst) idx = ndst;
    rps[tid] = rowptr[idx];
  }
  __syncthreads();
  int r00 = (int)rps[0], rEnd = (int)rps[32];
  int eblk = rEnd - r00;
  bool fits = (eblk <= EDGE_CAP);
  if (fits){
    for (int p = tid; p < eblk; p += 256) snb[p] = eidx[r00 + p];
  }
  __syncthreads();

  const unsigned short* lutc = lut_i + c;
  const unsigned short* xc = xsrc_in + c;
  for (int m = hh*16; m < hh*16+16; m++){
    int n = n0 + m;
    float a0=0.f, a1=0.f, a2=0.f, a3=0.f;
    int dg = 1;
    if (n < ndst){
      ab[m][c] = xdst_in[(size_t)n*128 + c];
      int r0 = (int)rps[m], r1 = (int)rps[m+1];
      dg = r1 - r0;
      int p = r0;
      for (; p + 3 < r1; p += 4){
        int v0,v1,v2,v3;
        if (fits){
          v0 = snb[p-r00]; v1 = snb[p-r00+1]; v2 = snb[p-r00+2]; v3 = snb[p-r00+3];
        } else {
          v0 = eidx[p]; v1 = eidx[p+1]; v2 = eidx[p+2]; v3 = eidx[p+3];
        }
        a0 += bf2f(lutc[(size_t)((unsigned)v0 >> 18)*128]) * bf2f(xc[(size_t)(v0 & 0x3FFFF)*128]);
        a1 += bf2f(lutc[(size_t)((unsigned)v1 >> 18)*128]) * bf2f(xc[(size_t)(v1 & 0x3FFFF)*128]);
        a2 += bf2f(lutc[(size_t)((unsigned)v2 >> 18)*128]) * bf2f(xc[(size_t)(v2 & 0x3FFFF)*128]);
        a3 += bf2f(lutc[(size_t)((unsigned)v3 >> 18)*128]) * bf2f(xc[(size_t)(v3 & 0x3FFFF)*128]);
      }
      for (; p < r1; p++){
        int v0 = fits ? snb[p-r00] : eidx[p];
        a0 += bf2f(lutc[(size_t)((unsigned)v0 >> 18)*128]) * bf2f(xc[(size_t)(v0 & 0x3FFFF)*128]);
      }
    } else {
      ab[m][c] = 0;
    }
    float inv = 1.f / (float)(dg > 1 ? dg : 1);
    ab[m][128 + c] = f2bf(((a0+a1)+(a2+a3)) * inv);
  }
  __syncthreads();

  int wave = tid >> 6, lane = tid & 63, quad = lane >> 4, l15 = lane & 15;
  int mt = wave & 1, nh = wave >> 1;
  int arow = mt*16 + l15;
  float4v acc[4] = {{0,0,0,0},{0,0,0,0},{0,0,0,0},{0,0,0,0}};
  for (int k0 = 0; k0 < 256; k0 += 32){
    short8 A = *(const short8*)&ab[arow][k0 + quad*8];
    #pragma unroll
    for (int nt=0;nt<4;nt++){
      short8 B = *(const short8*)&wcat[(size_t)(nh*64 + nt*16 + l15)*256 + k0 + quad*8];
      acc[nt] = __builtin_amdgcn_mfma_f32_16x16x32_bf16(A, B, acc[nt], 0, 0, 0);
    }
  }
  #pragma unroll
  for (int nt=0;nt<4;nt++){
    int col = nh*64 + nt*16 + l15;
    float bc = bias[col];
    #pragma unroll
    for (int r=0;r<4;r++){
      int row = mt*16 + quad*4 + r;
      float v = acc[nt][r] + bc;
      ob[row][col] = f2bf((v > 0.f) ? v : 0.01f*v);    // leaky_relu
    }
  }
  __syncthreads();
  for (int m = hh*16; m < hh*16+16; m++){
    int n = n0 + m;
    if (n < ndst){
      unsigned short vb = ob[m][c];
      size_t off = (size_t)n*128 + c;
      xout[off] = vb;
      xsum[off] = first ? vb : f2bf(bf2f(xsum[off]) + bf2f(vb));
    }
  }
}

// ---- merged MFMA hproj: blocks [0,NBL): ligand (+b1); [NBL,NBL+NBP): protein
__global__ __launch_bounds__(256) void k_hproj2(
    const unsigned short* __restrict__ xl_s, const unsigned short* __restrict__ xp_s,
    const unsigned short* __restrict__ w1t, const float* __restrict__ b1,
    unsigned* __restrict__ h_l, unsigned* __restrict__ h_p){
  __shared__ unsigned short hb[32][528];
  bool isL = blockIdx.x < NBL;
  const unsigned short* xs = isL ? xl_s : xp_s;
  const unsigned short* wt = isL ? w1t : w1t + 65536;
  unsigned* hout = isL ? h_l : h_p;
  int nn = isL ? NLn : NPn;
  int n0 = (isL ? blockIdx.x : blockIdx.x - NBL)*32;
  int tid = threadIdx.x;
  int wave = tid >> 6, lane = tid & 63, quad = lane >> 4, l15 = lane & 15;
  int mt = wave & 1, nh = wave >> 1;
  int an = n0 + mt*16 + l15; if (an >= nn) an = nn - 1;
  const unsigned short* aptr = xs + (size_t)an*128;
  float4v acc[16];
  #pragma unroll
  for (int i=0;i<16;i++) acc[i] = (float4v){0,0,0,0};
  for (int k0 = 0; k0 < 128; k0 += 32){
    short8 A = *(const short8*)&aptr[k0 + quad*8];
    #pragma unroll
    for (int nt=0;nt<16;nt++){
      short8 B = *(const short8*)&wt[(size_t)(nh*256 + nt*16 + l15)*128 + k0 + quad*8];
      acc[nt] = __builtin_amdgcn_mfma_f32_16x16x32_bf16(A, B, acc[nt], 0, 0, 0);
    }
  }
  #pragma unroll
  for (int nt=0;nt<16;nt++){
    int col = nh*256 + nt*16 + l15;
    float bv = isL ? b1[col] : 0.f;
    #pragma unroll
    for (int r=0;r<4;r++) hb[mt*16 + quad*4 + r][col] = f2bf(acc[nt][r] + bv);
  }
  __syncthreads();
  for (int m=0;m<32;m++){
    int n = n0 + m;
    if (n < nn){
      unsigned pack = (unsigned)hb[m][2*tid] | ((unsigned)hb[m][2*tid+1] << 16);
      hout[(size_t)n*256 + tid] = pack;
    }
  }
}

// ---- readout v8: 32 edges/block, 512 threads (8 waves), 32768B LDS ->
//      4 blocks/CU x 8 waves = 32 waves/CU (occupancy cap). Wave tiles
//      (M32,N16); phase 1 = 4 edges/wave; per-block work identical to v7.
//      chunked+xor-swizzled hbuf; m in registers; shuffle flush; XCD swizzle.
__global__ __launch_bounds__(512, 8) void k_readout4(
    const unsigned* __restrict__ hl, const unsigned* __restrict__ hp,
    const uint4* __restrict__ edgeL, const float* __restrict__ vvec,
    const unsigned short* __restrict__ w2t, const float* __restrict__ b2,
    const unsigned short* __restrict__ wmt, const float* __restrict__ bm,
    float* __restrict__ outw, unsigned* __restrict__ mmax){
  // 32768 B: phase 1 = chunked hbuf (chunk<64, edge<32 xor-swizzled, 8 shorts);
  //          phase 2 = msb[32][136] (aliases)
  __shared__ __align__(16) unsigned short lds[16384];
  unsigned short (*msb)[136] = (unsigned short(*)[136])lds;
  int tid = threadIdx.x, lane = tid & 63, wave = tid >> 6;
  // bijective XCD swizzle: nwg=15625, q=1953, r=1 -> contiguous chunk per XCD
  int xcd = blockIdx.x & 7, loc = blockIdx.x >> 3;
  int wg = (xcd == 0) ? loc : (1954 + (xcd - 1) * 1953 + loc);
  int e0 = wg*32;
  // one metadata load per wave: this wave's 4 edges = 16 dwords over lanes 0-15
  unsigned md = ((const unsigned*)(edgeL + e0))[wave*16 + (lane & 15)];
  // per-lane batch id for the epilogue (edge = lane&31; lanes 32-63 dup)
  int b_r = (int)((const unsigned*)edgeL)[((size_t)(e0 + (lane & 31)))*4 + 3];
  // vvec for chunk `lane`: h columns [8*lane, 8*lane+8)
  float4v vva = *(const float4v*)&vvec[lane*8];
  float4v vvb = *(const float4v*)&vvec[lane*8 + 4];
  int sw = lane & 31;
  const uint4* hl4 = (const uint4*)hl;   // one h row = 64 uint4
  const uint4* hp4 = (const uint4*)hp;
  #pragma unroll
  for (int ii=0; ii<4; ii++){
    int si = __shfl((int)md, ii*4);
    int di = __shfl((int)md, ii*4 + 1);
    float dd = __uint_as_float((unsigned)__shfl((int)md, ii*4 + 2));
    // lane l reads dwords 4l..4l+3 of the row == h columns [8l, 8l+8)
    uint4 ua = hl4[(size_t)si*64 + lane];
    uint4 ub = hp4[(size_t)di*64 + lane];
    int i = wave*4 + ii;
    unsigned o0, o1, o2, o3;
    float hx, hy;
    hx = fmaxf(bflo(ua.x) + bflo(ub.x) + dd*vva.x, 0.f);
    hy = fmaxf(bfhi(ua.x) + bfhi(ub.x) + dd*vva.y, 0.f);
    o0 = (unsigned)f2bf(hx) | ((unsigned)f2bf(hy) << 16);
    hx = fmaxf(bflo(ua.y) + bflo(ub.y) + dd*vva.z, 0.f);
    hy = fmaxf(bfhi(ua.y) + bfhi(ub.y) + dd*vva.w, 0.f);
    o1 = (unsigned)f2bf(hx) | ((unsigned)f2bf(hy) << 16);
    hx = fmaxf(bflo(ua.z) + bflo(ub.z) + dd*vvb.x, 0.f);
    hy = fmaxf(bfhi(ua.z) + bfhi(ub.z) + dd*vvb.y, 0.f);
    o2 = (unsigned)f2bf(hx) | ((unsigned)f2bf(hy) << 16);
    hx = fmaxf(bflo(ua.w) + bflo(ub.w) + dd*vvb.z, 0.f);
    hy = fmaxf(bfhi(ua.w) + bfhi(ub.w) + dd*vvb.w, 0.f);
    o3 = (unsigned)f2bf(hx) | ((unsigned)f2bf(hy) << 16);
    uint4 ov; ov.x = o0; ov.y = o1; ov.z = o2; ov.w = o3;
    *(uint4*)&lds[lane*256 + ((i ^ sw) << 3)] = ov;   // ds_write_b128
  }
  __syncthreads();
  int quad = lane >> 4, l15 = lane & 15;
  int ns = wave*16;                // each wave: M=32 (all edges), N-strip of 16

  // GEMM1: m[32,128] = h[32,512] @ W2^T + b2
  float4v acc[2] = {{0,0,0,0},{0,0,0,0}};
  for (int k0 = 0; k0 < 512; k0 += 32){
    int kcc = (k0 >> 3) + quad;
    int sw2 = kcc & 31;
    short8 A0 = *(const short8*)&lds[kcc*256 + ((l15 ^ sw2) << 3)];
    short8 A1 = *(const short8*)&lds[kcc*256 + (((16 + l15) ^ sw2) << 3)];
    short8 B0 = *(const short8*)&w2t[(size_t)(ns + l15)*512 + k0 + quad*8];
    acc[0] = __builtin_amdgcn_mfma_f32_16x16x32_bf16(A0, B0, acc[0], 0, 0, 0);
    acc[1] = __builtin_amdgcn_mfma_f32_16x16x32_bf16(A1, B0, acc[1], 0, 0, 0);
  }
  __syncthreads();   // all waves done reading hbuf; msb may overwrite
  float mreg[2][4];
  float b2c0 = b2[ns + l15];
  #pragma unroll
  for (int mt=0;mt<2;mt++){
    int col = ns + l15;
    #pragma unroll
    for (int r=0;r<4;r++){
      float mv = acc[mt][r] + b2c0;
      mreg[mt][r] = mv;
      msb[mt*16 + quad*4 + r][col] = f2bf(mv);
    }
  }
  __syncthreads();

  // GEMM2: t = tanh(m@Wm^T + bm); flush sum(t*m), max(m) per batch
  float4v acc2[2] = {{0,0,0,0},{0,0,0,0}};
  for (int k0 = 0; k0 < 128; k0 += 32){
    short8 A0 = *(const short8*)&msb[l15][k0 + quad*8];
    short8 A1 = *(const short8*)&msb[16 + l15][k0 + quad*8];
    short8 B0 = *(const short8*)&wmt[(size_t)(ns + l15)*128 + k0 + quad*8];
    acc2[0] = __builtin_amdgcn_mfma_f32_16x16x32_bf16(A0, B0, acc2[0], 0, 0, 0);
    acc2[1] = __builtin_amdgcn_mfma_f32_16x16x32_bf16(A1, B0, acc2[1], 0, 0, 0);
  }
  float bm0 = bm[ns + l15];
  int b0 = __shfl(b_r, 0);
  bool uni = (b0 == __shfl(b_r, 31));
  {
    int col = ns + l15;
    if (uni){
      float s = 0.f, mx = -3.402823466e38f;
      #pragma unroll
      for (int mt=0;mt<2;mt++){
        #pragma unroll
        for (int r=0;r<4;r++){
          float mv = mreg[mt][r];
          float t = tanh_fast(acc2[mt][r] + bm0);
          s += t*mv; mx = fmaxf(mx, mv);
        }
      }
      s += __shfl_xor(s, 16); s += __shfl_xor(s, 32);
      mx = fmaxf(mx, __shfl_xor(mx, 16)); mx = fmaxf(mx, __shfl_xor(mx, 32));
      if (quad == 0){
        atomicAdd(&outw[b0*256 + col], s);
        atomicMax(&mmax[b0*128 + col], encf(mx));
      }
    } else {
      #pragma unroll
      for (int mt=0;mt<2;mt++){
        #pragma unroll
        for (int r=0;r<4;r++){
          int row = mt*16 + quad*4 + r;
          int b = __shfl(b_r, row);
          float mv = mreg[mt][r];
          float t = tanh_fast(acc2[mt][r] + bm0);
          atomicAdd(&outw[b*256 + col], t*mv);
          atomicMax(&mmax[b*128 + col], encf(mv));
        }
      }
    }
  }
}

__global__ __launch_bounds__(256) void k_final(const unsigned* __restrict__ mmax,
    float* __restrict__ out){
  int gid = blockIdx.x*256 + threadIdx.x;   // 32768 = 256*128
  unsigned enc = mmax[gid];
  float v;
  if (enc == 0u) v = 0.f;
  else if (enc & 0x80000000u) v = __uint_as_float(enc & 0x7FFFFFFFu);
  else v = __uint_as_float(~enc);
  int g = gid >> 7, cc = gid & 127;
  out[g*256 + 128 + cc] = v;
}

extern "C" void kernel_launch(void* const* d_in, const int* in_sizes, int n_in,
                              void* d_out, int out_size, void* d_ws, size_t ws_size,
                              hipStream_t stream) {
  const float* x_l    = (const float*)d_in[0];
  const float* x_p    = (const float*)d_in[1];
  const float* ea     = (const float*)d_in[2];
  const int*   esrc   = (const int*)d_in[3];
  const int*   edst   = (const int*)d_in[4];
  const int*   lbatch = (const int*)d_in[5];
  const float* W_node = (const float*)d_in[6];
  const float* W_el   = (const float*)d_in[7];
  const float* Wb     = (const float*)d_in[8];
  const float* bb     = (const float*)d_in[9];
  const float* Wn     = (const float*)d_in[10];
  const float* Ws     = (const float*)d_in[11];
  const float* bconv  = (const float*)d_in[12];
  const float* W1     = (const float*)d_in[13];
  const float* b1     = (const float*)d_in[14];
  const float* W2     = (const float*)d_in[15];
  const float* b2     = (const float*)d_in[16];
  const float* Wm     = (const float*)d_in[17];
  const float* bm     = (const float*)d_in[18];

  // ---- workspace layout (decimal offsets), peak 267,354,496 B ----
  char* w = (char*)d_ws;
  unsigned short* xl0 = (unsigned short*)(w + 0);
  unsigned short* xl1 = (unsigned short*)(w + 12800000);
  unsigned short* xp0 = (unsigned short*)(w + 25600000);
  unsigned short* xp1 = (unsigned short*)(w + 64000000);
  int*      idxP  = (int*)(w + 102400000);
  int*      idxL  = (int*)(w + 104400000);
  unsigned short* lut = (unsigned short*)(w + 106400000);   // 6.29e6 B
  unsigned* h_l   = (unsigned*)(w + 0);
  unsigned* h_p   = (unsigned*)(w + 51200000);
  unsigned short* xl_s = (unsigned short*)(w + 204800000);
  unsigned short* xp_s = (unsigned short*)(w + 217600000);
  unsigned short* wcat = (unsigned short*)(w + 256000000);
  unsigned short* w1t  = (unsigned short*)(w + 256393216);
  unsigned short* w2t  = (unsigned short*)(w + 256655360);
  unsigned short* wmt  = (unsigned short*)(w + 256786432);
  float*    vvec  = (float*)(w + 256819200);
  unsigned* mmax  = (unsigned*)(w + 256821248);
  unsigned* bsumL = (unsigned*)(w + 256952320);
  unsigned* bsumP = (unsigned*)(w + 256953344);
  unsigned* rowptrL = (unsigned*)(w + 256954368);
  unsigned* cursorL = (unsigned*)(w + 257154432);
  unsigned* rowptrP = (unsigned*)(w + 257354432);
  unsigned* cursorP = (unsigned*)(w + 257954496);
  unsigned* cntL    = (unsigned*)(w + 258554496);
  unsigned* cntP    = (unsigned*)(w + 258754496);
  uint4*    edgeL   = (uint4*)(w + 259354496);   // {src, dst, bits(d), batch}

  float* out = (float*)d_out;

  k_prep<<<114470, 256, 0, stream>>>(
      (unsigned*)(w + 258554496), mmax, (unsigned*)d_out,
      x_l, x_p, W_node, xl0, xp0,
      W_el, W1, vvec, W2, w2t, Wm, wmt, Ws, Wn, wcat, w1t, Wb, bb, lut);

  k_count<<<1954, 256, 0, stream>>>(esrc, edst, cntL, cntP);
  k_cs2<<<196, 256, 0, stream>>>(cntL, rowptrL, bsumL, cntP, rowptrP, bsumP);
  k_sb2<<<2, 256, 0, stream>>>(bsumL, bsumP);
  k_ao2<<<782, 256, 0, stream>>>(rowptrL, cursorL, bsumL, rowptrP, cursorP, bsumP);
  k_place<<<1954, 256, 0, stream>>>(esrc, edst, ea, lbatch, cursorL, cursorP,
                                    edgeL, idxL, idxP);

  unsigned short *xlc = xl0, *xln = xl1, *xpc = xp0, *xpn = xp1;
  for (int l = 0; l < 3; ++l){
    int ilp = 2*l, ipl = 2*l + 1;
    k_conv2<<<NBP + NBL, 256, 0, stream>>>(
        xpc, xlc, xpn, xln, xp_s, xl_s,
        rowptrP, idxP, rowptrL, idxL,
        lut + (size_t)ilp*524288, wcat + ilp*32768, bconv + ilp*128,
        lut + (size_t)ipl*524288, wcat + ipl*32768, bconv + ipl*128,
        (l == 0) ? 1 : 0);
    unsigned short* t;
    t = xlc; xlc = xln; xln = t;
    t = xpc; xpc = xpn; xpn = t;
  }

  // b1 folded into h_l (ligand part); protein part no bias
  k_hproj2<<<NBL + NBP, 256, 0, stream>>>(xl_s, xp_s, w1t, b1, h_l, h_p);

  k_readout4<<<En/32, 512, 0, stream>>>(h_l, h_p, edgeL, vvec,
                                        w2t, b2, wmt, bm, out, mmax);
  k_final<<<128, 256, 0, stream>>>(mmax, out);
}

// Round 5
// 1772.253 us; speedup vs baseline: 1.0218x; 1.0218x over previous
//
#include <hip/hip_runtime.h>
#include <hip/hip_bf16.h>

// HeteroNet on MI355X — round 17.
// R16 falsified latency-TLP theory: occupancy 43->82% with dur 367->385us.
// Byte audit: every 32-edge block streams the ENTIRE w2t+wmt (160KB) from L2
// -> 2.5GB/dispatch, + 1GB h-gathers = ~9.5 TB/s on the L1-miss path. That
// invariant matches the pinned 355-390us across R12-R16.
// R17: persistent multi-tile blocks, B register-resident:
//  - 1024 blocks x 512thr; block owns ~16 contiguous tiles (XCD-chunked);
//  - per wave: w2t N16-strip (64 VGPR) + wmt strip (16 VGPR) loaded ONCE;
//    w2t traffic 2.5GB -> 164MB;
//  - hl dedupe via scalar (readfirstlane) skip of repeated sorted src rows.
// Occupancy drops to ~1 block/CU — R16 proved occupancy isn't binding.

#define NLn 50000
#define NPn 150000
#define En  500000
#define NBL 1563   // ceil(NLn/32)
#define NBP 4688   // ceil(NPn/32)

typedef __attribute__((ext_vector_type(8))) short short8;
typedef __attribute__((ext_vector_type(4))) float float4v;

__device__ __forceinline__ float bf2f(unsigned short u){ return __uint_as_float(((unsigned)u) << 16); }
__device__ __forceinline__ float bflo(unsigned u){ return __uint_as_float(u << 16); }
__device__ __forceinline__ float bfhi(unsigned u){ return __uint_as_float(u & 0xffff0000u); }
__device__ __forceinline__ unsigned short f2bf(float f){
  __hip_bfloat16 h = __float2bfloat16(f);
  return *reinterpret_cast<unsigned short*>(&h);
}
// order-preserving float->uint; enc(v)>0 for all finite v, so 0 == "empty segment"
__device__ __forceinline__ unsigned encf(float f){
  unsigned u = __float_as_uint(f);
  return (u & 0x80000000u) ? ~u : (u | 0x80000000u);
}
__device__ __forceinline__ float tanh_fast(float x){
  return 1.f - 2.f/(__expf(2.f*x) + 1.f);
}

// ---- k_prep: zeros + embed + weight transforms + LUT, one launch ----
__global__ __launch_bounds__(256) void k_prep(
    unsigned* __restrict__ cntz, unsigned* __restrict__ mmaxz, unsigned* __restrict__ outz,
    const float* __restrict__ Xl, const float* __restrict__ Xp,
    const float* __restrict__ Wnode,
    unsigned short* __restrict__ xl0, unsigned short* __restrict__ xp0,
    const float* __restrict__ Wel, const float* __restrict__ W1, float* __restrict__ vvec,
    const float* __restrict__ W2, unsigned short* __restrict__ w2t,
    const float* __restrict__ Wm, unsigned short* __restrict__ wmt,
    const float* __restrict__ Ws, const float* __restrict__ Wn,
    unsigned short* __restrict__ wcat, unsigned short* __restrict__ w1t,
    const float* __restrict__ Wb, const float* __restrict__ bb,
    unsigned short* __restrict__ lut){
  int b = blockIdx.x, tid = threadIdx.x;
  if (b < 196){
    for (long i = (long)b*256 + tid; i < 200000; i += 196*256) cntz[i] = 0u;
  } else if (b < 324){
    mmaxz[(b-196)*256 + tid] = 0u;
  } else if (b < 580){
    outz[(b-324)*256 + tid] = 0u;
  } else if (b < 100580){
    int lb = b - 580;
    bool isL = lb < 25000;
    const float* X = isL ? Xl : Xp;
    unsigned short* out = isL ? xl0 : xp0;
    int gid = (isL ? lb : lb - 25000)*256 + tid;
    int n = gid >> 7, c = gid & 127;
    const float* xr = X + (size_t)n*44;
    float acc = 0.f;
    #pragma unroll
    for (int k=0;k<44;k++) acc += xr[k]*Wnode[k*128+c];
    out[(size_t)n*128 + c] = f2bf(acc);
  } else if (b < 100582){
    int j = (b-100580)*256 + tid;
    float s = 0.f;
    #pragma unroll
    for (int r=0;r<8;r++) s += Wel[r]*W1[(256+r)*512 + j];
    vvec[j] = s;
  } else if (b < 100838){
    int gid = (b-100582)*256 + tid;                    // 65536
    int n = gid >> 9, k = gid & 511;
    w2t[n*512 + k] = f2bf(W2[k*128 + n]);
  } else if (b < 100902){
    int gid = (b-100838)*256 + tid;                    // 16384
    int n = gid >> 7, k = gid & 127;
    wmt[n*128 + k] = f2bf(Wm[k*128 + n]);
  } else if (b < 101670){
    int gid = (b-100902)*256 + tid;                    // 196608
    int i = gid >> 15, rem = gid & 32767;
    int n = rem >> 8, k = rem & 255;
    float v = (k < 128) ? Ws[i*16384 + k*128 + n] : Wn[i*16384 + (k-128)*128 + n];
    wcat[gid] = f2bf(v);
  } else if (b < 102182){
    int gid = (b-101670)*256 + tid;                    // 131072
    int part = gid >> 16, rem = gid & 65535;
    int n = rem >> 7, k = rem & 127;
    w1t[gid] = f2bf(W1[(part*128 + k)*512 + n]);
  } else {
    int gid = (b-102182)*256 + tid;                    // 3145728
    int c = gid & 127, bin = (gid >> 7) & 4095, i = gid >> 19;
    float d = ((float)bin + 0.5f) * 0.001220703125f;   // *5/4096
    float s = bb[i*128 + c];
    #pragma unroll
    for (int j=0;j<8;j++){
      float a = (d - 0.7142857143f*(float)j) * 1.6f;
      s += __expf(-a*a) * Wb[i*1024 + j*128 + c];
    }
    lut[gid] = f2bf(s / (1.f + __expf(-s)));
  }
}

// ---- CSR construction ----
__global__ __launch_bounds__(256) void k_count(const int* __restrict__ esrc,
    const int* __restrict__ edst, unsigned* __restrict__ cntL, unsigned* __restrict__ cntP){
  int e = blockIdx.x*256 + threadIdx.x;
  if (e >= En) return;
  atomicAdd(&cntL[esrc[e]], 1u);
  atomicAdd(&cntP[edst[e]], 1u);
}
__global__ __launch_bounds__(256) void k_cs2(const unsigned* __restrict__ cntL,
    unsigned* __restrict__ rowptrL, unsigned* __restrict__ bsumL,
    const unsigned* __restrict__ cntP, unsigned* __restrict__ rowptrP,
    unsigned* __restrict__ bsumP){
  bool isL = blockIdx.x < 49;
  const unsigned* cnt = isL ? cntL : cntP;
  unsigned* rowptr = isL ? rowptrL : rowptrP;
  unsigned* bsum = isL ? bsumL : bsumP;
  int n = isL ? NLn : NPn;
  int lb = isL ? blockIdx.x : blockIdx.x - 49;
  __shared__ unsigned ts[256];
  int tid = threadIdx.x;
  int base = lb*1024 + tid*4;
  unsigned v[4], run = 0;
  #pragma unroll
  for (int j=0;j<4;j++){ v[j] = run; run += (base+j < n) ? cnt[base+j] : 0u; }
  ts[tid] = run; __syncthreads();
  for (int off=1; off<256; off<<=1){
    unsigned t = (tid>=off) ? ts[tid-off] : 0u; __syncthreads();
    ts[tid] += t; __syncthreads();
  }
  unsigned excl = ts[tid] - run;
  #pragma unroll
  for (int j=0;j<4;j++) if (base+j < n) rowptr[base+j] = excl + v[j];
  if (tid == 255) bsum[lb] = ts[255];
}
__global__ void k_sb2(unsigned* __restrict__ bsumL, unsigned* __restrict__ bsumP){
  unsigned* bsum = blockIdx.x ? bsumP : bsumL;
  int nc = blockIdx.x ? 147 : 49;
  __shared__ unsigned ts[256];
  int tid = threadIdx.x;
  unsigned x = (tid < nc) ? bsum[tid] : 0u;
  ts[tid] = x; __syncthreads();
  for (int off=1; off<256; off<<=1){
    unsigned t = (tid>=off) ? ts[tid-off] : 0u; __syncthreads();
    ts[tid] += t; __syncthreads();
  }
  if (tid < nc) bsum[tid] = ts[tid] - x;
}
__global__ __launch_bounds__(256) void k_ao2(
    unsigned* __restrict__ rowptrL, unsigned* __restrict__ cursorL,
    const unsigned* __restrict__ bsumL,
    unsigned* __restrict__ rowptrP, unsigned* __restrict__ cursorP,
    const unsigned* __restrict__ bsumP){
  bool isL = blockIdx.x < 196;
  unsigned* rowptr = isL ? rowptrL : rowptrP;
  unsigned* cursor = isL ? cursorL : cursorP;
  const unsigned* bsum = isL ? bsumL : bsumP;
  int n = isL ? NLn : NPn;
  int i = (isL ? blockIdx.x : blockIdx.x - 196)*256 + threadIdx.x;
  if (i < n){
    unsigned r = rowptr[i] + bsum[i>>10];
    rowptr[i] = r; cursor[i] = r;
  }
  if (i == 0) rowptr[n] = En;
}
__global__ __launch_bounds__(256) void k_place(const int* __restrict__ esrc,
    const int* __restrict__ edst, const float* __restrict__ ea,
    const int* __restrict__ lbatch, unsigned* __restrict__ curL,
    unsigned* __restrict__ curP, uint4* __restrict__ edgeL,
    int* __restrict__ idxL, int* __restrict__ idxP){
  int e = blockIdx.x*256 + threadIdx.x;
  if (e >= En) return;
  int s = esrc[e], d = edst[e];
  float dd = ea[e];
  int bin = (int)(dd * 819.2f);
  bin = (bin < 0) ? 0 : ((bin > 4095) ? 4095 : bin);
  unsigned pl = atomicAdd(&curL[s], 1u);
  uint4 er; er.x = (unsigned)s; er.y = (unsigned)d;
  er.z = __float_as_uint(dd); er.w = (unsigned)lbatch[s];
  edgeL[pl] = er;
  idxL[pl] = d | (bin << 18);
  unsigned pp = atomicAdd(&curP[d], 1u);
  idxP[pp] = s | (bin << 18);
}

// ---- fused dual-direction conv with silu-LUT (R10 unroll-4 inner loop) ----
#define EDGE_CAP 1024
__global__ __launch_bounds__(256) void k_conv2(
    const unsigned short* __restrict__ xp_in, const unsigned short* __restrict__ xl_in,
    unsigned short* __restrict__ xp_out, unsigned short* __restrict__ xl_out,
    unsigned short* __restrict__ xp_sum, unsigned short* __restrict__ xl_sum,
    const unsigned* __restrict__ rowptrP, const int* __restrict__ idxP,
    const unsigned* __restrict__ rowptrL, const int* __restrict__ idxL,
    const unsigned short* __restrict__ lut_lp,
    const unsigned short* __restrict__ wcat_lp, const float* __restrict__ bias_lp,
    const unsigned short* __restrict__ lut_pl,
    const unsigned short* __restrict__ wcat_pl, const float* __restrict__ bias_pl,
    int first){
  __shared__ unsigned short ab[32][264];   // [m][k]: k<128 x_dst, k>=128 agg (bf16)
  __shared__ unsigned short ob[32][136];   // epilogue bf16
  __shared__ int snb[EDGE_CAP];
  __shared__ unsigned rps[33];
  int tid = threadIdx.x, c = tid & 127, hh = tid >> 7;
  bool isP = blockIdx.x < NBP;
  const unsigned short* xdst_in = isP ? xp_in : xl_in;
  const unsigned short* xsrc_in = isP ? xl_in : xp_in;
  unsigned short* xout = isP ? xp_out : xl_out;
  unsigned short* xsum = isP ? xp_sum : xl_sum;
  const unsigned* rowptr = isP ? rowptrP : rowptrL;
  const int* eidx = isP ? idxP : idxL;
  const unsigned short* lut_i = isP ? lut_lp : lut_pl;
  const unsigned short* wcat = isP ? wcat_lp : wcat_pl;
  const float* bias = isP ? bias_lp : bias_pl;
  int ndst = isP ? NPn : NLn;
  int n0 = (isP ? blockIdx.x : (blockIdx.x - NBP)) * 32;

  if (tid < 33){
    int idx = n0 + tid; if (idx > ndst) idx = ndst;
    rps[tid] = rowptr[idx];
  }
  __syncthreads();
  int r00 = (int)rps[0], rEnd = (int)rps[32];
  int eblk = rEnd - r00;
  bool fits = (eblk <= EDGE_CAP);
  if (fits){
    for (int p = tid; p < eblk; p += 256) snb[p] = eidx[r00 + p];
  }
  __syncthreads();

  const unsigned short* lutc = lut_i + c;
  const unsigned short* xc = xsrc_in + c;
  for (int m = hh*16; m < hh*16+16; m++){
    int n = n0 + m;
    float a0=0.f, a1=0.f, a2=0.f, a3=0.f;
    int dg = 1;
    if (n < ndst){
      ab[m][c] = xdst_in[(size_t)n*128 + c];
      int r0 = (int)rps[m], r1 = (int)rps[m+1];
      dg = r1 - r0;
      int p = r0;
      for (; p + 3 < r1; p += 4){
        int v0,v1,v2,v3;
        if (fits){
          v0 = snb[p-r00]; v1 = snb[p-r00+1]; v2 = snb[p-r00+2]; v3 = snb[p-r00+3];
        } else {
          v0 = eidx[p]; v1 = eidx[p+1]; v2 = eidx[p+2]; v3 = eidx[p+3];
        }
        a0 += bf2f(lutc[(size_t)((unsigned)v0 >> 18)*128]) * bf2f(xc[(size_t)(v0 & 0x3FFFF)*128]);
        a1 += bf2f(lutc[(size_t)((unsigned)v1 >> 18)*128]) * bf2f(xc[(size_t)(v1 & 0x3FFFF)*128]);
        a2 += bf2f(lutc[(size_t)((unsigned)v2 >> 18)*128]) * bf2f(xc[(size_t)(v2 & 0x3FFFF)*128]);
        a3 += bf2f(lutc[(size_t)((unsigned)v3 >> 18)*128]) * bf2f(xc[(size_t)(v3 & 0x3FFFF)*128]);
      }
      for (; p < r1; p++){
        int v0 = fits ? snb[p-r00] : eidx[p];
        a0 += bf2f(lutc[(size_t)((unsigned)v0 >> 18)*128]) * bf2f(xc[(size_t)(v0 & 0x3FFFF)*128]);
      }
    } else {
      ab[m][c] = 0;
    }
    float inv = 1.f / (float)(dg > 1 ? dg : 1);
    ab[m][128 + c] = f2bf(((a0+a1)+(a2+a3)) * inv);
  }
  __syncthreads();

  int wave = tid >> 6, lane = tid & 63, quad = lane >> 4, l15 = lane & 15;
  int mt = wave & 1, nh = wave >> 1;
  int arow = mt*16 + l15;
  float4v acc[4] = {{0,0,0,0},{0,0,0,0},{0,0,0,0},{0,0,0,0}};
  for (int k0 = 0; k0 < 256; k0 += 32){
    short8 A = *(const short8*)&ab[arow][k0 + quad*8];
    #pragma unroll
    for (int nt=0;nt<4;nt++){
      short8 B = *(const short8*)&wcat[(size_t)(nh*64 + nt*16 + l15)*256 + k0 + quad*8];
      acc[nt] = __builtin_amdgcn_mfma_f32_16x16x32_bf16(A, B, acc[nt], 0, 0, 0);
    }
  }
  #pragma unroll
  for (int nt=0;nt<4;nt++){
    int col = nh*64 + nt*16 + l15;
    float bc = bias[col];
    #pragma unroll
    for (int r=0;r<4;r++){
      int row = mt*16 + quad*4 + r;
      float v = acc[nt][r] + bc;
      ob[row][col] = f2bf((v > 0.f) ? v : 0.01f*v);    // leaky_relu
    }
  }
  __syncthreads();
  for (int m = hh*16; m < hh*16+16; m++){
    int n = n0 + m;
    if (n < ndst){
      unsigned short vb = ob[m][c];
      size_t off = (size_t)n*128 + c;
      xout[off] = vb;
      xsum[off] = first ? vb : f2bf(bf2f(xsum[off]) + bf2f(vb));
    }
  }
}

// ---- merged MFMA hproj: blocks [0,NBL): ligand (+b1); [NBL,NBL+NBP): protein
__global__ __launch_bounds__(256) void k_hproj2(
    const unsigned short* __restrict__ xl_s, const unsigned short* __restrict__ xp_s,
    const unsigned short* __restrict__ w1t, const float* __restrict__ b1,
    unsigned* __restrict__ h_l, unsigned* __restrict__ h_p){
  __shared__ unsigned short hb[32][528];
  bool isL = blockIdx.x < NBL;
  const unsigned short* xs = isL ? xl_s : xp_s;
  const unsigned short* wt = isL ? w1t : w1t + 65536;
  unsigned* hout = isL ? h_l : h_p;
  int nn = isL ? NLn : NPn;
  int n0 = (isL ? blockIdx.x : blockIdx.x - NBL)*32;
  int tid = threadIdx.x;
  int wave = tid >> 6, lane = tid & 63, quad = lane >> 4, l15 = lane & 15;
  int mt = wave & 1, nh = wave >> 1;
  int an = n0 + mt*16 + l15; if (an >= nn) an = nn - 1;
  const unsigned short* aptr = xs + (size_t)an*128;
  float4v acc[16];
  #pragma unroll
  for (int i=0;i<16;i++) acc[i] = (float4v){0,0,0,0};
  for (int k0 = 0; k0 < 128; k0 += 32){
    short8 A = *(const short8*)&aptr[k0 + quad*8];
    #pragma unroll
    for (int nt=0;nt<16;nt++){
      short8 B = *(const short8*)&wt[(size_t)(nh*256 + nt*16 + l15)*128 + k0 + quad*8];
      acc[nt] = __builtin_amdgcn_mfma_f32_16x16x32_bf16(A, B, acc[nt], 0, 0, 0);
    }
  }
  #pragma unroll
  for (int nt=0;nt<16;nt++){
    int col = nh*256 + nt*16 + l15;
    float bv = isL ? b1[col] : 0.f;
    #pragma unroll
    for (int r=0;r<4;r++) hb[mt*16 + quad*4 + r][col] = f2bf(acc[nt][r] + bv);
  }
  __syncthreads();
  for (int m=0;m<32;m++){
    int n = n0 + m;
    if (n < nn){
      unsigned pack = (unsigned)hb[m][2*tid] | ((unsigned)hb[m][2*tid+1] << 16);
      hout[(size_t)n*256 + tid] = pack;
    }
  }
}

// ---- readout v9: persistent blocks, register-resident B.
//      1024 blocks x 512 thr; block owns ~16 contiguous 32-edge tiles
//      (XCD-chunked). Per wave: w2t N16-strip (16x short8 = 64 VGPR) + wmt
//      strip (4x short8) loaded once; tile loop: {metadata, phase1 (4 edges/
//      wave, hl scalar-dedupe), GEMM1, msb, GEMM2, atomics}. 4 barriers/tile.
__global__ __launch_bounds__(512) void k_readout4(
    const unsigned* __restrict__ hl, const unsigned* __restrict__ hp,
    const uint4* __restrict__ edgeL, const float* __restrict__ vvec,
    const unsigned short* __restrict__ w2t, const float* __restrict__ b2,
    const unsigned short* __restrict__ wmt, const float* __restrict__ bm,
    float* __restrict__ outw, unsigned* __restrict__ mmax){
  // 32768 B: phase 1 = chunked hbuf (chunk<64, edge<32 xor-swizzled, 8 shorts);
  //          phase 2 = msb[32][136] (aliases)
  __shared__ __align__(16) unsigned short lds[16384];
  unsigned short (*msb)[136] = (unsigned short(*)[136])lds;
  int tid = threadIdx.x, lane = tid & 63, wave = tid >> 6;
  int quad = lane >> 4, l15 = lane & 15;
  int ns = wave*16;                // this wave's N-strip (cols) for both GEMMs

  // XCD-chunked tile mapping: blocks on XCD k (b&7==k) take contiguous tiles
  int wg = (blockIdx.x & 7)*128 + (blockIdx.x >> 3);   // bijective [0,1024)
  int t0 = wg*16;
  int t1 = t0 + 16; if (t1 > En/32) t1 = En/32;

  // ---- register-resident B: w2t strip (64 VGPR) + wmt strip (16 VGPR) ----
  short8 Bk[16];
  #pragma unroll
  for (int kk=0;kk<16;kk++)
    Bk[kk] = *(const short8*)&w2t[(size_t)(ns + l15)*512 + kk*32 + quad*8];
  short8 Bm[4];
  #pragma unroll
  for (int kk=0;kk<4;kk++)
    Bm[kk] = *(const short8*)&wmt[(size_t)(ns + l15)*128 + kk*32 + quad*8];
  float b2c0 = b2[ns + l15];
  float bm0  = bm[ns + l15];

  // vvec for chunk `lane`: h columns [8*lane, 8*lane+8)
  float4v vva = *(const float4v*)&vvec[lane*8];
  float4v vvb = *(const float4v*)&vvec[lane*8 + 4];
  int sw = lane & 31;
  const uint4* hl4 = (const uint4*)hl;   // one h row = 64 uint4
  const uint4* hp4 = (const uint4*)hp;

  int si_prev = -1;
  uint4 ua = {0,0,0,0};

  for (int t = t0; t < t1; ++t){
    int e0 = t*32;
    // one metadata load per wave: this wave's 4 edges = 16 dwords, lanes dup x4
    unsigned md = ((const unsigned*)(edgeL + e0))[wave*16 + (lane & 15)];
    // per-lane batch id for the epilogue (edge = lane&31)
    int b_r = (int)((const unsigned*)edgeL)[((size_t)(e0 + (lane & 31)))*4 + 3];

    __syncthreads();   // prev tile's GEMM2 msb reads done before hbuf overwrite
    #pragma unroll
    for (int ii=0; ii<4; ii++){
      int si = __builtin_amdgcn_readfirstlane(__shfl((int)md, ii*4));
      int di = __builtin_amdgcn_readfirstlane(__shfl((int)md, ii*4 + 1));
      float dd = __uint_as_float((unsigned)__builtin_amdgcn_readfirstlane(__shfl((int)md, ii*4 + 2)));
      if (si != si_prev){            // scalar branch: CSR-sorted src dedupe
        ua = hl4[(size_t)si*64 + lane];
        si_prev = si;
      }
      uint4 ub = hp4[(size_t)di*64 + lane];
      int i = wave*4 + ii;
      unsigned o0, o1, o2, o3;
      float hx, hy;
      hx = fmaxf(bflo(ua.x) + bflo(ub.x) + dd*vva.x, 0.f);
      hy = fmaxf(bfhi(ua.x) + bfhi(ub.x) + dd*vva.y, 0.f);
      o0 = (unsigned)f2bf(hx) | ((unsigned)f2bf(hy) << 16);
      hx = fmaxf(bflo(ua.y) + bflo(ub.y) + dd*vva.z, 0.f);
      hy = fmaxf(bfhi(ua.y) + bfhi(ub.y) + dd*vva.w, 0.f);
      o1 = (unsigned)f2bf(hx) | ((unsigned)f2bf(hy) << 16);
      hx = fmaxf(bflo(ua.z) + bflo(ub.z) + dd*vvb.x, 0.f);
      hy = fmaxf(bfhi(ua.z) + bfhi(ub.z) + dd*vvb.y, 0.f);
      o2 = (unsigned)f2bf(hx) | ((unsigned)f2bf(hy) << 16);
      hx = fmaxf(bflo(ua.w) + bflo(ub.w) + dd*vvb.z, 0.f);
      hy = fmaxf(bfhi(ua.w) + bfhi(ub.w) + dd*vvb.w, 0.f);
      o3 = (unsigned)f2bf(hx) | ((unsigned)f2bf(hy) << 16);
      uint4 ov; ov.x = o0; ov.y = o1; ov.z = o2; ov.w = o3;
      *(uint4*)&lds[lane*256 + ((i ^ sw) << 3)] = ov;   // ds_write_b128
    }
    __syncthreads();

    // GEMM1: m[32,128] = h[32,512] @ W2^T + b2  (B from registers)
    float4v acc[2] = {{0,0,0,0},{0,0,0,0}};
    #pragma unroll
    for (int kk = 0; kk < 16; kk++){
      int kcc = kk*4 + quad;
      int sw2 = kcc & 31;
      short8 A0 = *(const short8*)&lds[kcc*256 + ((l15 ^ sw2) << 3)];
      short8 A1 = *(const short8*)&lds[kcc*256 + (((16 + l15) ^ sw2) << 3)];
      acc[0] = __builtin_amdgcn_mfma_f32_16x16x32_bf16(A0, Bk[kk], acc[0], 0, 0, 0);
      acc[1] = __builtin_amdgcn_mfma_f32_16x16x32_bf16(A1, Bk[kk], acc[1], 0, 0, 0);
    }
    __syncthreads();   // all waves done reading hbuf; msb may overwrite
    float mreg[2][4];
    #pragma unroll
    for (int mt=0;mt<2;mt++){
      int col = ns + l15;
      #pragma unroll
      for (int r=0;r<4;r++){
        float mv = acc[mt][r] + b2c0;
        mreg[mt][r] = mv;
        msb[mt*16 + quad*4 + r][col] = f2bf(mv);
      }
    }
    __syncthreads();

    // GEMM2: t = tanh(m@Wm^T + bm); flush sum(t*m), max(m) per batch
    float4v acc2[2] = {{0,0,0,0},{0,0,0,0}};
    #pragma unroll
    for (int kk = 0; kk < 4; kk++){
      short8 A0 = *(const short8*)&msb[l15][kk*32 + quad*8];
      short8 A1 = *(const short8*)&msb[16 + l15][kk*32 + quad*8];
      acc2[0] = __builtin_amdgcn_mfma_f32_16x16x32_bf16(A0, Bm[kk], acc2[0], 0, 0, 0);
      acc2[1] = __builtin_amdgcn_mfma_f32_16x16x32_bf16(A1, Bm[kk], acc2[1], 0, 0, 0);
    }
    int b0 = __shfl(b_r, 0);
    bool uni = (b0 == __shfl(b_r, 31));
    int col = ns + l15;
    if (uni){
      float s = 0.f, mx = -3.402823466e38f;
      #pragma unroll
      for (int mt=0;mt<2;mt++){
        #pragma unroll
        for (int r=0;r<4;r++){
          float mv = mreg[mt][r];
          float tt = tanh_fast(acc2[mt][r] + bm0);
          s += tt*mv; mx = fmaxf(mx, mv);
        }
      }
      s += __shfl_xor(s, 16); s += __shfl_xor(s, 32);
      mx = fmaxf(mx, __shfl_xor(mx, 16)); mx = fmaxf(mx, __shfl_xor(mx, 32));
      if (quad == 0){
        atomicAdd(&outw[b0*256 + col], s);
        atomicMax(&mmax[b0*128 + col], encf(mx));
      }
    } else {
      #pragma unroll
      for (int mt=0;mt<2;mt++){
        #pragma unroll
        for (int r=0;r<4;r++){
          int row = mt*16 + quad*4 + r;
          int b = __shfl(b_r, row);
          float mv = mreg[mt][r];
          float tt = tanh_fast(acc2[mt][r] + bm0);
          atomicAdd(&outw[b*256 + col], tt*mv);
          atomicMax(&mmax[b*128 + col], encf(mv));
        }
      }
    }
  }
}

__global__ __launch_bounds__(256) void k_final(const unsigned* __restrict__ mmax,
    float* __restrict__ out){
  int gid = blockIdx.x*256 + threadIdx.x;   // 32768 = 256*128
  unsigned enc = mmax[gid];
  float v;
  if (enc == 0u) v = 0.f;
  else if (enc & 0x80000000u) v = __uint_as_float(enc & 0x7FFFFFFFu);
  else v = __uint_as_float(~enc);
  int g = gid >> 7, cc = gid & 127;
  out[g*256 + 128 + cc] = v;
}

extern "C" void kernel_launch(void* const* d_in, const int* in_sizes, int n_in,
                              void* d_out, int out_size, void* d_ws, size_t ws_size,
                              hipStream_t stream) {
  const float* x_l    = (const float*)d_in[0];
  const float* x_p    = (const float*)d_in[1];
  const float* ea     = (const float*)d_in[2];
  const int*   esrc   = (const int*)d_in[3];
  const int*   edst   = (const int*)d_in[4];
  const int*   lbatch = (const int*)d_in[5];
  const float* W_node = (const float*)d_in[6];
  const float* W_el   = (const float*)d_in[7];
  const float* Wb     = (const float*)d_in[8];
  const float* bb     = (const float*)d_in[9];
  const float* Wn     = (const float*)d_in[10];
  const float* Ws     = (const float*)d_in[11];
  const float* bconv  = (const float*)d_in[12];
  const float* W1     = (const float*)d_in[13];
  const float* b1     = (const float*)d_in[14];
  const float* W2     = (const float*)d_in[15];
  const float* b2     = (const float*)d_in[16];
  const float* Wm     = (const float*)d_in[17];
  const float* bm     = (const float*)d_in[18];

  // ---- workspace layout (decimal offsets), peak 267,354,496 B ----
  char* w = (char*)d_ws;
  unsigned short* xl0 = (unsigned short*)(w + 0);
  unsigned short* xl1 = (unsigned short*)(w + 12800000);
  unsigned short* xp0 = (unsigned short*)(w + 25600000);
  unsigned short* xp1 = (unsigned short*)(w + 64000000);
  int*      idxP  = (int*)(w + 102400000);
  int*      idxL  = (int*)(w + 104400000);
  unsigned short* lut = (unsigned short*)(w + 106400000);   // 6.29e6 B
  unsigned* h_l   = (unsigned*)(w + 0);
  unsigned* h_p   = (unsigned*)(w + 51200000);
  unsigned short* xl_s = (unsigned short*)(w + 204800000);
  unsigned short* xp_s = (unsigned short*)(w + 217600000);
  unsigned short* wcat = (unsigned short*)(w + 256000000);
  unsigned short* w1t  = (unsigned short*)(w + 256393216);
  unsigned short* w2t  = (unsigned short*)(w + 256655360);
  unsigned short* wmt  = (unsigned short*)(w + 256786432);
  float*    vvec  = (float*)(w + 256819200);
  unsigned* mmax  = (unsigned*)(w + 256821248);
  unsigned* bsumL = (unsigned*)(w + 256952320);
  unsigned* bsumP = (unsigned*)(w + 256953344);
  unsigned* rowptrL = (unsigned*)(w + 256954368);
  unsigned* cursorL = (unsigned*)(w + 257154432);
  unsigned* rowptrP = (unsigned*)(w + 257354432);
  unsigned* cursorP = (unsigned*)(w + 257954496);
  unsigned* cntL    = (unsigned*)(w + 258554496);
  unsigned* cntP    = (unsigned*)(w + 258754496);
  uint4*    edgeL   = (uint4*)(w + 259354496);   // {src, dst, bits(d), batch}

  float* out = (float*)d_out;

  k_prep<<<114470, 256, 0, stream>>>(
      (unsigned*)(w + 258554496), mmax, (unsigned*)d_out,
      x_l, x_p, W_node, xl0, xp0,
      W_el, W1, vvec, W2, w2t, Wm, wmt, Ws, Wn, wcat, w1t, Wb, bb, lut);

  k_count<<<1954, 256, 0, stream>>>(esrc, edst, cntL, cntP);
  k_cs2<<<196, 256, 0, stream>>>(cntL, rowptrL, bsumL, cntP, rowptrP, bsumP);
  k_sb2<<<2, 256, 0, stream>>>(bsumL, bsumP);
  k_ao2<<<782, 256, 0, stream>>>(rowptrL, cursorL, bsumL, rowptrP, cursorP, bsumP);
  k_place<<<1954, 256, 0, stream>>>(esrc, edst, ea, lbatch, cursorL, cursorP,
                                    edgeL, idxL, idxP);

  unsigned short *xlc = xl0, *xln = xl1, *xpc = xp0, *xpn = xp1;
  for (int l = 0; l < 3; ++l){
    int ilp = 2*l, ipl = 2*l + 1;
    k_conv2<<<NBP + NBL, 256, 0, stream>>>(
        xpc, xlc, xpn, xln, xp_s, xl_s,
        rowptrP, idxP, rowptrL, idxL,
        lut + (size_t)ilp*524288, wcat + ilp*32768, bconv + ilp*128,
        lut + (size_t)ipl*524288, wcat + ipl*32768, bconv + ipl*128,
        (l == 0) ? 1 : 0);
    unsigned short* t;
    t = xlc; xlc = xln; xln = t;
    t = xpc; xpc = xpn; xpn = t;
  }

  // b1 folded into h_l (ligand part); protein part no bias
  k_hproj2<<<NBL + NBP, 256, 0, stream>>>(xl_s, xp_s, w1t, b1, h_l, h_p);

  k_readout4<<<1024, 512, 0, stream>>>(h_l, h_p, edgeL, vvec,
                                       w2t, b2, wmt, bm, out, mmax);
  k_final<<<128, 256, 0, stream>>>(mmax, out);
}

// Round 6
// 1699.935 us; speedup vs baseline: 1.0652x; 1.0425x over previous
//
#include <hip/hip_runtime.h>
#include <hip/hip_bf16.h>

// HeteroNet on MI355X — round 18.
// R17 (persistent + reg-resident B) 385->341us: byte-cut confirmed partial.
// Residual: per-tile serial chain md->gather->barrier->GEMM x4 barriers,
// ~13K cyc/tile wall vs ~2.5K work -> exposed gather latency (T14 regime).
// R18: cross-tile software pipeline: double-buffered hbuf (2x32KB + msb =
// 74.2KB LDS, still 2 blocks/CU), issue md(t+2) + hp gathers(t+1) + deduped
// hl(t+1) BEFORE GEMM1(t); consume after GEMM2(t) into hbuf[cur^1].
// Barriers 4->2 per tile. VGPR budget ~119 <= 128 keeps 2 blocks/CU.

#define NLn 50000
#define NPn 150000
#define En  500000
#define NBL 1563   // ceil(NLn/32)
#define NBP 4688   // ceil(NPn/32)

typedef __attribute__((ext_vector_type(8))) short short8;
typedef __attribute__((ext_vector_type(4))) float float4v;

__device__ __forceinline__ float bf2f(unsigned short u){ return __uint_as_float(((unsigned)u) << 16); }
__device__ __forceinline__ float bflo(unsigned u){ return __uint_as_float(u << 16); }
__device__ __forceinline__ float bfhi(unsigned u){ return __uint_as_float(u & 0xffff0000u); }
__device__ __forceinline__ unsigned short f2bf(float f){
  __hip_bfloat16 h = __float2bfloat16(f);
  return *reinterpret_cast<unsigned short*>(&h);
}
// order-preserving float->uint; enc(v)>0 for all finite v, so 0 == "empty segment"
__device__ __forceinline__ unsigned encf(float f){
  unsigned u = __float_as_uint(f);
  return (u & 0x80000000u) ? ~u : (u | 0x80000000u);
}
__device__ __forceinline__ float tanh_fast(float x){
  return 1.f - 2.f/(__expf(2.f*x) + 1.f);
}

// ---- k_prep: zeros + embed + weight transforms + LUT, one launch ----
__global__ __launch_bounds__(256) void k_prep(
    unsigned* __restrict__ cntz, unsigned* __restrict__ mmaxz, unsigned* __restrict__ outz,
    const float* __restrict__ Xl, const float* __restrict__ Xp,
    const float* __restrict__ Wnode,
    unsigned short* __restrict__ xl0, unsigned short* __restrict__ xp0,
    const float* __restrict__ Wel, const float* __restrict__ W1, float* __restrict__ vvec,
    const float* __restrict__ W2, unsigned short* __restrict__ w2t,
    const float* __restrict__ Wm, unsigned short* __restrict__ wmt,
    const float* __restrict__ Ws, const float* __restrict__ Wn,
    unsigned short* __restrict__ wcat, unsigned short* __restrict__ w1t,
    const float* __restrict__ Wb, const float* __restrict__ bb,
    unsigned short* __restrict__ lut){
  int b = blockIdx.x, tid = threadIdx.x;
  if (b < 196){
    for (long i = (long)b*256 + tid; i < 200000; i += 196*256) cntz[i] = 0u;
  } else if (b < 324){
    mmaxz[(b-196)*256 + tid] = 0u;
  } else if (b < 580){
    outz[(b-324)*256 + tid] = 0u;
  } else if (b < 100580){
    int lb = b - 580;
    bool isL = lb < 25000;
    const float* X = isL ? Xl : Xp;
    unsigned short* out = isL ? xl0 : xp0;
    int gid = (isL ? lb : lb - 25000)*256 + tid;
    int n = gid >> 7, c = gid & 127;
    const float* xr = X + (size_t)n*44;
    float acc = 0.f;
    #pragma unroll
    for (int k=0;k<44;k++) acc += xr[k]*Wnode[k*128+c];
    out[(size_t)n*128 + c] = f2bf(acc);
  } else if (b < 100582){
    int j = (b-100580)*256 + tid;
    float s = 0.f;
    #pragma unroll
    for (int r=0;r<8;r++) s += Wel[r]*W1[(256+r)*512 + j];
    vvec[j] = s;
  } else if (b < 100838){
    int gid = (b-100582)*256 + tid;                    // 65536
    int n = gid >> 9, k = gid & 511;
    w2t[n*512 + k] = f2bf(W2[k*128 + n]);
  } else if (b < 100902){
    int gid = (b-100838)*256 + tid;                    // 16384
    int n = gid >> 7, k = gid & 127;
    wmt[n*128 + k] = f2bf(Wm[k*128 + n]);
  } else if (b < 101670){
    int gid = (b-100902)*256 + tid;                    // 196608
    int i = gid >> 15, rem = gid & 32767;
    int n = rem >> 8, k = rem & 255;
    float v = (k < 128) ? Ws[i*16384 + k*128 + n] : Wn[i*16384 + (k-128)*128 + n];
    wcat[gid] = f2bf(v);
  } else if (b < 102182){
    int gid = (b-101670)*256 + tid;                    // 131072
    int part = gid >> 16, rem = gid & 65535;
    int n = rem >> 7, k = rem & 127;
    w1t[gid] = f2bf(W1[(part*128 + k)*512 + n]);
  } else {
    int gid = (b-102182)*256 + tid;                    // 3145728
    int c = gid & 127, bin = (gid >> 7) & 4095, i = gid >> 19;
    float d = ((float)bin + 0.5f) * 0.001220703125f;   // *5/4096
    float s = bb[i*128 + c];
    #pragma unroll
    for (int j=0;j<8;j++){
      float a = (d - 0.7142857143f*(float)j) * 1.6f;
      s += __expf(-a*a) * Wb[i*1024 + j*128 + c];
    }
    lut[gid] = f2bf(s / (1.f + __expf(-s)));
  }
}

// ---- CSR construction ----
__global__ __launch_bounds__(256) void k_count(const int* __restrict__ esrc,
    const int* __restrict__ edst, unsigned* __restrict__ cntL, unsigned* __restrict__ cntP){
  int e = blockIdx.x*256 + threadIdx.x;
  if (e >= En) return;
  atomicAdd(&cntL[esrc[e]], 1u);
  atomicAdd(&cntP[edst[e]], 1u);
}
__global__ __launch_bounds__(256) void k_cs2(const unsigned* __restrict__ cntL,
    unsigned* __restrict__ rowptrL, unsigned* __restrict__ bsumL,
    const unsigned* __restrict__ cntP, unsigned* __restrict__ rowptrP,
    unsigned* __restrict__ bsumP){
  bool isL = blockIdx.x < 49;
  const unsigned* cnt = isL ? cntL : cntP;
  unsigned* rowptr = isL ? rowptrL : rowptrP;
  unsigned* bsum = isL ? bsumL : bsumP;
  int n = isL ? NLn : NPn;
  int lb = isL ? blockIdx.x : blockIdx.x - 49;
  __shared__ unsigned ts[256];
  int tid = threadIdx.x;
  int base = lb*1024 + tid*4;
  unsigned v[4], run = 0;
  #pragma unroll
  for (int j=0;j<4;j++){ v[j] = run; run += (base+j < n) ? cnt[base+j] : 0u; }
  ts[tid] = run; __syncthreads();
  for (int off=1; off<256; off<<=1){
    unsigned t = (tid>=off) ? ts[tid-off] : 0u; __syncthreads();
    ts[tid] += t; __syncthreads();
  }
  unsigned excl = ts[tid] - run;
  #pragma unroll
  for (int j=0;j<4;j++) if (base+j < n) rowptr[base+j] = excl + v[j];
  if (tid == 255) bsum[lb] = ts[255];
}
__global__ void k_sb2(unsigned* __restrict__ bsumL, unsigned* __restrict__ bsumP){
  unsigned* bsum = blockIdx.x ? bsumP : bsumL;
  int nc = blockIdx.x ? 147 : 49;
  __shared__ unsigned ts[256];
  int tid = threadIdx.x;
  unsigned x = (tid < nc) ? bsum[tid] : 0u;
  ts[tid] = x; __syncthreads();
  for (int off=1; off<256; off<<=1){
    unsigned t = (tid>=off) ? ts[tid-off] : 0u; __syncthreads();
    ts[tid] += t; __syncthreads();
  }
  if (tid < nc) bsum[tid] = ts[tid] - x;
}
__global__ __launch_bounds__(256) void k_ao2(
    unsigned* __restrict__ rowptrL, unsigned* __restrict__ cursorL,
    const unsigned* __restrict__ bsumL,
    unsigned* __restrict__ rowptrP, unsigned* __restrict__ cursorP,
    const unsigned* __restrict__ bsumP){
  bool isL = blockIdx.x < 196;
  unsigned* rowptr = isL ? rowptrL : rowptrP;
  unsigned* cursor = isL ? cursorL : cursorP;
  const unsigned* bsum = isL ? bsumL : bsumP;
  int n = isL ? NLn : NPn;
  int i = (isL ? blockIdx.x : blockIdx.x - 196)*256 + threadIdx.x;
  if (i < n){
    unsigned r = rowptr[i] + bsum[i>>10];
    rowptr[i] = r; cursor[i] = r;
  }
  if (i == 0) rowptr[n] = En;
}
__global__ __launch_bounds__(256) void k_place(const int* __restrict__ esrc,
    const int* __restrict__ edst, const float* __restrict__ ea,
    const int* __restrict__ lbatch, unsigned* __restrict__ curL,
    unsigned* __restrict__ curP, uint4* __restrict__ edgeL,
    int* __restrict__ idxL, int* __restrict__ idxP){
  int e = blockIdx.x*256 + threadIdx.x;
  if (e >= En) return;
  int s = esrc[e], d = edst[e];
  float dd = ea[e];
  int bin = (int)(dd * 819.2f);
  bin = (bin < 0) ? 0 : ((bin > 4095) ? 4095 : bin);
  unsigned pl = atomicAdd(&curL[s], 1u);
  uint4 er; er.x = (unsigned)s; er.y = (unsigned)d;
  er.z = __float_as_uint(dd); er.w = (unsigned)lbatch[s];
  edgeL[pl] = er;
  idxL[pl] = d | (bin << 18);
  unsigned pp = atomicAdd(&curP[d], 1u);
  idxP[pp] = s | (bin << 18);
}

// ---- fused dual-direction conv with silu-LUT (R10 unroll-4 inner loop) ----
#define EDGE_CAP 1024
__global__ __launch_bounds__(256) void k_conv2(
    const unsigned short* __restrict__ xp_in, const unsigned short* __restrict__ xl_in,
    unsigned short* __restrict__ xp_out, unsigned short* __restrict__ xl_out,
    unsigned short* __restrict__ xp_sum, unsigned short* __restrict__ xl_sum,
    const unsigned* __restrict__ rowptrP, const int* __restrict__ idxP,
    const unsigned* __restrict__ rowptrL, const int* __restrict__ idxL,
    const unsigned short* __restrict__ lut_lp,
    const unsigned short* __restrict__ wcat_lp, const float* __restrict__ bias_lp,
    const unsigned short* __restrict__ lut_pl,
    const unsigned short* __restrict__ wcat_pl, const float* __restrict__ bias_pl,
    int first){
  __shared__ unsigned short ab[32][264];   // [m][k]: k<128 x_dst, k>=128 agg (bf16)
  __shared__ unsigned short ob[32][136];   // epilogue bf16
  __shared__ int snb[EDGE_CAP];
  __shared__ unsigned rps[33];
  int tid = threadIdx.x, c = tid & 127, hh = tid >> 7;
  bool isP = blockIdx.x < NBP;
  const unsigned short* xdst_in = isP ? xp_in : xl_in;
  const unsigned short* xsrc_in = isP ? xl_in : xp_in;
  unsigned short* xout = isP ? xp_out : xl_out;
  unsigned short* xsum = isP ? xp_sum : xl_sum;
  const unsigned* rowptr = isP ? rowptrP : rowptrL;
  const int* eidx = isP ? idxP : idxL;
  const unsigned short* lut_i = isP ? lut_lp : lut_pl;
  const unsigned short* wcat = isP ? wcat_lp : wcat_pl;
  const float* bias = isP ? bias_lp : bias_pl;
  int ndst = isP ? NPn : NLn;
  int n0 = (isP ? blockIdx.x : (blockIdx.x - NBP)) * 32;

  if (tid < 33){
    int idx = n0 + tid; if (idx > ndst) idx = ndst;
    rps[tid] = rowptr[idx];
  }
  __syncthreads();
  int r00 = (int)rps[0], rEnd = (int)rps[32];
  int eblk = rEnd - r00;
  bool fits = (eblk <= EDGE_CAP);
  if (fits){
    for (int p = tid; p < eblk; p += 256) snb[p] = eidx[r00 + p];
  }
  __syncthreads();

  const unsigned short* lutc = lut_i + c;
  const unsigned short* xc = xsrc_in + c;
  for (int m = hh*16; m < hh*16+16; m++){
    int n = n0 + m;
    float a0=0.f, a1=0.f, a2=0.f, a3=0.f;
    int dg = 1;
    if (n < ndst){
      ab[m][c] = xdst_in[(size_t)n*128 + c];
      int r0 = (int)rps[m], r1 = (int)rps[m+1];
      dg = r1 - r0;
      int p = r0;
      for (; p + 3 < r1; p += 4){
        int v0,v1,v2,v3;
        if (fits){
          v0 = snb[p-r00]; v1 = snb[p-r00+1]; v2 = snb[p-r00+2]; v3 = snb[p-r00+3];
        } else {
          v0 = eidx[p]; v1 = eidx[p+1]; v2 = eidx[p+2]; v3 = eidx[p+3];
        }
        a0 += bf2f(lutc[(size_t)((unsigned)v0 >> 18)*128]) * bf2f(xc[(size_t)(v0 & 0x3FFFF)*128]);
        a1 += bf2f(lutc[(size_t)((unsigned)v1 >> 18)*128]) * bf2f(xc[(size_t)(v1 & 0x3FFFF)*128]);
        a2 += bf2f(lutc[(size_t)((unsigned)v2 >> 18)*128]) * bf2f(xc[(size_t)(v2 & 0x3FFFF)*128]);
        a3 += bf2f(lutc[(size_t)((unsigned)v3 >> 18)*128]) * bf2f(xc[(size_t)(v3 & 0x3FFFF)*128]);
      }
      for (; p < r1; p++){
        int v0 = fits ? snb[p-r00] : eidx[p];
        a0 += bf2f(lutc[(size_t)((unsigned)v0 >> 18)*128]) * bf2f(xc[(size_t)(v0 & 0x3FFFF)*128]);
      }
    } else {
      ab[m][c] = 0;
    }
    float inv = 1.f / (float)(dg > 1 ? dg : 1);
    ab[m][128 + c] = f2bf(((a0+a1)+(a2+a3)) * inv);
  }
  __syncthreads();

  int wave = tid >> 6, lane = tid & 63, quad = lane >> 4, l15 = lane & 15;
  int mt = wave & 1, nh = wave >> 1;
  int arow = mt*16 + l15;
  float4v acc[4] = {{0,0,0,0},{0,0,0,0},{0,0,0,0},{0,0,0,0}};
  for (int k0 = 0; k0 < 256; k0 += 32){
    short8 A = *(const short8*)&ab[arow][k0 + quad*8];
    #pragma unroll
    for (int nt=0;nt<4;nt++){
      short8 B = *(const short8*)&wcat[(size_t)(nh*64 + nt*16 + l15)*256 + k0 + quad*8];
      acc[nt] = __builtin_amdgcn_mfma_f32_16x16x32_bf16(A, B, acc[nt], 0, 0, 0);
    }
  }
  #pragma unroll
  for (int nt=0;nt<4;nt++){
    int col = nh*64 + nt*16 + l15;
    float bc = bias[col];
    #pragma unroll
    for (int r=0;r<4;r++){
      int row = mt*16 + quad*4 + r;
      float v = acc[nt][r] + bc;
      ob[row][col] = f2bf((v > 0.f) ? v : 0.01f*v);    // leaky_relu
    }
  }
  __syncthreads();
  for (int m = hh*16; m < hh*16+16; m++){
    int n = n0 + m;
    if (n < ndst){
      unsigned short vb = ob[m][c];
      size_t off = (size_t)n*128 + c;
      xout[off] = vb;
      xsum[off] = first ? vb : f2bf(bf2f(xsum[off]) + bf2f(vb));
    }
  }
}

// ---- merged MFMA hproj: blocks [0,NBL): ligand (+b1); [NBL,NBL+NBP): protein
__global__ __launch_bounds__(256) void k_hproj2(
    const unsigned short* __restrict__ xl_s, const unsigned short* __restrict__ xp_s,
    const unsigned short* __restrict__ w1t, const float* __restrict__ b1,
    unsigned* __restrict__ h_l, unsigned* __restrict__ h_p){
  __shared__ unsigned short hb[32][528];
  bool isL = blockIdx.x < NBL;
  const unsigned short* xs = isL ? xl_s : xp_s;
  const unsigned short* wt = isL ? w1t : w1t + 65536;
  unsigned* hout = isL ? h_l : h_p;
  int nn = isL ? NLn : NPn;
  int n0 = (isL ? blockIdx.x : blockIdx.x - NBL)*32;
  int tid = threadIdx.x;
  int wave = tid >> 6, lane = tid & 63, quad = lane >> 4, l15 = lane & 15;
  int mt = wave & 1, nh = wave >> 1;
  int an = n0 + mt*16 + l15; if (an >= nn) an = nn - 1;
  const unsigned short* aptr = xs + (size_t)an*128;
  float4v acc[16];
  #pragma unroll
  for (int i=0;i<16;i++) acc[i] = (float4v){0,0,0,0};
  for (int k0 = 0; k0 < 128; k0 += 32){
    short8 A = *(const short8*)&aptr[k0 + quad*8];
    #pragma unroll
    for (int nt=0;nt<16;nt++){
      short8 B = *(const short8*)&wt[(size_t)(nh*256 + nt*16 + l15)*128 + k0 + quad*8];
      acc[nt] = __builtin_amdgcn_mfma_f32_16x16x32_bf16(A, B, acc[nt], 0, 0, 0);
    }
  }
  #pragma unroll
  for (int nt=0;nt<16;nt++){
    int col = nh*256 + nt*16 + l15;
    float bv = isL ? b1[col] : 0.f;
    #pragma unroll
    for (int r=0;r<4;r++) hb[mt*16 + quad*4 + r][col] = f2bf(acc[nt][r] + bv);
  }
  __syncthreads();
  for (int m=0;m<32;m++){
    int n = n0 + m;
    if (n < nn){
      unsigned pack = (unsigned)hb[m][2*tid] | ((unsigned)hb[m][2*tid+1] << 16);
      hout[(size_t)n*256 + tid] = pack;
    }
  }
}

// ---- readout v10: persistent + reg-resident B + cross-tile pipeline.
//      LDS = double hbuf (2x16384 shorts) + msb (4352 shorts) = 74240 B
//      -> 2 blocks/CU. Per iteration t: issue md(t+2), hp-gathers(t+1),
//      deduped hl(t+1) BEFORE GEMM1(t); consume after GEMM2(t) into
//      hbuf[cur^1]. 2 barriers/tile.
__global__ __launch_bounds__(512) void k_readout4(
    const unsigned* __restrict__ hl, const unsigned* __restrict__ hp,
    const uint4* __restrict__ edgeL, const float* __restrict__ vvec,
    const unsigned short* __restrict__ w2t, const float* __restrict__ b2,
    const unsigned short* __restrict__ wmt, const float* __restrict__ bm,
    float* __restrict__ outw, unsigned* __restrict__ mmax){
  __shared__ __align__(16) unsigned short lds[37120];   // 2x16384 hbuf + msb
  unsigned short (*msb)[136] = (unsigned short(*)[136])(lds + 32768);
  int tid = threadIdx.x, lane = tid & 63, wave = tid >> 6;
  int quad = lane >> 4, l15 = lane & 15;
  int ns = wave*16;                // this wave's N-strip for both GEMMs

  // XCD-chunked tile mapping
  int wg = (blockIdx.x & 7)*128 + (blockIdx.x >> 3);   // bijective [0,1024)
  int nt_tot = En/32;
  int t0 = wg*16;
  int t1 = t0 + 16; if (t1 > nt_tot) t1 = nt_tot;
  if (t0 >= t1) return;

  // ---- register-resident B: w2t strip (64 VGPR) + wmt strip (16 VGPR) ----
  short8 Bk[16];
  #pragma unroll
  for (int kk=0;kk<16;kk++)
    Bk[kk] = *(const short8*)&w2t[(size_t)(ns + l15)*512 + kk*32 + quad*8];
  short8 Bm[4];
  #pragma unroll
  for (int kk=0;kk<4;kk++)
    Bm[kk] = *(const short8*)&wmt[(size_t)(ns + l15)*128 + kk*32 + quad*8];
  float b2c0 = b2[ns + l15];
  float bm0  = bm[ns + l15];

  // vvec for chunk `lane`: h columns [8*lane, 8*lane+8)
  float4v vva = *(const float4v*)&vvec[lane*8];
  float4v vvb = *(const float4v*)&vvec[lane*8 + 4];
  int sw = lane & 31;
  const uint4* hl4 = (const uint4*)hl;   // one h row = 64 uint4
  const uint4* hp4 = (const uint4*)hp;
  const unsigned* e32 = (const unsigned*)edgeL;

  int si_prev = -1;
  uint4 ua = {0,0,0,0};
  int lm = wave*16 + (lane & 15);        // metadata dword index for this wave
  int le = lane & 31;                    // epilogue edge index

  // helper lambda-ish macro for the h-compute of one edge
  #define H_EDGE(UA, UB, DD, I, WB)                                          \
    {                                                                        \
      unsigned o0,o1,o2,o3; float hx,hy;                                     \
      hx = fmaxf(bflo(UA.x)+bflo(UB.x)+(DD)*vva.x, 0.f);                     \
      hy = fmaxf(bfhi(UA.x)+bfhi(UB.x)+(DD)*vva.y, 0.f);                     \
      o0 = (unsigned)f2bf(hx) | ((unsigned)f2bf(hy) << 16);                  \
      hx = fmaxf(bflo(UA.y)+bflo(UB.y)+(DD)*vva.z, 0.f);                     \
      hy = fmaxf(bfhi(UA.y)+bfhi(UB.y)+(DD)*vva.w, 0.f);                     \
      o1 = (unsigned)f2bf(hx) | ((unsigned)f2bf(hy) << 16);                  \
      hx = fmaxf(bflo(UA.z)+bflo(UB.z)+(DD)*vvb.x, 0.f);                     \
      hy = fmaxf(bfhi(UA.z)+bfhi(UB.z)+(DD)*vvb.y, 0.f);                     \
      o2 = (unsigned)f2bf(hx) | ((unsigned)f2bf(hy) << 16);                  \
      hx = fmaxf(bflo(UA.w)+bflo(UB.w)+(DD)*vvb.z, 0.f);                     \
      hy = fmaxf(bfhi(UA.w)+bfhi(UB.w)+(DD)*vvb.w, 0.f);                     \
      o3 = (unsigned)f2bf(hx) | ((unsigned)f2bf(hy) << 16);                  \
      uint4 ov; ov.x=o0; ov.y=o1; ov.z=o2; ov.w=o3;                          \
      *(uint4*)&lds[(WB) + lane*256 + (((I) ^ sw) << 3)] = ov;               \
    }

  // ---- prologue: tile t0 -> hbuf0; load md1/br1 for t0+1 ----
  unsigned md1 = 0; int br_cur = 0, br1 = 0;
  {
    unsigned md0 = e32[(size_t)t0*128 + lm];
    br_cur = (int)e32[((size_t)(t0*32 + le))*4 + 3];
    #pragma unroll
    for (int ii=0; ii<4; ii++){
      int si = __builtin_amdgcn_readfirstlane(__shfl((int)md0, ii*4));
      int di = __builtin_amdgcn_readfirstlane(__shfl((int)md0, ii*4 + 1));
      float dd = __uint_as_float((unsigned)__builtin_amdgcn_readfirstlane(__shfl((int)md0, ii*4 + 2)));
      if (si != si_prev){ ua = hl4[(size_t)si*64 + lane]; si_prev = si; }
      uint4 ub = hp4[(size_t)di*64 + lane];
      H_EDGE(ua, ub, dd, wave*4 + ii, 0)
    }
    if (t0 + 1 < t1){
      md1 = e32[(size_t)(t0+1)*128 + lm];
      br1 = (int)e32[((size_t)((t0+1)*32 + le))*4 + 3];
    }
    __syncthreads();
  }

  int cur = 0;
  unsigned md2 = md1; int br2 = br1;
  for (int t = t0; t < t1; ++t){
    bool pf = (t + 1 < t1);
    // issue next-next metadata
    if (t + 2 < t1){
      md2 = e32[(size_t)(t+2)*128 + lm];
      br2 = (int)e32[((size_t)((t+2)*32 + le))*4 + 3];
    }
    // issue hp gathers + deduped hl for tile t+1 (consumed after GEMM2)
    uint4 ub0, ub1, ub2, ub3;
    if (pf){
      int d0 = __builtin_amdgcn_readfirstlane(__shfl((int)md1, 1));
      int d1 = __builtin_amdgcn_readfirstlane(__shfl((int)md1, 5));
      int d2 = __builtin_amdgcn_readfirstlane(__shfl((int)md1, 9));
      int d3 = __builtin_amdgcn_readfirstlane(__shfl((int)md1, 13));
      ub0 = hp4[(size_t)d0*64 + lane];
      ub1 = hp4[(size_t)d1*64 + lane];
      ub2 = hp4[(size_t)d2*64 + lane];
      ub3 = hp4[(size_t)d3*64 + lane];
      int s0 = __builtin_amdgcn_readfirstlane(__shfl((int)md1, 0));
      if (s0 != si_prev){ ua = hl4[(size_t)s0*64 + lane]; si_prev = s0; }
    }

    int rb = cur ? 16384 : 0;
    // GEMM1: m[32,128] = h[32,512] @ W2^T + b2  (B from registers)
    float4v acc[2] = {{0,0,0,0},{0,0,0,0}};
    #pragma unroll
    for (int kk = 0; kk < 16; kk++){
      int kcc = kk*4 + quad;
      int sw2 = kcc & 31;
      short8 A0 = *(const short8*)&lds[rb + kcc*256 + ((l15 ^ sw2) << 3)];
      short8 A1 = *(const short8*)&lds[rb + kcc*256 + (((16 + l15) ^ sw2) << 3)];
      acc[0] = __builtin_amdgcn_mfma_f32_16x16x32_bf16(A0, Bk[kk], acc[0], 0, 0, 0);
      acc[1] = __builtin_amdgcn_mfma_f32_16x16x32_bf16(A1, Bk[kk], acc[1], 0, 0, 0);
    }
    float mreg[2][4];
    #pragma unroll
    for (int mt=0;mt<2;mt++){
      int col = ns + l15;
      #pragma unroll
      for (int r=0;r<4;r++){
        float mv = acc[mt][r] + b2c0;
        mreg[mt][r] = mv;
        msb[mt*16 + quad*4 + r][col] = f2bf(mv);
      }
    }
    __syncthreads();    // barrier A: msb visible

    // GEMM2: t = tanh(m@Wm^T + bm); flush sum(t*m), max(m) per batch
    float4v acc2[2] = {{0,0,0,0},{0,0,0,0}};
    #pragma unroll
    for (int kk = 0; kk < 4; kk++){
      short8 A0 = *(const short8*)&msb[l15][kk*32 + quad*8];
      short8 A1 = *(const short8*)&msb[16 + l15][kk*32 + quad*8];
      acc2[0] = __builtin_amdgcn_mfma_f32_16x16x32_bf16(A0, Bm[kk], acc2[0], 0, 0, 0);
      acc2[1] = __builtin_amdgcn_mfma_f32_16x16x32_bf16(A1, Bm[kk], acc2[1], 0, 0, 0);
    }
    {
      int b0 = __shfl(br_cur, 0);
      bool uni = (b0 == __shfl(br_cur, 31));
      int col = ns + l15;
      if (uni){
        float s = 0.f, mx = -3.402823466e38f;
        #pragma unroll
        for (int mt=0;mt<2;mt++){
          #pragma unroll
          for (int r=0;r<4;r++){
            float mv = mreg[mt][r];
            float tt = tanh_fast(acc2[mt][r] + bm0);
            s += tt*mv; mx = fmaxf(mx, mv);
          }
        }
        s += __shfl_xor(s, 16); s += __shfl_xor(s, 32);
        mx = fmaxf(mx, __shfl_xor(mx, 16)); mx = fmaxf(mx, __shfl_xor(mx, 32));
        if (quad == 0){
          atomicAdd(&outw[b0*256 + col], s);
          atomicMax(&mmax[b0*128 + col], encf(mx));
        }
      } else {
        #pragma unroll
        for (int mt=0;mt<2;mt++){
          #pragma unroll
          for (int r=0;r<4;r++){
            int row = mt*16 + quad*4 + r;
            int b = __shfl(br_cur, row);
            float mv = mreg[mt][r];
            float tt = tanh_fast(acc2[mt][r] + bm0);
            atomicAdd(&outw[b*256 + col], tt*mv);
            atomicMax(&mmax[b*128 + col], encf(mv));
          }
        }
      }
    }

    // consume prefetched gathers -> h(t+1) into the other hbuf
    if (pf){
      int wb = cur ? 0 : 16384;
      #pragma unroll
      for (int ii=0; ii<4; ii++){
        int si = __builtin_amdgcn_readfirstlane(__shfl((int)md1, ii*4));
        float dd = __uint_as_float((unsigned)__builtin_amdgcn_readfirstlane(__shfl((int)md1, ii*4 + 2)));
        if (si != si_prev){ ua = hl4[(size_t)si*64 + lane]; si_prev = si; }
        uint4 ub = (ii==0) ? ub0 : (ii==1) ? ub1 : (ii==2) ? ub2 : ub3;
        H_EDGE(ua, ub, dd, wave*4 + ii, wb)
      }
    }
    __syncthreads();    // barrier B: hbuf[cur^1] + msb reads complete

    md1 = md2; br_cur = br1; br1 = br2;
    cur ^= 1;
  }
  #undef H_EDGE
}

__global__ __launch_bounds__(256) void k_final(const unsigned* __restrict__ mmax,
    float* __restrict__ out){
  int gid = blockIdx.x*256 + threadIdx.x;   // 32768 = 256*128
  unsigned enc = mmax[gid];
  float v;
  if (enc == 0u) v = 0.f;
  else if (enc & 0x80000000u) v = __uint_as_float(enc & 0x7FFFFFFFu);
  else v = __uint_as_float(~enc);
  int g = gid >> 7, cc = gid & 127;
  out[g*256 + 128 + cc] = v;
}

extern "C" void kernel_launch(void* const* d_in, const int* in_sizes, int n_in,
                              void* d_out, int out_size, void* d_ws, size_t ws_size,
                              hipStream_t stream) {
  const float* x_l    = (const float*)d_in[0];
  const float* x_p    = (const float*)d_in[1];
  const float* ea     = (const float*)d_in[2];
  const int*   esrc   = (const int*)d_in[3];
  const int*   edst   = (const int*)d_in[4];
  const int*   lbatch = (const int*)d_in[5];
  const float* W_node = (const float*)d_in[6];
  const float* W_el   = (const float*)d_in[7];
  const float* Wb     = (const float*)d_in[8];
  const float* bb     = (const float*)d_in[9];
  const float* Wn     = (const float*)d_in[10];
  const float* Ws     = (const float*)d_in[11];
  const float* bconv  = (const float*)d_in[12];
  const float* W1     = (const float*)d_in[13];
  const float* b1     = (const float*)d_in[14];
  const float* W2     = (const float*)d_in[15];
  const float* b2     = (const float*)d_in[16];
  const float* Wm     = (const float*)d_in[17];
  const float* bm     = (const float*)d_in[18];

  // ---- workspace layout (decimal offsets), peak 267,354,496 B ----
  char* w = (char*)d_ws;
  unsigned short* xl0 = (unsigned short*)(w + 0);
  unsigned short* xl1 = (unsigned short*)(w + 12800000);
  unsigned short* xp0 = (unsigned short*)(w + 25600000);
  unsigned short* xp1 = (unsigned short*)(w + 64000000);
  int*      idxP  = (int*)(w + 102400000);
  int*      idxL  = (int*)(w + 104400000);
  unsigned short* lut = (unsigned short*)(w + 106400000);   // 6.29e6 B
  unsigned* h_l   = (unsigned*)(w + 0);
  unsigned* h_p   = (unsigned*)(w + 51200000);
  unsigned short* xl_s = (unsigned short*)(w + 204800000);
  unsigned short* xp_s = (unsigned short*)(w + 217600000);
  unsigned short* wcat = (unsigned short*)(w + 256000000);
  unsigned short* w1t  = (unsigned short*)(w + 256393216);
  unsigned short* w2t  = (unsigned short*)(w + 256655360);
  unsigned short* wmt  = (unsigned short*)(w + 256786432);
  float*    vvec  = (float*)(w + 256819200);
  unsigned* mmax  = (unsigned*)(w + 256821248);
  unsigned* bsumL = (unsigned*)(w + 256952320);
  unsigned* bsumP = (unsigned*)(w + 256953344);
  unsigned* rowptrL = (unsigned*)(w + 256954368);
  unsigned* cursorL = (unsigned*)(w + 257154432);
  unsigned* rowptrP = (unsigned*)(w + 257354432);
  unsigned* cursorP = (unsigned*)(w + 257954496);
  unsigned* cntL    = (unsigned*)(w + 258554496);
  unsigned* cntP    = (unsigned*)(w + 258754496);
  uint4*    edgeL   = (uint4*)(w + 259354496);   // {src, dst, bits(d), batch}

  float* out = (float*)d_out;

  k_prep<<<114470, 256, 0, stream>>>(
      (unsigned*)(w + 258554496), mmax, (unsigned*)d_out,
      x_l, x_p, W_node, xl0, xp0,
      W_el, W1, vvec, W2, w2t, Wm, wmt, Ws, Wn, wcat, w1t, Wb, bb, lut);

  k_count<<<1954, 256, 0, stream>>>(esrc, edst, cntL, cntP);
  k_cs2<<<196, 256, 0, stream>>>(cntL, rowptrL, bsumL, cntP, rowptrP, bsumP);
  k_sb2<<<2, 256, 0, stream>>>(bsumL, bsumP);
  k_ao2<<<782, 256, 0, stream>>>(rowptrL, cursorL, bsumL, rowptrP, cursorP, bsumP);
  k_place<<<1954, 256, 0, stream>>>(esrc, edst, ea, lbatch, cursorL, cursorP,
                                    edgeL, idxL, idxP);

  unsigned short *xlc = xl0, *xln = xl1, *xpc = xp0, *xpn = xp1;
  for (int l = 0; l < 3; ++l){
    int ilp = 2*l, ipl = 2*l + 1;
    k_conv2<<<NBP + NBL, 256, 0, stream>>>(
        xpc, xlc, xpn, xln, xp_s, xl_s,
        rowptrP, idxP, rowptrL, idxL,
        lut + (size_t)ilp*524288, wcat + ilp*32768, bconv + ilp*128,
        lut + (size_t)ipl*524288, wcat + ipl*32768, bconv + ipl*128,
        (l == 0) ? 1 : 0);
    unsigned short* t;
    t = xlc; xlc = xln; xln = t;
    t = xpc; xpc = xpn; xpn = t;
  }

  // b1 folded into h_l (ligand part); protein part no bias
  k_hproj2<<<NBL + NBP, 256, 0, stream>>>(xl_s, xp_s, w1t, b1, h_l, h_p);

  k_readout4<<<1024, 512, 0, stream>>>(h_l, h_p, edgeL, vvec,
                                       w2t, b2, wmt, bm, out, mmax);
  k_final<<<128, 256, 0, stream>>>(mmax, out);
}

// Round 7
// 1503.511 us; speedup vs baseline: 1.2044x; 1.1306x over previous
//
#include <hip/hip_runtime.h>
#include <hip/hip_bf16.h>

// HeteroNet on MI355X — round 19.
// R18 (readout cross-tile pipeline) 1772->1700us; readout4 now <280us.
// New top steady-state kernel: k_prep at 280us, 87% of whose blocks are the
// node-embed branch: 2 rows/block, 44 scalar X loads/thread, ~132 inst and
// ~88 VMEM per output for a 2.25-GFLOP GEMM (VALUBusy 22%, HBM 4% -> pure
// inefficiency). R19: dedicated k_embed — 32 rows/block, X staged to LDS via
// coalesced float4, thread = (col, 16 rows) register tile: ~45 inst/output,
// Wnode L1-hot. k_prep keeps remaining branches (grid 14470).

#define NLn 50000
#define NPn 150000
#define En  500000
#define NBL 1563   // ceil(NLn/32)
#define NBP 4688   // ceil(NPn/32)

typedef __attribute__((ext_vector_type(8))) short short8;
typedef __attribute__((ext_vector_type(4))) float float4v;

__device__ __forceinline__ float bf2f(unsigned short u){ return __uint_as_float(((unsigned)u) << 16); }
__device__ __forceinline__ float bflo(unsigned u){ return __uint_as_float(u << 16); }
__device__ __forceinline__ float bfhi(unsigned u){ return __uint_as_float(u & 0xffff0000u); }
__device__ __forceinline__ unsigned short f2bf(float f){
  __hip_bfloat16 h = __float2bfloat16(f);
  return *reinterpret_cast<unsigned short*>(&h);
}
// order-preserving float->uint; enc(v)>0 for all finite v, so 0 == "empty segment"
__device__ __forceinline__ unsigned encf(float f){
  unsigned u = __float_as_uint(f);
  return (u & 0x80000000u) ? ~u : (u | 0x80000000u);
}
__device__ __forceinline__ float tanh_fast(float x){
  return 1.f - 2.f/(__expf(2.f*x) + 1.f);
}

// ---- k_embed: X @ W_node -> bf16, 32 rows/block, register-tiled ----
__global__ __launch_bounds__(256) void k_embed(
    const float* __restrict__ Xl, const float* __restrict__ Xp,
    const float* __restrict__ Wnode,
    unsigned short* __restrict__ xl0, unsigned short* __restrict__ xp0){
  __shared__ float xs[1408];   // 32 rows x 44 fp32
  int b = blockIdx.x, tid = threadIdx.x;
  bool isL = b < NBL;
  const float* X = isL ? Xl : Xp;
  unsigned short* out = isL ? xl0 : xp0;
  int n = isL ? NLn : NPn;
  int n0 = (isL ? b : b - NBL) * 32;
  int nrows = n - n0; if (nrows > 32) nrows = 32;   // always 32 or 16 here
  int nflt = nrows * 44;                            // multiple of 4
  const float4* Xv = (const float4*)(X + (size_t)n0*44);
  for (int j = tid; j*4 < nflt; j += 256){
    float4 v = Xv[j];
    xs[j*4+0]=v.x; xs[j*4+1]=v.y; xs[j*4+2]=v.z; xs[j*4+3]=v.w;
  }
  __syncthreads();
  int c = tid & 127, half = tid >> 7;
  float acc[16];
  #pragma unroll
  for (int r=0;r<16;r++) acc[r]=0.f;
  const float* xrow = xs + half*16*44;
  #pragma unroll 4
  for (int k=0;k<44;k++){
    float w = Wnode[k*128 + c];
    #pragma unroll
    for (int r=0;r<16;r++) acc[r] += xrow[r*44 + k] * w;
  }
  int rbase = n0 + half*16;
  #pragma unroll
  for (int r=0;r<16;r++){
    int nn = rbase + r;
    if (nn < n) out[(size_t)nn*128 + c] = f2bf(acc[r]);
  }
}

// ---- k_prep: zeros + weight transforms + LUT (embed split out) ----
__global__ __launch_bounds__(256) void k_prep(
    unsigned* __restrict__ cntz, unsigned* __restrict__ mmaxz, unsigned* __restrict__ outz,
    const float* __restrict__ Wel, const float* __restrict__ W1, float* __restrict__ vvec,
    const float* __restrict__ W2, unsigned short* __restrict__ w2t,
    const float* __restrict__ Wm, unsigned short* __restrict__ wmt,
    const float* __restrict__ Ws, const float* __restrict__ Wn,
    unsigned short* __restrict__ wcat, unsigned short* __restrict__ w1t,
    const float* __restrict__ Wb, const float* __restrict__ bb,
    unsigned short* __restrict__ lut){
  int b = blockIdx.x, tid = threadIdx.x;
  if (b < 196){
    for (long i = (long)b*256 + tid; i < 200000; i += 196*256) cntz[i] = 0u;
  } else if (b < 324){
    mmaxz[(b-196)*256 + tid] = 0u;
  } else if (b < 580){
    outz[(b-324)*256 + tid] = 0u;
  } else if (b < 582){
    int j = (b-580)*256 + tid;
    float s = 0.f;
    #pragma unroll
    for (int r=0;r<8;r++) s += Wel[r]*W1[(256+r)*512 + j];
    vvec[j] = s;
  } else if (b < 838){
    int gid = (b-582)*256 + tid;                       // 65536
    int n = gid >> 9, k = gid & 511;
    w2t[n*512 + k] = f2bf(W2[k*128 + n]);
  } else if (b < 902){
    int gid = (b-838)*256 + tid;                       // 16384
    int n = gid >> 7, k = gid & 127;
    wmt[n*128 + k] = f2bf(Wm[k*128 + n]);
  } else if (b < 1670){
    int gid = (b-902)*256 + tid;                       // 196608
    int i = gid >> 15, rem = gid & 32767;
    int n = rem >> 8, k = rem & 255;
    float v = (k < 128) ? Ws[i*16384 + k*128 + n] : Wn[i*16384 + (k-128)*128 + n];
    wcat[gid] = f2bf(v);
  } else if (b < 2182){
    int gid = (b-1670)*256 + tid;                      // 131072
    int part = gid >> 16, rem = gid & 65535;
    int n = rem >> 7, k = rem & 127;
    w1t[gid] = f2bf(W1[(part*128 + k)*512 + n]);
  } else {
    int gid = (b-2182)*256 + tid;                      // 3145728
    int c = gid & 127, bin = (gid >> 7) & 4095, i = gid >> 19;
    float d = ((float)bin + 0.5f) * 0.001220703125f;   // *5/4096
    float s = bb[i*128 + c];
    #pragma unroll
    for (int j=0;j<8;j++){
      float a = (d - 0.7142857143f*(float)j) * 1.6f;
      s += __expf(-a*a) * Wb[i*1024 + j*128 + c];
    }
    lut[gid] = f2bf(s / (1.f + __expf(-s)));
  }
}

// ---- CSR construction ----
__global__ __launch_bounds__(256) void k_count(const int* __restrict__ esrc,
    const int* __restrict__ edst, unsigned* __restrict__ cntL, unsigned* __restrict__ cntP){
  int e = blockIdx.x*256 + threadIdx.x;
  if (e >= En) return;
  atomicAdd(&cntL[esrc[e]], 1u);
  atomicAdd(&cntP[edst[e]], 1u);
}
__global__ __launch_bounds__(256) void k_cs2(const unsigned* __restrict__ cntL,
    unsigned* __restrict__ rowptrL, unsigned* __restrict__ bsumL,
    const unsigned* __restrict__ cntP, unsigned* __restrict__ rowptrP,
    unsigned* __restrict__ bsumP){
  bool isL = blockIdx.x < 49;
  const unsigned* cnt = isL ? cntL : cntP;
  unsigned* rowptr = isL ? rowptrL : rowptrP;
  unsigned* bsum = isL ? bsumL : bsumP;
  int n = isL ? NLn : NPn;
  int lb = isL ? blockIdx.x : blockIdx.x - 49;
  __shared__ unsigned ts[256];
  int tid = threadIdx.x;
  int base = lb*1024 + tid*4;
  unsigned v[4], run = 0;
  #pragma unroll
  for (int j=0;j<4;j++){ v[j] = run; run += (base+j < n) ? cnt[base+j] : 0u; }
  ts[tid] = run; __syncthreads();
  for (int off=1; off<256; off<<=1){
    unsigned t = (tid>=off) ? ts[tid-off] : 0u; __syncthreads();
    ts[tid] += t; __syncthreads();
  }
  unsigned excl = ts[tid] - run;
  #pragma unroll
  for (int j=0;j<4;j++) if (base+j < n) rowptr[base+j] = excl + v[j];
  if (tid == 255) bsum[lb] = ts[255];
}
__global__ void k_sb2(unsigned* __restrict__ bsumL, unsigned* __restrict__ bsumP){
  unsigned* bsum = blockIdx.x ? bsumP : bsumL;
  int nc = blockIdx.x ? 147 : 49;
  __shared__ unsigned ts[256];
  int tid = threadIdx.x;
  unsigned x = (tid < nc) ? bsum[tid] : 0u;
  ts[tid] = x; __syncthreads();
  for (int off=1; off<256; off<<=1){
    unsigned t = (tid>=off) ? ts[tid-off] : 0u; __syncthreads();
    ts[tid] += t; __syncthreads();
  }
  if (tid < nc) bsum[tid] = ts[tid] - x;
}
__global__ __launch_bounds__(256) void k_ao2(
    unsigned* __restrict__ rowptrL, unsigned* __restrict__ cursorL,
    const unsigned* __restrict__ bsumL,
    unsigned* __restrict__ rowptrP, unsigned* __restrict__ cursorP,
    const unsigned* __restrict__ bsumP){
  bool isL = blockIdx.x < 196;
  unsigned* rowptr = isL ? rowptrL : rowptrP;
  unsigned* cursor = isL ? cursorL : cursorP;
  const unsigned* bsum = isL ? bsumL : bsumP;
  int n = isL ? NLn : NPn;
  int i = (isL ? blockIdx.x : blockIdx.x - 196)*256 + threadIdx.x;
  if (i < n){
    unsigned r = rowptr[i] + bsum[i>>10];
    rowptr[i] = r; cursor[i] = r;
  }
  if (i == 0) rowptr[n] = En;
}
__global__ __launch_bounds__(256) void k_place(const int* __restrict__ esrc,
    const int* __restrict__ edst, const float* __restrict__ ea,
    const int* __restrict__ lbatch, unsigned* __restrict__ curL,
    unsigned* __restrict__ curP, uint4* __restrict__ edgeL,
    int* __restrict__ idxL, int* __restrict__ idxP){
  int e = blockIdx.x*256 + threadIdx.x;
  if (e >= En) return;
  int s = esrc[e], d = edst[e];
  float dd = ea[e];
  int bin = (int)(dd * 819.2f);
  bin = (bin < 0) ? 0 : ((bin > 4095) ? 4095 : bin);
  unsigned pl = atomicAdd(&curL[s], 1u);
  uint4 er; er.x = (unsigned)s; er.y = (unsigned)d;
  er.z = __float_as_uint(dd); er.w = (unsigned)lbatch[s];
  edgeL[pl] = er;
  idxL[pl] = d | (bin << 18);
  unsigned pp = atomicAdd(&curP[d], 1u);
  idxP[pp] = s | (bin << 18);
}

// ---- fused dual-direction conv with silu-LUT (R10 unroll-4 inner loop) ----
#define EDGE_CAP 1024
__global__ __launch_bounds__(256) void k_conv2(
    const unsigned short* __restrict__ xp_in, const unsigned short* __restrict__ xl_in,
    unsigned short* __restrict__ xp_out, unsigned short* __restrict__ xl_out,
    unsigned short* __restrict__ xp_sum, unsigned short* __restrict__ xl_sum,
    const unsigned* __restrict__ rowptrP, const int* __restrict__ idxP,
    const unsigned* __restrict__ rowptrL, const int* __restrict__ idxL,
    const unsigned short* __restrict__ lut_lp,
    const unsigned short* __restrict__ wcat_lp, const float* __restrict__ bias_lp,
    const unsigned short* __restrict__ lut_pl,
    const unsigned short* __restrict__ wcat_pl, const float* __restrict__ bias_pl,
    int first){
  __shared__ unsigned short ab[32][264];   // [m][k]: k<128 x_dst, k>=128 agg (bf16)
  __shared__ unsigned short ob[32][136];   // epilogue bf16
  __shared__ int snb[EDGE_CAP];
  __shared__ unsigned rps[33];
  int tid = threadIdx.x, c = tid & 127, hh = tid >> 7;
  bool isP = blockIdx.x < NBP;
  const unsigned short* xdst_in = isP ? xp_in : xl_in;
  const unsigned short* xsrc_in = isP ? xl_in : xp_in;
  unsigned short* xout = isP ? xp_out : xl_out;
  unsigned short* xsum = isP ? xp_sum : xl_sum;
  const unsigned* rowptr = isP ? rowptrP : rowptrL;
  const int* eidx = isP ? idxP : idxL;
  const unsigned short* lut_i = isP ? lut_lp : lut_pl;
  const unsigned short* wcat = isP ? wcat_lp : wcat_pl;
  const float* bias = isP ? bias_lp : bias_pl;
  int ndst = isP ? NPn : NLn;
  int n0 = (isP ? blockIdx.x : (blockIdx.x - NBP)) * 32;

  if (tid < 33){
    int idx = n0 + tid; if (idx > ndst) idx = ndst;
    rps[tid] = rowptr[idx];
  }
  __syncthreads();
  int r00 = (int)rps[0], rEnd = (int)rps[32];
  int eblk = rEnd - r00;
  bool fits = (eblk <= EDGE_CAP);
  if (fits){
    for (int p = tid; p < eblk; p += 256) snb[p] = eidx[r00 + p];
  }
  __syncthreads();

  const unsigned short* lutc = lut_i + c;
  const unsigned short* xc = xsrc_in + c;
  for (int m = hh*16; m < hh*16+16; m++){
    int n = n0 + m;
    float a0=0.f, a1=0.f, a2=0.f, a3=0.f;
    int dg = 1;
    if (n < ndst){
      ab[m][c] = xdst_in[(size_t)n*128 + c];
      int r0 = (int)rps[m], r1 = (int)rps[m+1];
      dg = r1 - r0;
      int p = r0;
      for (; p + 3 < r1; p += 4){
        int v0,v1,v2,v3;
        if (fits){
          v0 = snb[p-r00]; v1 = snb[p-r00+1]; v2 = snb[p-r00+2]; v3 = snb[p-r00+3];
        } else {
          v0 = eidx[p]; v1 = eidx[p+1]; v2 = eidx[p+2]; v3 = eidx[p+3];
        }
        a0 += bf2f(lutc[(size_t)((unsigned)v0 >> 18)*128]) * bf2f(xc[(size_t)(v0 & 0x3FFFF)*128]);
        a1 += bf2f(lutc[(size_t)((unsigned)v1 >> 18)*128]) * bf2f(xc[(size_t)(v1 & 0x3FFFF)*128]);
        a2 += bf2f(lutc[(size_t)((unsigned)v2 >> 18)*128]) * bf2f(xc[(size_t)(v2 & 0x3FFFF)*128]);
        a3 += bf2f(lutc[(size_t)((unsigned)v3 >> 18)*128]) * bf2f(xc[(size_t)(v3 & 0x3FFFF)*128]);
      }
      for (; p < r1; p++){
        int v0 = fits ? snb[p-r00] : eidx[p];
        a0 += bf2f(lutc[(size_t)((unsigned)v0 >> 18)*128]) * bf2f(xc[(size_t)(v0 & 0x3FFFF)*128]);
      }
    } else {
      ab[m][c] = 0;
    }
    float inv = 1.f / (float)(dg > 1 ? dg : 1);
    ab[m][128 + c] = f2bf(((a0+a1)+(a2+a3)) * inv);
  }
  __syncthreads();

  int wave = tid >> 6, lane = tid & 63, quad = lane >> 4, l15 = lane & 15;
  int mt = wave & 1, nh = wave >> 1;
  int arow = mt*16 + l15;
  float4v acc[4] = {{0,0,0,0},{0,0,0,0},{0,0,0,0},{0,0,0,0}};
  for (int k0 = 0; k0 < 256; k0 += 32){
    short8 A = *(const short8*)&ab[arow][k0 + quad*8];
    #pragma unroll
    for (int nt=0;nt<4;nt++){
      short8 B = *(const short8*)&wcat[(size_t)(nh*64 + nt*16 + l15)*256 + k0 + quad*8];
      acc[nt] = __builtin_amdgcn_mfma_f32_16x16x32_bf16(A, B, acc[nt], 0, 0, 0);
    }
  }
  #pragma unroll
  for (int nt=0;nt<4;nt++){
    int col = nh*64 + nt*16 + l15;
    float bc = bias[col];
    #pragma unroll
    for (int r=0;r<4;r++){
      int row = mt*16 + quad*4 + r;
      float v = acc[nt][r] + bc;
      ob[row][col] = f2bf((v > 0.f) ? v : 0.01f*v);    // leaky_relu
    }
  }
  __syncthreads();
  for (int m = hh*16; m < hh*16+16; m++){
    int n = n0 + m;
    if (n < ndst){
      unsigned short vb = ob[m][c];
      size_t off = (size_t)n*128 + c;
      xout[off] = vb;
      xsum[off] = first ? vb : f2bf(bf2f(xsum[off]) + bf2f(vb));
    }
  }
}

// ---- merged MFMA hproj: blocks [0,NBL): ligand (+b1); [NBL,NBL+NBP): protein
__global__ __launch_bounds__(256) void k_hproj2(
    const unsigned short* __restrict__ xl_s, const unsigned short* __restrict__ xp_s,
    const unsigned short* __restrict__ w1t, const float* __restrict__ b1,
    unsigned* __restrict__ h_l, unsigned* __restrict__ h_p){
  __shared__ unsigned short hb[32][528];
  bool isL = blockIdx.x < NBL;
  const unsigned short* xs = isL ? xl_s : xp_s;
  const unsigned short* wt = isL ? w1t : w1t + 65536;
  unsigned* hout = isL ? h_l : h_p;
  int nn = isL ? NLn : NPn;
  int n0 = (isL ? blockIdx.x : blockIdx.x - NBL)*32;
  int tid = threadIdx.x;
  int wave = tid >> 6, lane = tid & 63, quad = lane >> 4, l15 = lane & 15;
  int mt = wave & 1, nh = wave >> 1;
  int an = n0 + mt*16 + l15; if (an >= nn) an = nn - 1;
  const unsigned short* aptr = xs + (size_t)an*128;
  float4v acc[16];
  #pragma unroll
  for (int i=0;i<16;i++) acc[i] = (float4v){0,0,0,0};
  for (int k0 = 0; k0 < 128; k0 += 32){
    short8 A = *(const short8*)&aptr[k0 + quad*8];
    #pragma unroll
    for (int nt=0;nt<16;nt++){
      short8 B = *(const short8*)&wt[(size_t)(nh*256 + nt*16 + l15)*128 + k0 + quad*8];
      acc[nt] = __builtin_amdgcn_mfma_f32_16x16x32_bf16(A, B, acc[nt], 0, 0, 0);
    }
  }
  #pragma unroll
  for (int nt=0;nt<16;nt++){
    int col = nh*256 + nt*16 + l15;
    float bv = isL ? b1[col] : 0.f;
    #pragma unroll
    for (int r=0;r<4;r++) hb[mt*16 + quad*4 + r][col] = f2bf(acc[nt][r] + bv);
  }
  __syncthreads();
  for (int m=0;m<32;m++){
    int n = n0 + m;
    if (n < nn){
      unsigned pack = (unsigned)hb[m][2*tid] | ((unsigned)hb[m][2*tid+1] << 16);
      hout[(size_t)n*256 + tid] = pack;
    }
  }
}

// ---- readout v10: persistent + reg-resident B + cross-tile pipeline. ----
__global__ __launch_bounds__(512) void k_readout4(
    const unsigned* __restrict__ hl, const unsigned* __restrict__ hp,
    const uint4* __restrict__ edgeL, const float* __restrict__ vvec,
    const unsigned short* __restrict__ w2t, const float* __restrict__ b2,
    const unsigned short* __restrict__ wmt, const float* __restrict__ bm,
    float* __restrict__ outw, unsigned* __restrict__ mmax){
  __shared__ __align__(16) unsigned short lds[37120];   // 2x16384 hbuf + msb
  unsigned short (*msb)[136] = (unsigned short(*)[136])(lds + 32768);
  int tid = threadIdx.x, lane = tid & 63, wave = tid >> 6;
  int quad = lane >> 4, l15 = lane & 15;
  int ns = wave*16;                // this wave's N-strip for both GEMMs

  // XCD-chunked tile mapping
  int wg = (blockIdx.x & 7)*128 + (blockIdx.x >> 3);   // bijective [0,1024)
  int nt_tot = En/32;
  int t0 = wg*16;
  int t1 = t0 + 16; if (t1 > nt_tot) t1 = nt_tot;
  if (t0 >= t1) return;

  // ---- register-resident B: w2t strip (64 VGPR) + wmt strip (16 VGPR) ----
  short8 Bk[16];
  #pragma unroll
  for (int kk=0;kk<16;kk++)
    Bk[kk] = *(const short8*)&w2t[(size_t)(ns + l15)*512 + kk*32 + quad*8];
  short8 Bm[4];
  #pragma unroll
  for (int kk=0;kk<4;kk++)
    Bm[kk] = *(const short8*)&wmt[(size_t)(ns + l15)*128 + kk*32 + quad*8];
  float b2c0 = b2[ns + l15];
  float bm0  = bm[ns + l15];

  // vvec for chunk `lane`: h columns [8*lane, 8*lane+8)
  float4v vva = *(const float4v*)&vvec[lane*8];
  float4v vvb = *(const float4v*)&vvec[lane*8 + 4];
  int sw = lane & 31;
  const uint4* hl4 = (const uint4*)hl;   // one h row = 64 uint4
  const uint4* hp4 = (const uint4*)hp;
  const unsigned* e32 = (const unsigned*)edgeL;

  int si_prev = -1;
  uint4 ua = {0,0,0,0};
  int lm = wave*16 + (lane & 15);        // metadata dword index for this wave
  int le = lane & 31;                    // epilogue edge index

  #define H_EDGE(UA, UB, DD, I, WB)                                          \
    {                                                                        \
      unsigned o0,o1,o2,o3; float hx,hy;                                     \
      hx = fmaxf(bflo(UA.x)+bflo(UB.x)+(DD)*vva.x, 0.f);                     \
      hy = fmaxf(bfhi(UA.x)+bfhi(UB.x)+(DD)*vva.y, 0.f);                     \
      o0 = (unsigned)f2bf(hx) | ((unsigned)f2bf(hy) << 16);                  \
      hx = fmaxf(bflo(UA.y)+bflo(UB.y)+(DD)*vva.z, 0.f);                     \
      hy = fmaxf(bfhi(UA.y)+bfhi(UB.y)+(DD)*vva.w, 0.f);                     \
      o1 = (unsigned)f2bf(hx) | ((unsigned)f2bf(hy) << 16);                  \
      hx = fmaxf(bflo(UA.z)+bflo(UB.z)+(DD)*vvb.x, 0.f);                     \
      hy = fmaxf(bfhi(UA.z)+bfhi(UB.z)+(DD)*vvb.y, 0.f);                     \
      o2 = (unsigned)f2bf(hx) | ((unsigned)f2bf(hy) << 16);                  \
      hx = fmaxf(bflo(UA.w)+bflo(UB.w)+(DD)*vvb.z, 0.f);                     \
      hy = fmaxf(bfhi(UA.w)+bfhi(UB.w)+(DD)*vvb.w, 0.f);                     \
      o3 = (unsigned)f2bf(hx) | ((unsigned)f2bf(hy) << 16);                  \
      uint4 ov; ov.x=o0; ov.y=o1; ov.z=o2; ov.w=o3;                          \
      *(uint4*)&lds[(WB) + lane*256 + (((I) ^ sw) << 3)] = ov;               \
    }

  // ---- prologue: tile t0 -> hbuf0; load md1/br1 for t0+1 ----
  unsigned md1 = 0; int br_cur = 0, br1 = 0;
  {
    unsigned md0 = e32[(size_t)t0*128 + lm];
    br_cur = (int)e32[((size_t)(t0*32 + le))*4 + 3];
    #pragma unroll
    for (int ii=0; ii<4; ii++){
      int si = __builtin_amdgcn_readfirstlane(__shfl((int)md0, ii*4));
      int di = __builtin_amdgcn_readfirstlane(__shfl((int)md0, ii*4 + 1));
      float dd = __uint_as_float((unsigned)__builtin_amdgcn_readfirstlane(__shfl((int)md0, ii*4 + 2)));
      if (si != si_prev){ ua = hl4[(size_t)si*64 + lane]; si_prev = si; }
      uint4 ub = hp4[(size_t)di*64 + lane];
      H_EDGE(ua, ub, dd, wave*4 + ii, 0)
    }
    if (t0 + 1 < t1){
      md1 = e32[(size_t)(t0+1)*128 + lm];
      br1 = (int)e32[((size_t)((t0+1)*32 + le))*4 + 3];
    }
    __syncthreads();
  }

  int cur = 0;
  unsigned md2 = md1; int br2 = br1;
  for (int t = t0; t < t1; ++t){
    bool pf = (t + 1 < t1);
    // issue next-next metadata
    if (t + 2 < t1){
      md2 = e32[(size_t)(t+2)*128 + lm];
      br2 = (int)e32[((size_t)((t+2)*32 + le))*4 + 3];
    }
    // issue hp gathers + deduped hl for tile t+1 (consumed after GEMM2)
    uint4 ub0, ub1, ub2, ub3;
    if (pf){
      int d0 = __builtin_amdgcn_readfirstlane(__shfl((int)md1, 1));
      int d1 = __builtin_amdgcn_readfirstlane(__shfl((int)md1, 5));
      int d2 = __builtin_amdgcn_readfirstlane(__shfl((int)md1, 9));
      int d3 = __builtin_amdgcn_readfirstlane(__shfl((int)md1, 13));
      ub0 = hp4[(size_t)d0*64 + lane];
      ub1 = hp4[(size_t)d1*64 + lane];
      ub2 = hp4[(size_t)d2*64 + lane];
      ub3 = hp4[(size_t)d3*64 + lane];
      int s0 = __builtin_amdgcn_readfirstlane(__shfl((int)md1, 0));
      if (s0 != si_prev){ ua = hl4[(size_t)s0*64 + lane]; si_prev = s0; }
    }

    int rb = cur ? 16384 : 0;
    // GEMM1: m[32,128] = h[32,512] @ W2^T + b2  (B from registers)
    float4v acc[2] = {{0,0,0,0},{0,0,0,0}};
    #pragma unroll
    for (int kk = 0; kk < 16; kk++){
      int kcc = kk*4 + quad;
      int sw2 = kcc & 31;
      short8 A0 = *(const short8*)&lds[rb + kcc*256 + ((l15 ^ sw2) << 3)];
      short8 A1 = *(const short8*)&lds[rb + kcc*256 + (((16 + l15) ^ sw2) << 3)];
      acc[0] = __builtin_amdgcn_mfma_f32_16x16x32_bf16(A0, Bk[kk], acc[0], 0, 0, 0);
      acc[1] = __builtin_amdgcn_mfma_f32_16x16x32_bf16(A1, Bk[kk], acc[1], 0, 0, 0);
    }
    float mreg[2][4];
    #pragma unroll
    for (int mt=0;mt<2;mt++){
      int col = ns + l15;
      #pragma unroll
      for (int r=0;r<4;r++){
        float mv = acc[mt][r] + b2c0;
        mreg[mt][r] = mv;
        msb[mt*16 + quad*4 + r][col] = f2bf(mv);
      }
    }
    __syncthreads();    // barrier A: msb visible

    // GEMM2: t = tanh(m@Wm^T + bm); flush sum(t*m), max(m) per batch
    float4v acc2[2] = {{0,0,0,0},{0,0,0,0}};
    #pragma unroll
    for (int kk = 0; kk < 4; kk++){
      short8 A0 = *(const short8*)&msb[l15][kk*32 + quad*8];
      short8 A1 = *(const short8*)&msb[16 + l15][kk*32 + quad*8];
      acc2[0] = __builtin_amdgcn_mfma_f32_16x16x32_bf16(A0, Bm[kk], acc2[0], 0, 0, 0);
      acc2[1] = __builtin_amdgcn_mfma_f32_16x16x32_bf16(A1, Bm[kk], acc2[1], 0, 0, 0);
    }
    {
      int b0 = __shfl(br_cur, 0);
      bool uni = (b0 == __shfl(br_cur, 31));
      int col = ns + l15;
      if (uni){
        float s = 0.f, mx = -3.402823466e38f;
        #pragma unroll
        for (int mt=0;mt<2;mt++){
          #pragma unroll
          for (int r=0;r<4;r++){
            float mv = mreg[mt][r];
            float tt = tanh_fast(acc2[mt][r] + bm0);
            s += tt*mv; mx = fmaxf(mx, mv);
          }
        }
        s += __shfl_xor(s, 16); s += __shfl_xor(s, 32);
        mx = fmaxf(mx, __shfl_xor(mx, 16)); mx = fmaxf(mx, __shfl_xor(mx, 32));
        if (quad == 0){
          atomicAdd(&outw[b0*256 + col], s);
          atomicMax(&mmax[b0*128 + col], encf(mx));
        }
      } else {
        #pragma unroll
        for (int mt=0;mt<2;mt++){
          #pragma unroll
          for (int r=0;r<4;r++){
            int row = mt*16 + quad*4 + r;
            int b = __shfl(br_cur, row);
            float mv = mreg[mt][r];
            float tt = tanh_fast(acc2[mt][r] + bm0);
            atomicAdd(&outw[b*256 + col], tt*mv);
            atomicMax(&mmax[b*128 + col], encf(mv));
          }
        }
      }
    }

    // consume prefetched gathers -> h(t+1) into the other hbuf
    if (pf){
      int wb = cur ? 0 : 16384;
      #pragma unroll
      for (int ii=0; ii<4; ii++){
        int si = __builtin_amdgcn_readfirstlane(__shfl((int)md1, ii*4));
        float dd = __uint_as_float((unsigned)__builtin_amdgcn_readfirstlane(__shfl((int)md1, ii*4 + 2)));
        if (si != si_prev){ ua = hl4[(size_t)si*64 + lane]; si_prev = si; }
        uint4 ub = (ii==0) ? ub0 : (ii==1) ? ub1 : (ii==2) ? ub2 : ub3;
        H_EDGE(ua, ub, dd, wave*4 + ii, wb)
      }
    }
    __syncthreads();    // barrier B: hbuf[cur^1] + msb reads complete

    md1 = md2; br_cur = br1; br1 = br2;
    cur ^= 1;
  }
  #undef H_EDGE
}

__global__ __launch_bounds__(256) void k_final(const unsigned* __restrict__ mmax,
    float* __restrict__ out){
  int gid = blockIdx.x*256 + threadIdx.x;   // 32768 = 256*128
  unsigned enc = mmax[gid];
  float v;
  if (enc == 0u) v = 0.f;
  else if (enc & 0x80000000u) v = __uint_as_float(enc & 0x7FFFFFFFu);
  else v = __uint_as_float(~enc);
  int g = gid >> 7, cc = gid & 127;
  out[g*256 + 128 + cc] = v;
}

extern "C" void kernel_launch(void* const* d_in, const int* in_sizes, int n_in,
                              void* d_out, int out_size, void* d_ws, size_t ws_size,
                              hipStream_t stream) {
  const float* x_l    = (const float*)d_in[0];
  const float* x_p    = (const float*)d_in[1];
  const float* ea     = (const float*)d_in[2];
  const int*   esrc   = (const int*)d_in[3];
  const int*   edst   = (const int*)d_in[4];
  const int*   lbatch = (const int*)d_in[5];
  const float* W_node = (const float*)d_in[6];
  const float* W_el   = (const float*)d_in[7];
  const float* Wb     = (const float*)d_in[8];
  const float* bb     = (const float*)d_in[9];
  const float* Wn     = (const float*)d_in[10];
  const float* Ws     = (const float*)d_in[11];
  const float* bconv  = (const float*)d_in[12];
  const float* W1     = (const float*)d_in[13];
  const float* b1     = (const float*)d_in[14];
  const float* W2     = (const float*)d_in[15];
  const float* b2     = (const float*)d_in[16];
  const float* Wm     = (const float*)d_in[17];
  const float* bm     = (const float*)d_in[18];

  // ---- workspace layout (decimal offsets), peak 267,354,496 B ----
  char* w = (char*)d_ws;
  unsigned short* xl0 = (unsigned short*)(w + 0);
  unsigned short* xl1 = (unsigned short*)(w + 12800000);
  unsigned short* xp0 = (unsigned short*)(w + 25600000);
  unsigned short* xp1 = (unsigned short*)(w + 64000000);
  int*      idxP  = (int*)(w + 102400000);
  int*      idxL  = (int*)(w + 104400000);
  unsigned short* lut = (unsigned short*)(w + 106400000);   // 6.29e6 B
  unsigned* h_l   = (unsigned*)(w + 0);
  unsigned* h_p   = (unsigned*)(w + 51200000);
  unsigned short* xl_s = (unsigned short*)(w + 204800000);
  unsigned short* xp_s = (unsigned short*)(w + 217600000);
  unsigned short* wcat = (unsigned short*)(w + 256000000);
  unsigned short* w1t  = (unsigned short*)(w + 256393216);
  unsigned short* w2t  = (unsigned short*)(w + 256655360);
  unsigned short* wmt  = (unsigned short*)(w + 256786432);
  float*    vvec  = (float*)(w + 256819200);
  unsigned* mmax  = (unsigned*)(w + 256821248);
  unsigned* bsumL = (unsigned*)(w + 256952320);
  unsigned* bsumP = (unsigned*)(w + 256953344);
  unsigned* rowptrL = (unsigned*)(w + 256954368);
  unsigned* cursorL = (unsigned*)(w + 257154432);
  unsigned* rowptrP = (unsigned*)(w + 257354432);
  unsigned* cursorP = (unsigned*)(w + 257954496);
  unsigned* cntL    = (unsigned*)(w + 258554496);
  unsigned* cntP    = (unsigned*)(w + 258754496);
  uint4*    edgeL   = (uint4*)(w + 259354496);   // {src, dst, bits(d), batch}

  float* out = (float*)d_out;

  k_prep<<<14470, 256, 0, stream>>>(
      (unsigned*)(w + 258554496), mmax, (unsigned*)d_out,
      W_el, W1, vvec, W2, w2t, Wm, wmt, Ws, Wn, wcat, w1t, Wb, bb, lut);
  k_embed<<<NBL + NBP, 256, 0, stream>>>(x_l, x_p, W_node, xl0, xp0);

  k_count<<<1954, 256, 0, stream>>>(esrc, edst, cntL, cntP);
  k_cs2<<<196, 256, 0, stream>>>(cntL, rowptrL, bsumL, cntP, rowptrP, bsumP);
  k_sb2<<<2, 256, 0, stream>>>(bsumL, bsumP);
  k_ao2<<<782, 256, 0, stream>>>(rowptrL, cursorL, bsumL, rowptrP, cursorP, bsumP);
  k_place<<<1954, 256, 0, stream>>>(esrc, edst, ea, lbatch, cursorL, cursorP,
                                    edgeL, idxL, idxP);

  unsigned short *xlc = xl0, *xln = xl1, *xpc = xp0, *xpn = xp1;
  for (int l = 0; l < 3; ++l){
    int ilp = 2*l, ipl = 2*l + 1;
    k_conv2<<<NBP + NBL, 256, 0, stream>>>(
        xpc, xlc, xpn, xln, xp_s, xl_s,
        rowptrP, idxP, rowptrL, idxL,
        lut + (size_t)ilp*524288, wcat + ilp*32768, bconv + ilp*128,
        lut + (size_t)ipl*524288, wcat + ipl*32768, bconv + ipl*128,
        (l == 0) ? 1 : 0);
    unsigned short* t;
    t = xlc; xlc = xln; xln = t;
    t = xpc; xpc = xpn; xpn = t;
  }

  // b1 folded into h_l (ligand part); protein part no bias
  k_hproj2<<<NBL + NBP, 256, 0, stream>>>(xl_s, xp_s, w1t, b1, h_l, h_p);

  k_readout4<<<1024, 512, 0, stream>>>(h_l, h_p, edgeL, vvec,
                                       w2t, b2, wmt, bm, out, mmax);
  k_final<<<128, 256, 0, stream>>>(mmax, out);
}

// Round 8
// 1287.101 us; speedup vs baseline: 1.4069x; 1.1681x over previous
//
#include <hip/hip_runtime.h>
#include <hip/hip_bf16.h>

// HeteroNet on MI355X — round 20.
// R19: embed split -> 1503us. Profile now: conv2 = 265us x3 = 53% of total,
// MfmaUtil 2%, VALUBusy 34%, HBM 14% -> gather phase issue+latency bound,
// 2B/lane scalar bf16 gathers (Common-mistake #2 in gather form).
// R20: conv2 gather remapped (2 halves x 128 cols x 16 rows) ->
// (4 groups x 64 col-PAIRS x 8 rows): dword loads for x_src/lut (VMEM/edge
// halved), address math halved, serial chain halved, dword-packed epilogue.
// MFMA phase / snb / LDS layout unchanged.

#define NLn 50000
#define NPn 150000
#define En  500000
#define NBL 1563   // ceil(NLn/32)
#define NBP 4688   // ceil(NPn/32)

typedef __attribute__((ext_vector_type(8))) short short8;
typedef __attribute__((ext_vector_type(4))) float float4v;

__device__ __forceinline__ float bf2f(unsigned short u){ return __uint_as_float(((unsigned)u) << 16); }
__device__ __forceinline__ float bflo(unsigned u){ return __uint_as_float(u << 16); }
__device__ __forceinline__ float bfhi(unsigned u){ return __uint_as_float(u & 0xffff0000u); }
__device__ __forceinline__ unsigned short f2bf(float f){
  __hip_bfloat16 h = __float2bfloat16(f);
  return *reinterpret_cast<unsigned short*>(&h);
}
// order-preserving float->uint; enc(v)>0 for all finite v, so 0 == "empty segment"
__device__ __forceinline__ unsigned encf(float f){
  unsigned u = __float_as_uint(f);
  return (u & 0x80000000u) ? ~u : (u | 0x80000000u);
}
__device__ __forceinline__ float tanh_fast(float x){
  return 1.f - 2.f/(__expf(2.f*x) + 1.f);
}

// ---- k_embed: X @ W_node -> bf16, 32 rows/block, register-tiled ----
__global__ __launch_bounds__(256) void k_embed(
    const float* __restrict__ Xl, const float* __restrict__ Xp,
    const float* __restrict__ Wnode,
    unsigned short* __restrict__ xl0, unsigned short* __restrict__ xp0){
  __shared__ float xs[1408];   // 32 rows x 44 fp32
  int b = blockIdx.x, tid = threadIdx.x;
  bool isL = b < NBL;
  const float* X = isL ? Xl : Xp;
  unsigned short* out = isL ? xl0 : xp0;
  int n = isL ? NLn : NPn;
  int n0 = (isL ? b : b - NBL) * 32;
  int nrows = n - n0; if (nrows > 32) nrows = 32;
  int nflt = nrows * 44;                            // multiple of 4
  const float4* Xv = (const float4*)(X + (size_t)n0*44);
  for (int j = tid; j*4 < nflt; j += 256){
    float4 v = Xv[j];
    xs[j*4+0]=v.x; xs[j*4+1]=v.y; xs[j*4+2]=v.z; xs[j*4+3]=v.w;
  }
  __syncthreads();
  int c = tid & 127, half = tid >> 7;
  float acc[16];
  #pragma unroll
  for (int r=0;r<16;r++) acc[r]=0.f;
  const float* xrow = xs + half*16*44;
  #pragma unroll 4
  for (int k=0;k<44;k++){
    float w = Wnode[k*128 + c];
    #pragma unroll
    for (int r=0;r<16;r++) acc[r] += xrow[r*44 + k] * w;
  }
  int rbase = n0 + half*16;
  #pragma unroll
  for (int r=0;r<16;r++){
    int nn = rbase + r;
    if (nn < n) out[(size_t)nn*128 + c] = f2bf(acc[r]);
  }
}

// ---- k_prep: zeros + weight transforms + LUT (embed split out) ----
__global__ __launch_bounds__(256) void k_prep(
    unsigned* __restrict__ cntz, unsigned* __restrict__ mmaxz, unsigned* __restrict__ outz,
    const float* __restrict__ Wel, const float* __restrict__ W1, float* __restrict__ vvec,
    const float* __restrict__ W2, unsigned short* __restrict__ w2t,
    const float* __restrict__ Wm, unsigned short* __restrict__ wmt,
    const float* __restrict__ Ws, const float* __restrict__ Wn,
    unsigned short* __restrict__ wcat, unsigned short* __restrict__ w1t,
    const float* __restrict__ Wb, const float* __restrict__ bb,
    unsigned short* __restrict__ lut){
  int b = blockIdx.x, tid = threadIdx.x;
  if (b < 196){
    for (long i = (long)b*256 + tid; i < 200000; i += 196*256) cntz[i] = 0u;
  } else if (b < 324){
    mmaxz[(b-196)*256 + tid] = 0u;
  } else if (b < 580){
    outz[(b-324)*256 + tid] = 0u;
  } else if (b < 582){
    int j = (b-580)*256 + tid;
    float s = 0.f;
    #pragma unroll
    for (int r=0;r<8;r++) s += Wel[r]*W1[(256+r)*512 + j];
    vvec[j] = s;
  } else if (b < 838){
    int gid = (b-582)*256 + tid;                       // 65536
    int n = gid >> 9, k = gid & 511;
    w2t[n*512 + k] = f2bf(W2[k*128 + n]);
  } else if (b < 902){
    int gid = (b-838)*256 + tid;                       // 16384
    int n = gid >> 7, k = gid & 127;
    wmt[n*128 + k] = f2bf(Wm[k*128 + n]);
  } else if (b < 1670){
    int gid = (b-902)*256 + tid;                       // 196608
    int i = gid >> 15, rem = gid & 32767;
    int n = rem >> 8, k = rem & 255;
    float v = (k < 128) ? Ws[i*16384 + k*128 + n] : Wn[i*16384 + (k-128)*128 + n];
    wcat[gid] = f2bf(v);
  } else if (b < 2182){
    int gid = (b-1670)*256 + tid;                      // 131072
    int part = gid >> 16, rem = gid & 65535;
    int n = rem >> 7, k = rem & 127;
    w1t[gid] = f2bf(W1[(part*128 + k)*512 + n]);
  } else {
    int gid = (b-2182)*256 + tid;                      // 3145728
    int c = gid & 127, bin = (gid >> 7) & 4095, i = gid >> 19;
    float d = ((float)bin + 0.5f) * 0.001220703125f;   // *5/4096
    float s = bb[i*128 + c];
    #pragma unroll
    for (int j=0;j<8;j++){
      float a = (d - 0.7142857143f*(float)j) * 1.6f;
      s += __expf(-a*a) * Wb[i*1024 + j*128 + c];
    }
    lut[gid] = f2bf(s / (1.f + __expf(-s)));
  }
}

// ---- CSR construction ----
__global__ __launch_bounds__(256) void k_count(const int* __restrict__ esrc,
    const int* __restrict__ edst, unsigned* __restrict__ cntL, unsigned* __restrict__ cntP){
  int e = blockIdx.x*256 + threadIdx.x;
  if (e >= En) return;
  atomicAdd(&cntL[esrc[e]], 1u);
  atomicAdd(&cntP[edst[e]], 1u);
}
__global__ __launch_bounds__(256) void k_cs2(const unsigned* __restrict__ cntL,
    unsigned* __restrict__ rowptrL, unsigned* __restrict__ bsumL,
    const unsigned* __restrict__ cntP, unsigned* __restrict__ rowptrP,
    unsigned* __restrict__ bsumP){
  bool isL = blockIdx.x < 49;
  const unsigned* cnt = isL ? cntL : cntP;
  unsigned* rowptr = isL ? rowptrL : rowptrP;
  unsigned* bsum = isL ? bsumL : bsumP;
  int n = isL ? NLn : NPn;
  int lb = isL ? blockIdx.x : blockIdx.x - 49;
  __shared__ unsigned ts[256];
  int tid = threadIdx.x;
  int base = lb*1024 + tid*4;
  unsigned v[4], run = 0;
  #pragma unroll
  for (int j=0;j<4;j++){ v[j] = run; run += (base+j < n) ? cnt[base+j] : 0u; }
  ts[tid] = run; __syncthreads();
  for (int off=1; off<256; off<<=1){
    unsigned t = (tid>=off) ? ts[tid-off] : 0u; __syncthreads();
    ts[tid] += t; __syncthreads();
  }
  unsigned excl = ts[tid] - run;
  #pragma unroll
  for (int j=0;j<4;j++) if (base+j < n) rowptr[base+j] = excl + v[j];
  if (tid == 255) bsum[lb] = ts[255];
}
__global__ void k_sb2(unsigned* __restrict__ bsumL, unsigned* __restrict__ bsumP){
  unsigned* bsum = blockIdx.x ? bsumP : bsumL;
  int nc = blockIdx.x ? 147 : 49;
  __shared__ unsigned ts[256];
  int tid = threadIdx.x;
  unsigned x = (tid < nc) ? bsum[tid] : 0u;
  ts[tid] = x; __syncthreads();
  for (int off=1; off<256; off<<=1){
    unsigned t = (tid>=off) ? ts[tid-off] : 0u; __syncthreads();
    ts[tid] += t; __syncthreads();
  }
  if (tid < nc) bsum[tid] = ts[tid] - x;
}
__global__ __launch_bounds__(256) void k_ao2(
    unsigned* __restrict__ rowptrL, unsigned* __restrict__ cursorL,
    const unsigned* __restrict__ bsumL,
    unsigned* __restrict__ rowptrP, unsigned* __restrict__ cursorP,
    const unsigned* __restrict__ bsumP){
  bool isL = blockIdx.x < 196;
  unsigned* rowptr = isL ? rowptrL : rowptrP;
  unsigned* cursor = isL ? cursorL : cursorP;
  const unsigned* bsum = isL ? bsumL : bsumP;
  int n = isL ? NLn : NPn;
  int i = (isL ? blockIdx.x : blockIdx.x - 196)*256 + threadIdx.x;
  if (i < n){
    unsigned r = rowptr[i] + bsum[i>>10];
    rowptr[i] = r; cursor[i] = r;
  }
  if (i == 0) rowptr[n] = En;
}
__global__ __launch_bounds__(256) void k_place(const int* __restrict__ esrc,
    const int* __restrict__ edst, const float* __restrict__ ea,
    const int* __restrict__ lbatch, unsigned* __restrict__ curL,
    unsigned* __restrict__ curP, uint4* __restrict__ edgeL,
    int* __restrict__ idxL, int* __restrict__ idxP){
  int e = blockIdx.x*256 + threadIdx.x;
  if (e >= En) return;
  int s = esrc[e], d = edst[e];
  float dd = ea[e];
  int bin = (int)(dd * 819.2f);
  bin = (bin < 0) ? 0 : ((bin > 4095) ? 4095 : bin);
  unsigned pl = atomicAdd(&curL[s], 1u);
  uint4 er; er.x = (unsigned)s; er.y = (unsigned)d;
  er.z = __float_as_uint(dd); er.w = (unsigned)lbatch[s];
  edgeL[pl] = er;
  idxL[pl] = d | (bin << 18);
  unsigned pp = atomicAdd(&curP[d], 1u);
  idxP[pp] = s | (bin << 18);
}

// ---- fused dual-direction conv, dword (col-pair) gather ----
#define EDGE_CAP 1024
__global__ __launch_bounds__(256) void k_conv2(
    const unsigned short* __restrict__ xp_in, const unsigned short* __restrict__ xl_in,
    unsigned short* __restrict__ xp_out, unsigned short* __restrict__ xl_out,
    unsigned short* __restrict__ xp_sum, unsigned short* __restrict__ xl_sum,
    const unsigned* __restrict__ rowptrP, const int* __restrict__ idxP,
    const unsigned* __restrict__ rowptrL, const int* __restrict__ idxL,
    const unsigned short* __restrict__ lut_lp,
    const unsigned short* __restrict__ wcat_lp, const float* __restrict__ bias_lp,
    const unsigned short* __restrict__ lut_pl,
    const unsigned short* __restrict__ wcat_pl, const float* __restrict__ bias_pl,
    int first){
  __shared__ unsigned short ab[32][264];   // [m][k]: k<128 x_dst, k>=128 agg (bf16)
  __shared__ unsigned short ob[32][136];   // epilogue bf16
  __shared__ int snb[EDGE_CAP];
  __shared__ unsigned rps[33];
  int tid = threadIdx.x;
  int c2 = tid & 63, grp = tid >> 6;       // 4 groups x 64 col-pairs x 8 rows
  bool isP = blockIdx.x < NBP;
  const unsigned short* xdst_in = isP ? xp_in : xl_in;
  const unsigned short* xsrc_in = isP ? xl_in : xp_in;
  unsigned short* xout = isP ? xp_out : xl_out;
  unsigned short* xsum = isP ? xp_sum : xl_sum;
  const unsigned* rowptr = isP ? rowptrP : rowptrL;
  const int* eidx = isP ? idxP : idxL;
  const unsigned short* lut_i = isP ? lut_lp : lut_pl;
  const unsigned short* wcat = isP ? wcat_lp : wcat_pl;
  const float* bias = isP ? bias_lp : bias_pl;
  int ndst = isP ? NPn : NLn;
  int n0 = (isP ? blockIdx.x : (blockIdx.x - NBP)) * 32;

  if (tid < 33){
    int idx = n0 + tid; if (idx > ndst) idx = ndst;
    rps[tid] = rowptr[idx];
  }
  __syncthreads();
  int r00 = (int)rps[0], rEnd = (int)rps[32];
  int eblk = rEnd - r00;
  bool fits = (eblk <= EDGE_CAP);
  if (fits){
    for (int p = tid; p < eblk; p += 256) snb[p] = eidx[r00 + p];
  }
  __syncthreads();

  const unsigned short* lutc = lut_i + 2*c2;
  const unsigned short* xc = xsrc_in + 2*c2;
  for (int m = grp*8; m < grp*8+8; m++){
    int n = n0 + m;
    float al0=0.f,ah0=0.f,al1=0.f,ah1=0.f,al2=0.f,ah2=0.f,al3=0.f,ah3=0.f;
    int dg = 1;
    if (n < ndst){
      *(unsigned*)&ab[m][2*c2] = *(const unsigned*)&xdst_in[(size_t)n*128 + 2*c2];
      int r0 = (int)rps[m], r1 = (int)rps[m+1];
      dg = r1 - r0;
      int p = r0;
      for (; p + 3 < r1; p += 4){
        int v0,v1,v2,v3;
        if (fits){
          v0 = snb[p-r00]; v1 = snb[p-r00+1]; v2 = snb[p-r00+2]; v3 = snb[p-r00+3];
        } else {
          v0 = eidx[p]; v1 = eidx[p+1]; v2 = eidx[p+2]; v3 = eidx[p+3];
        }
        unsigned l0 = *(const unsigned*)&lutc[(size_t)((unsigned)v0 >> 18)*128];
        unsigned x0 = *(const unsigned*)&xc[(size_t)(v0 & 0x3FFFF)*128];
        unsigned l1 = *(const unsigned*)&lutc[(size_t)((unsigned)v1 >> 18)*128];
        unsigned x1 = *(const unsigned*)&xc[(size_t)(v1 & 0x3FFFF)*128];
        unsigned l2 = *(const unsigned*)&lutc[(size_t)((unsigned)v2 >> 18)*128];
        unsigned x2 = *(const unsigned*)&xc[(size_t)(v2 & 0x3FFFF)*128];
        unsigned l3 = *(const unsigned*)&lutc[(size_t)((unsigned)v3 >> 18)*128];
        unsigned x3 = *(const unsigned*)&xc[(size_t)(v3 & 0x3FFFF)*128];
        al0 += bflo(l0)*bflo(x0); ah0 += bfhi(l0)*bfhi(x0);
        al1 += bflo(l1)*bflo(x1); ah1 += bfhi(l1)*bfhi(x1);
        al2 += bflo(l2)*bflo(x2); ah2 += bfhi(l2)*bfhi(x2);
        al3 += bflo(l3)*bflo(x3); ah3 += bfhi(l3)*bfhi(x3);
      }
      for (; p < r1; p++){
        int v0 = fits ? snb[p-r00] : eidx[p];
        unsigned l0 = *(const unsigned*)&lutc[(size_t)((unsigned)v0 >> 18)*128];
        unsigned x0 = *(const unsigned*)&xc[(size_t)(v0 & 0x3FFFF)*128];
        al0 += bflo(l0)*bflo(x0); ah0 += bfhi(l0)*bfhi(x0);
      }
    } else {
      *(unsigned*)&ab[m][2*c2] = 0u;
    }
    float inv = 1.f / (float)(dg > 1 ? dg : 1);
    float alo = ((al0+al1)+(al2+al3)) * inv;
    float ahi = ((ah0+ah1)+(ah2+ah3)) * inv;
    *(unsigned*)&ab[m][128 + 2*c2] = (unsigned)f2bf(alo) | ((unsigned)f2bf(ahi) << 16);
  }
  __syncthreads();

  int wave = tid >> 6, lane = tid & 63, quad = lane >> 4, l15 = lane & 15;
  int mt = wave & 1, nh = wave >> 1;
  int arow = mt*16 + l15;
  float4v acc[4] = {{0,0,0,0},{0,0,0,0},{0,0,0,0},{0,0,0,0}};
  for (int k0 = 0; k0 < 256; k0 += 32){
    short8 A = *(const short8*)&ab[arow][k0 + quad*8];
    #pragma unroll
    for (int nt=0;nt<4;nt++){
      short8 B = *(const short8*)&wcat[(size_t)(nh*64 + nt*16 + l15)*256 + k0 + quad*8];
      acc[nt] = __builtin_amdgcn_mfma_f32_16x16x32_bf16(A, B, acc[nt], 0, 0, 0);
    }
  }
  #pragma unroll
  for (int nt=0;nt<4;nt++){
    int col = nh*64 + nt*16 + l15;
    float bc = bias[col];
    #pragma unroll
    for (int r=0;r<4;r++){
      int row = mt*16 + quad*4 + r;
      float v = acc[nt][r] + bc;
      ob[row][col] = f2bf((v > 0.f) ? v : 0.01f*v);    // leaky_relu
    }
  }
  __syncthreads();
  for (int m = grp*8; m < grp*8+8; m++){
    int n = n0 + m;
    if (n < ndst){
      unsigned vb = *(unsigned*)&ob[m][2*c2];
      size_t off = (size_t)n*128 + 2*c2;
      *(unsigned*)&xout[off] = vb;
      if (first){
        *(unsigned*)&xsum[off] = vb;
      } else {
        unsigned so = *(unsigned*)&xsum[off];
        float lo = bflo(so) + bflo(vb);
        float hi = bfhi(so) + bfhi(vb);
        *(unsigned*)&xsum[off] = (unsigned)f2bf(lo) | ((unsigned)f2bf(hi) << 16);
      }
    }
  }
}

// ---- merged MFMA hproj: blocks [0,NBL): ligand (+b1); [NBL,NBL+NBP): protein
__global__ __launch_bounds__(256) void k_hproj2(
    const unsigned short* __restrict__ xl_s, const unsigned short* __restrict__ xp_s,
    const unsigned short* __restrict__ w1t, const float* __restrict__ b1,
    unsigned* __restrict__ h_l, unsigned* __restrict__ h_p){
  __shared__ unsigned short hb[32][528];
  bool isL = blockIdx.x < NBL;
  const unsigned short* xs = isL ? xl_s : xp_s;
  const unsigned short* wt = isL ? w1t : w1t + 65536;
  unsigned* hout = isL ? h_l : h_p;
  int nn = isL ? NLn : NPn;
  int n0 = (isL ? blockIdx.x : blockIdx.x - NBL)*32;
  int tid = threadIdx.x;
  int wave = tid >> 6, lane = tid & 63, quad = lane >> 4, l15 = lane & 15;
  int mt = wave & 1, nh = wave >> 1;
  int an = n0 + mt*16 + l15; if (an >= nn) an = nn - 1;
  const unsigned short* aptr = xs + (size_t)an*128;
  float4v acc[16];
  #pragma unroll
  for (int i=0;i<16;i++) acc[i] = (float4v){0,0,0,0};
  for (int k0 = 0; k0 < 128; k0 += 32){
    short8 A = *(const short8*)&aptr[k0 + quad*8];
    #pragma unroll
    for (int nt=0;nt<16;nt++){
      short8 B = *(const short8*)&wt[(size_t)(nh*256 + nt*16 + l15)*128 + k0 + quad*8];
      acc[nt] = __builtin_amdgcn_mfma_f32_16x16x32_bf16(A, B, acc[nt], 0, 0, 0);
    }
  }
  #pragma unroll
  for (int nt=0;nt<16;nt++){
    int col = nh*256 + nt*16 + l15;
    float bv = isL ? b1[col] : 0.f;
    #pragma unroll
    for (int r=0;r<4;r++) hb[mt*16 + quad*4 + r][col] = f2bf(acc[nt][r] + bv);
  }
  __syncthreads();
  for (int m=0;m<32;m++){
    int n = n0 + m;
    if (n < nn){
      unsigned pack = (unsigned)hb[m][2*tid] | ((unsigned)hb[m][2*tid+1] << 16);
      hout[(size_t)n*256 + tid] = pack;
    }
  }
}

// ---- readout v10: persistent + reg-resident B + cross-tile pipeline. ----
__global__ __launch_bounds__(512) void k_readout4(
    const unsigned* __restrict__ hl, const unsigned* __restrict__ hp,
    const uint4* __restrict__ edgeL, const float* __restrict__ vvec,
    const unsigned short* __restrict__ w2t, const float* __restrict__ b2,
    const unsigned short* __restrict__ wmt, const float* __restrict__ bm,
    float* __restrict__ outw, unsigned* __restrict__ mmax){
  __shared__ __align__(16) unsigned short lds[37120];   // 2x16384 hbuf + msb
  unsigned short (*msb)[136] = (unsigned short(*)[136])(lds + 32768);
  int tid = threadIdx.x, lane = tid & 63, wave = tid >> 6;
  int quad = lane >> 4, l15 = lane & 15;
  int ns = wave*16;                // this wave's N-strip for both GEMMs

  // XCD-chunked tile mapping
  int wg = (blockIdx.x & 7)*128 + (blockIdx.x >> 3);   // bijective [0,1024)
  int nt_tot = En/32;
  int t0 = wg*16;
  int t1 = t0 + 16; if (t1 > nt_tot) t1 = nt_tot;
  if (t0 >= t1) return;

  // ---- register-resident B: w2t strip (64 VGPR) + wmt strip (16 VGPR) ----
  short8 Bk[16];
  #pragma unroll
  for (int kk=0;kk<16;kk++)
    Bk[kk] = *(const short8*)&w2t[(size_t)(ns + l15)*512 + kk*32 + quad*8];
  short8 Bm[4];
  #pragma unroll
  for (int kk=0;kk<4;kk++)
    Bm[kk] = *(const short8*)&wmt[(size_t)(ns + l15)*128 + kk*32 + quad*8];
  float b2c0 = b2[ns + l15];
  float bm0  = bm[ns + l15];

  // vvec for chunk `lane`: h columns [8*lane, 8*lane+8)
  float4v vva = *(const float4v*)&vvec[lane*8];
  float4v vvb = *(const float4v*)&vvec[lane*8 + 4];
  int sw = lane & 31;
  const uint4* hl4 = (const uint4*)hl;   // one h row = 64 uint4
  const uint4* hp4 = (const uint4*)hp;
  const unsigned* e32 = (const unsigned*)edgeL;

  int si_prev = -1;
  uint4 ua = {0,0,0,0};
  int lm = wave*16 + (lane & 15);        // metadata dword index for this wave
  int le = lane & 31;                    // epilogue edge index

  #define H_EDGE(UA, UB, DD, I, WB)                                          \
    {                                                                        \
      unsigned o0,o1,o2,o3; float hx,hy;                                     \
      hx = fmaxf(bflo(UA.x)+bflo(UB.x)+(DD)*vva.x, 0.f);                     \
      hy = fmaxf(bfhi(UA.x)+bfhi(UB.x)+(DD)*vva.y, 0.f);                     \
      o0 = (unsigned)f2bf(hx) | ((unsigned)f2bf(hy) << 16);                  \
      hx = fmaxf(bflo(UA.y)+bflo(UB.y)+(DD)*vva.z, 0.f);                     \
      hy = fmaxf(bfhi(UA.y)+bfhi(UB.y)+(DD)*vva.w, 0.f);                     \
      o1 = (unsigned)f2bf(hx) | ((unsigned)f2bf(hy) << 16);                  \
      hx = fmaxf(bflo(UA.z)+bflo(UB.z)+(DD)*vvb.x, 0.f);                     \
      hy = fmaxf(bfhi(UA.z)+bfhi(UB.z)+(DD)*vvb.y, 0.f);                     \
      o2 = (unsigned)f2bf(hx) | ((unsigned)f2bf(hy) << 16);                  \
      hx = fmaxf(bflo(UA.w)+bflo(UB.w)+(DD)*vvb.z, 0.f);                     \
      hy = fmaxf(bfhi(UA.w)+bfhi(UB.w)+(DD)*vvb.w, 0.f);                     \
      o3 = (unsigned)f2bf(hx) | ((unsigned)f2bf(hy) << 16);                  \
      uint4 ov; ov.x=o0; ov.y=o1; ov.z=o2; ov.w=o3;                          \
      *(uint4*)&lds[(WB) + lane*256 + (((I) ^ sw) << 3)] = ov;               \
    }

  // ---- prologue: tile t0 -> hbuf0; load md1/br1 for t0+1 ----
  unsigned md1 = 0; int br_cur = 0, br1 = 0;
  {
    unsigned md0 = e32[(size_t)t0*128 + lm];
    br_cur = (int)e32[((size_t)(t0*32 + le))*4 + 3];
    #pragma unroll
    for (int ii=0; ii<4; ii++){
      int si = __builtin_amdgcn_readfirstlane(__shfl((int)md0, ii*4));
      int di = __builtin_amdgcn_readfirstlane(__shfl((int)md0, ii*4 + 1));
      float dd = __uint_as_float((unsigned)__builtin_amdgcn_readfirstlane(__shfl((int)md0, ii*4 + 2)));
      if (si != si_prev){ ua = hl4[(size_t)si*64 + lane]; si_prev = si; }
      uint4 ub = hp4[(size_t)di*64 + lane];
      H_EDGE(ua, ub, dd, wave*4 + ii, 0)
    }
    if (t0 + 1 < t1){
      md1 = e32[(size_t)(t0+1)*128 + lm];
      br1 = (int)e32[((size_t)((t0+1)*32 + le))*4 + 3];
    }
    __syncthreads();
  }

  int cur = 0;
  unsigned md2 = md1; int br2 = br1;
  for (int t = t0; t < t1; ++t){
    bool pf = (t + 1 < t1);
    // issue next-next metadata
    if (t + 2 < t1){
      md2 = e32[(size_t)(t+2)*128 + lm];
      br2 = (int)e32[((size_t)((t+2)*32 + le))*4 + 3];
    }
    // issue hp gathers + deduped hl for tile t+1 (consumed after GEMM2)
    uint4 ub0, ub1, ub2, ub3;
    if (pf){
      int d0 = __builtin_amdgcn_readfirstlane(__shfl((int)md1, 1));
      int d1 = __builtin_amdgcn_readfirstlane(__shfl((int)md1, 5));
      int d2 = __builtin_amdgcn_readfirstlane(__shfl((int)md1, 9));
      int d3 = __builtin_amdgcn_readfirstlane(__shfl((int)md1, 13));
      ub0 = hp4[(size_t)d0*64 + lane];
      ub1 = hp4[(size_t)d1*64 + lane];
      ub2 = hp4[(size_t)d2*64 + lane];
      ub3 = hp4[(size_t)d3*64 + lane];
      int s0 = __builtin_amdgcn_readfirstlane(__shfl((int)md1, 0));
      if (s0 != si_prev){ ua = hl4[(size_t)s0*64 + lane]; si_prev = s0; }
    }

    int rb = cur ? 16384 : 0;
    // GEMM1: m[32,128] = h[32,512] @ W2^T + b2  (B from registers)
    float4v acc[2] = {{0,0,0,0},{0,0,0,0}};
    #pragma unroll
    for (int kk = 0; kk < 16; kk++){
      int kcc = kk*4 + quad;
      int sw2 = kcc & 31;
      short8 A0 = *(const short8*)&lds[rb + kcc*256 + ((l15 ^ sw2) << 3)];
      short8 A1 = *(const short8*)&lds[rb + kcc*256 + (((16 + l15) ^ sw2) << 3)];
      acc[0] = __builtin_amdgcn_mfma_f32_16x16x32_bf16(A0, Bk[kk], acc[0], 0, 0, 0);
      acc[1] = __builtin_amdgcn_mfma_f32_16x16x32_bf16(A1, Bk[kk], acc[1], 0, 0, 0);
    }
    float mreg[2][4];
    #pragma unroll
    for (int mt=0;mt<2;mt++){
      int col = ns + l15;
      #pragma unroll
      for (int r=0;r<4;r++){
        float mv = acc[mt][r] + b2c0;
        mreg[mt][r] = mv;
        msb[mt*16 + quad*4 + r][col] = f2bf(mv);
      }
    }
    __syncthreads();    // barrier A: msb visible

    // GEMM2: t = tanh(m@Wm^T + bm); flush sum(t*m), max(m) per batch
    float4v acc2[2] = {{0,0,0,0},{0,0,0,0}};
    #pragma unroll
    for (int kk = 0; kk < 4; kk++){
      short8 A0 = *(const short8*)&msb[l15][kk*32 + quad*8];
      short8 A1 = *(const short8*)&msb[16 + l15][kk*32 + quad*8];
      acc2[0] = __builtin_amdgcn_mfma_f32_16x16x32_bf16(A0, Bm[kk], acc2[0], 0, 0, 0);
      acc2[1] = __builtin_amdgcn_mfma_f32_16x16x32_bf16(A1, Bm[kk], acc2[1], 0, 0, 0);
    }
    {
      int b0 = __shfl(br_cur, 0);
      bool uni = (b0 == __shfl(br_cur, 31));
      int col = ns + l15;
      if (uni){
        float s = 0.f, mx = -3.402823466e38f;
        #pragma unroll
        for (int mt=0;mt<2;mt++){
          #pragma unroll
          for (int r=0;r<4;r++){
            float mv = mreg[mt][r];
            float tt = tanh_fast(acc2[mt][r] + bm0);
            s += tt*mv; mx = fmaxf(mx, mv);
          }
        }
        s += __shfl_xor(s, 16); s += __shfl_xor(s, 32);
        mx = fmaxf(mx, __shfl_xor(mx, 16)); mx = fmaxf(mx, __shfl_xor(mx, 32));
        if (quad == 0){
          atomicAdd(&outw[b0*256 + col], s);
          atomicMax(&mmax[b0*128 + col], encf(mx));
        }
      } else {
        #pragma unroll
        for (int mt=0;mt<2;mt++){
          #pragma unroll
          for (int r=0;r<4;r++){
            int row = mt*16 + quad*4 + r;
            int b = __shfl(br_cur, row);
            float mv = mreg[mt][r];
            float tt = tanh_fast(acc2[mt][r] + bm0);
            atomicAdd(&outw[b*256 + col], tt*mv);
            atomicMax(&mmax[b*128 + col], encf(mv));
          }
        }
      }
    }

    // consume prefetched gathers -> h(t+1) into the other hbuf
    if (pf){
      int wb = cur ? 0 : 16384;
      #pragma unroll
      for (int ii=0; ii<4; ii++){
        int si = __builtin_amdgcn_readfirstlane(__shfl((int)md1, ii*4));
        float dd = __uint_as_float((unsigned)__builtin_amdgcn_readfirstlane(__shfl((int)md1, ii*4 + 2)));
        if (si != si_prev){ ua = hl4[(size_t)si*64 + lane]; si_prev = si; }
        uint4 ub = (ii==0) ? ub0 : (ii==1) ? ub1 : (ii==2) ? ub2 : ub3;
        H_EDGE(ua, ub, dd, wave*4 + ii, wb)
      }
    }
    __syncthreads();    // barrier B: hbuf[cur^1] + msb reads complete

    md1 = md2; br_cur = br1; br1 = br2;
    cur ^= 1;
  }
  #undef H_EDGE
}

__global__ __launch_bounds__(256) void k_final(const unsigned* __restrict__ mmax,
    float* __restrict__ out){
  int gid = blockIdx.x*256 + threadIdx.x;   // 32768 = 256*128
  unsigned enc = mmax[gid];
  float v;
  if (enc == 0u) v = 0.f;
  else if (enc & 0x80000000u) v = __uint_as_float(enc & 0x7FFFFFFFu);
  else v = __uint_as_float(~enc);
  int g = gid >> 7, cc = gid & 127;
  out[g*256 + 128 + cc] = v;
}

extern "C" void kernel_launch(void* const* d_in, const int* in_sizes, int n_in,
                              void* d_out, int out_size, void* d_ws, size_t ws_size,
                              hipStream_t stream) {
  const float* x_l    = (const float*)d_in[0];
  const float* x_p    = (const float*)d_in[1];
  const float* ea     = (const float*)d_in[2];
  const int*   esrc   = (const int*)d_in[3];
  const int*   edst   = (const int*)d_in[4];
  const int*   lbatch = (const int*)d_in[5];
  const float* W_node = (const float*)d_in[6];
  const float* W_el   = (const float*)d_in[7];
  const float* Wb     = (const float*)d_in[8];
  const float* bb     = (const float*)d_in[9];
  const float* Wn     = (const float*)d_in[10];
  const float* Ws     = (const float*)d_in[11];
  const float* bconv  = (const float*)d_in[12];
  const float* W1     = (const float*)d_in[13];
  const float* b1     = (const float*)d_in[14];
  const float* W2     = (const float*)d_in[15];
  const float* b2     = (const float*)d_in[16];
  const float* Wm     = (const float*)d_in[17];
  const float* bm     = (const float*)d_in[18];

  // ---- workspace layout (decimal offsets), peak 267,354,496 B ----
  char* w = (char*)d_ws;
  unsigned short* xl0 = (unsigned short*)(w + 0);
  unsigned short* xl1 = (unsigned short*)(w + 12800000);
  unsigned short* xp0 = (unsigned short*)(w + 25600000);
  unsigned short* xp1 = (unsigned short*)(w + 64000000);
  int*      idxP  = (int*)(w + 102400000);
  int*      idxL  = (int*)(w + 104400000);
  unsigned short* lut = (unsigned short*)(w + 106400000);   // 6.29e6 B
  unsigned* h_l   = (unsigned*)(w + 0);
  unsigned* h_p   = (unsigned*)(w + 51200000);
  unsigned short* xl_s = (unsigned short*)(w + 204800000);
  unsigned short* xp_s = (unsigned short*)(w + 217600000);
  unsigned short* wcat = (unsigned short*)(w + 256000000);
  unsigned short* w1t  = (unsigned short*)(w + 256393216);
  unsigned short* w2t  = (unsigned short*)(w + 256655360);
  unsigned short* wmt  = (unsigned short*)(w + 256786432);
  float*    vvec  = (float*)(w + 256819200);
  unsigned* mmax  = (unsigned*)(w + 256821248);
  unsigned* bsumL = (unsigned*)(w + 256952320);
  unsigned* bsumP = (unsigned*)(w + 256953344);
  unsigned* rowptrL = (unsigned*)(w + 256954368);
  unsigned* cursorL = (unsigned*)(w + 257154432);
  unsigned* rowptrP = (unsigned*)(w + 257354432);
  unsigned* cursorP = (unsigned*)(w + 257954496);
  unsigned* cntL    = (unsigned*)(w + 258554496);
  unsigned* cntP    = (unsigned*)(w + 258754496);
  uint4*    edgeL   = (uint4*)(w + 259354496);   // {src, dst, bits(d), batch}

  float* out = (float*)d_out;

  k_prep<<<14470, 256, 0, stream>>>(
      (unsigned*)(w + 258554496), mmax, (unsigned*)d_out,
      W_el, W1, vvec, W2, w2t, Wm, wmt, Ws, Wn, wcat, w1t, Wb, bb, lut);
  k_embed<<<NBL + NBP, 256, 0, stream>>>(x_l, x_p, W_node, xl0, xp0);

  k_count<<<1954, 256, 0, stream>>>(esrc, edst, cntL, cntP);
  k_cs2<<<196, 256, 0, stream>>>(cntL, rowptrL, bsumL, cntP, rowptrP, bsumP);
  k_sb2<<<2, 256, 0, stream>>>(bsumL, bsumP);
  k_ao2<<<782, 256, 0, stream>>>(rowptrL, cursorL, bsumL, rowptrP, cursorP, bsumP);
  k_place<<<1954, 256, 0, stream>>>(esrc, edst, ea, lbatch, cursorL, cursorP,
                                    edgeL, idxL, idxP);

  unsigned short *xlc = xl0, *xln = xl1, *xpc = xp0, *xpn = xp1;
  for (int l = 0; l < 3; ++l){
    int ilp = 2*l, ipl = 2*l + 1;
    k_conv2<<<NBP + NBL, 256, 0, stream>>>(
        xpc, xlc, xpn, xln, xp_s, xl_s,
        rowptrP, idxP, rowptrL, idxL,
        lut + (size_t)ilp*524288, wcat + ilp*32768, bconv + ilp*128,
        lut + (size_t)ipl*524288, wcat + ipl*32768, bconv + ipl*128,
        (l == 0) ? 1 : 0);
    unsigned short* t;
    t = xlc; xlc = xln; xln = t;
    t = xpc; xpc = xpn; xpn = t;
  }

  // b1 folded into h_l (ligand part); protein part no bias
  k_hproj2<<<NBL + NBP, 256, 0, stream>>>(xl_s, xp_s, w1t, b1, h_l, h_p);

  k_readout4<<<1024, 512, 0, stream>>>(h_l, h_p, edgeL, vvec,
                                       w2t, b2, wmt, bm, out, mmax);
  k_final<<<128, 256, 0, stream>>>(mmax, out);
}

// Round 9
// 1243.495 us; speedup vs baseline: 1.4562x; 1.0351x over previous
//
#include <hip/hip_runtime.h>
#include <hip/hip_bf16.h>

// HeteroNet on MI355X — round 21.
// R20 (dword col-pair gather) 1503->1287us; conv2 out of top-5 (~185/launch
// est). Aggregate conv2 x3 still ~550us > readout 265. conv2 is gather-
// latency bound (L3-random, ~600cy) with 8-row serial chains and 20 waves/CU.
// R21: conv2 at 512 threads — (8 groups x 64 col-pairs x 4 rows): serial
// chain halved, 4 blocks/CU x 8 waves = 32 waves/CU (vs 20). MFMA phase
// remapped to 8 waves (2 nt-tiles each). All else unchanged.

#define NLn 50000
#define NPn 150000
#define En  500000
#define NBL 1563   // ceil(NLn/32)
#define NBP 4688   // ceil(NPn/32)

typedef __attribute__((ext_vector_type(8))) short short8;
typedef __attribute__((ext_vector_type(4))) float float4v;

__device__ __forceinline__ float bf2f(unsigned short u){ return __uint_as_float(((unsigned)u) << 16); }
__device__ __forceinline__ float bflo(unsigned u){ return __uint_as_float(u << 16); }
__device__ __forceinline__ float bfhi(unsigned u){ return __uint_as_float(u & 0xffff0000u); }
__device__ __forceinline__ unsigned short f2bf(float f){
  __hip_bfloat16 h = __float2bfloat16(f);
  return *reinterpret_cast<unsigned short*>(&h);
}
// order-preserving float->uint; enc(v)>0 for all finite v, so 0 == "empty segment"
__device__ __forceinline__ unsigned encf(float f){
  unsigned u = __float_as_uint(f);
  return (u & 0x80000000u) ? ~u : (u | 0x80000000u);
}
__device__ __forceinline__ float tanh_fast(float x){
  return 1.f - 2.f/(__expf(2.f*x) + 1.f);
}

// ---- k_embed: X @ W_node -> bf16, 32 rows/block, register-tiled ----
__global__ __launch_bounds__(256) void k_embed(
    const float* __restrict__ Xl, const float* __restrict__ Xp,
    const float* __restrict__ Wnode,
    unsigned short* __restrict__ xl0, unsigned short* __restrict__ xp0){
  __shared__ float xs[1408];   // 32 rows x 44 fp32
  int b = blockIdx.x, tid = threadIdx.x;
  bool isL = b < NBL;
  const float* X = isL ? Xl : Xp;
  unsigned short* out = isL ? xl0 : xp0;
  int n = isL ? NLn : NPn;
  int n0 = (isL ? b : b - NBL) * 32;
  int nrows = n - n0; if (nrows > 32) nrows = 32;
  int nflt = nrows * 44;                            // multiple of 4
  const float4* Xv = (const float4*)(X + (size_t)n0*44);
  for (int j = tid; j*4 < nflt; j += 256){
    float4 v = Xv[j];
    xs[j*4+0]=v.x; xs[j*4+1]=v.y; xs[j*4+2]=v.z; xs[j*4+3]=v.w;
  }
  __syncthreads();
  int c = tid & 127, half = tid >> 7;
  float acc[16];
  #pragma unroll
  for (int r=0;r<16;r++) acc[r]=0.f;
  const float* xrow = xs + half*16*44;
  #pragma unroll 4
  for (int k=0;k<44;k++){
    float w = Wnode[k*128 + c];
    #pragma unroll
    for (int r=0;r<16;r++) acc[r] += xrow[r*44 + k] * w;
  }
  int rbase = n0 + half*16;
  #pragma unroll
  for (int r=0;r<16;r++){
    int nn = rbase + r;
    if (nn < n) out[(size_t)nn*128 + c] = f2bf(acc[r]);
  }
}

// ---- k_prep: zeros + weight transforms + LUT (embed split out) ----
__global__ __launch_bounds__(256) void k_prep(
    unsigned* __restrict__ cntz, unsigned* __restrict__ mmaxz, unsigned* __restrict__ outz,
    const float* __restrict__ Wel, const float* __restrict__ W1, float* __restrict__ vvec,
    const float* __restrict__ W2, unsigned short* __restrict__ w2t,
    const float* __restrict__ Wm, unsigned short* __restrict__ wmt,
    const float* __restrict__ Ws, const float* __restrict__ Wn,
    unsigned short* __restrict__ wcat, unsigned short* __restrict__ w1t,
    const float* __restrict__ Wb, const float* __restrict__ bb,
    unsigned short* __restrict__ lut){
  int b = blockIdx.x, tid = threadIdx.x;
  if (b < 196){
    for (long i = (long)b*256 + tid; i < 200000; i += 196*256) cntz[i] = 0u;
  } else if (b < 324){
    mmaxz[(b-196)*256 + tid] = 0u;
  } else if (b < 580){
    outz[(b-324)*256 + tid] = 0u;
  } else if (b < 582){
    int j = (b-580)*256 + tid;
    float s = 0.f;
    #pragma unroll
    for (int r=0;r<8;r++) s += Wel[r]*W1[(256+r)*512 + j];
    vvec[j] = s;
  } else if (b < 838){
    int gid = (b-582)*256 + tid;                       // 65536
    int n = gid >> 9, k = gid & 511;
    w2t[n*512 + k] = f2bf(W2[k*128 + n]);
  } else if (b < 902){
    int gid = (b-838)*256 + tid;                       // 16384
    int n = gid >> 7, k = gid & 127;
    wmt[n*128 + k] = f2bf(Wm[k*128 + n]);
  } else if (b < 1670){
    int gid = (b-902)*256 + tid;                       // 196608
    int i = gid >> 15, rem = gid & 32767;
    int n = rem >> 8, k = rem & 255;
    float v = (k < 128) ? Ws[i*16384 + k*128 + n] : Wn[i*16384 + (k-128)*128 + n];
    wcat[gid] = f2bf(v);
  } else if (b < 2182){
    int gid = (b-1670)*256 + tid;                      // 131072
    int part = gid >> 16, rem = gid & 65535;
    int n = rem >> 7, k = rem & 127;
    w1t[gid] = f2bf(W1[(part*128 + k)*512 + n]);
  } else {
    int gid = (b-2182)*256 + tid;                      // 3145728
    int c = gid & 127, bin = (gid >> 7) & 4095, i = gid >> 19;
    float d = ((float)bin + 0.5f) * 0.001220703125f;   // *5/4096
    float s = bb[i*128 + c];
    #pragma unroll
    for (int j=0;j<8;j++){
      float a = (d - 0.7142857143f*(float)j) * 1.6f;
      s += __expf(-a*a) * Wb[i*1024 + j*128 + c];
    }
    lut[gid] = f2bf(s / (1.f + __expf(-s)));
  }
}

// ---- CSR construction ----
__global__ __launch_bounds__(256) void k_count(const int* __restrict__ esrc,
    const int* __restrict__ edst, unsigned* __restrict__ cntL, unsigned* __restrict__ cntP){
  int e = blockIdx.x*256 + threadIdx.x;
  if (e >= En) return;
  atomicAdd(&cntL[esrc[e]], 1u);
  atomicAdd(&cntP[edst[e]], 1u);
}
__global__ __launch_bounds__(256) void k_cs2(const unsigned* __restrict__ cntL,
    unsigned* __restrict__ rowptrL, unsigned* __restrict__ bsumL,
    const unsigned* __restrict__ cntP, unsigned* __restrict__ rowptrP,
    unsigned* __restrict__ bsumP){
  bool isL = blockIdx.x < 49;
  const unsigned* cnt = isL ? cntL : cntP;
  unsigned* rowptr = isL ? rowptrL : rowptrP;
  unsigned* bsum = isL ? bsumL : bsumP;
  int n = isL ? NLn : NPn;
  int lb = isL ? blockIdx.x : blockIdx.x - 49;
  __shared__ unsigned ts[256];
  int tid = threadIdx.x;
  int base = lb*1024 + tid*4;
  unsigned v[4], run = 0;
  #pragma unroll
  for (int j=0;j<4;j++){ v[j] = run; run += (base+j < n) ? cnt[base+j] : 0u; }
  ts[tid] = run; __syncthreads();
  for (int off=1; off<256; off<<=1){
    unsigned t = (tid>=off) ? ts[tid-off] : 0u; __syncthreads();
    ts[tid] += t; __syncthreads();
  }
  unsigned excl = ts[tid] - run;
  #pragma unroll
  for (int j=0;j<4;j++) if (base+j < n) rowptr[base+j] = excl + v[j];
  if (tid == 255) bsum[lb] = ts[255];
}
__global__ void k_sb2(unsigned* __restrict__ bsumL, unsigned* __restrict__ bsumP){
  unsigned* bsum = blockIdx.x ? bsumP : bsumL;
  int nc = blockIdx.x ? 147 : 49;
  __shared__ unsigned ts[256];
  int tid = threadIdx.x;
  unsigned x = (tid < nc) ? bsum[tid] : 0u;
  ts[tid] = x; __syncthreads();
  for (int off=1; off<256; off<<=1){
    unsigned t = (tid>=off) ? ts[tid-off] : 0u; __syncthreads();
    ts[tid] += t; __syncthreads();
  }
  if (tid < nc) bsum[tid] = ts[tid] - x;
}
__global__ __launch_bounds__(256) void k_ao2(
    unsigned* __restrict__ rowptrL, unsigned* __restrict__ cursorL,
    const unsigned* __restrict__ bsumL,
    unsigned* __restrict__ rowptrP, unsigned* __restrict__ cursorP,
    const unsigned* __restrict__ bsumP){
  bool isL = blockIdx.x < 196;
  unsigned* rowptr = isL ? rowptrL : rowptrP;
  unsigned* cursor = isL ? cursorL : cursorP;
  const unsigned* bsum = isL ? bsumL : bsumP;
  int n = isL ? NLn : NPn;
  int i = (isL ? blockIdx.x : blockIdx.x - 196)*256 + threadIdx.x;
  if (i < n){
    unsigned r = rowptr[i] + bsum[i>>10];
    rowptr[i] = r; cursor[i] = r;
  }
  if (i == 0) rowptr[n] = En;
}
__global__ __launch_bounds__(256) void k_place(const int* __restrict__ esrc,
    const int* __restrict__ edst, const float* __restrict__ ea,
    const int* __restrict__ lbatch, unsigned* __restrict__ curL,
    unsigned* __restrict__ curP, uint4* __restrict__ edgeL,
    int* __restrict__ idxL, int* __restrict__ idxP){
  int e = blockIdx.x*256 + threadIdx.x;
  if (e >= En) return;
  int s = esrc[e], d = edst[e];
  float dd = ea[e];
  int bin = (int)(dd * 819.2f);
  bin = (bin < 0) ? 0 : ((bin > 4095) ? 4095 : bin);
  unsigned pl = atomicAdd(&curL[s], 1u);
  uint4 er; er.x = (unsigned)s; er.y = (unsigned)d;
  er.z = __float_as_uint(dd); er.w = (unsigned)lbatch[s];
  edgeL[pl] = er;
  idxL[pl] = d | (bin << 18);
  unsigned pp = atomicAdd(&curP[d], 1u);
  idxP[pp] = s | (bin << 18);
}

// ---- fused dual-direction conv, dword gather, 512 threads ----
#define EDGE_CAP 1024
__global__ __launch_bounds__(512) void k_conv2(
    const unsigned short* __restrict__ xp_in, const unsigned short* __restrict__ xl_in,
    unsigned short* __restrict__ xp_out, unsigned short* __restrict__ xl_out,
    unsigned short* __restrict__ xp_sum, unsigned short* __restrict__ xl_sum,
    const unsigned* __restrict__ rowptrP, const int* __restrict__ idxP,
    const unsigned* __restrict__ rowptrL, const int* __restrict__ idxL,
    const unsigned short* __restrict__ lut_lp,
    const unsigned short* __restrict__ wcat_lp, const float* __restrict__ bias_lp,
    const unsigned short* __restrict__ lut_pl,
    const unsigned short* __restrict__ wcat_pl, const float* __restrict__ bias_pl,
    int first){
  __shared__ unsigned short ab[32][264];   // [m][k]: k<128 x_dst, k>=128 agg (bf16)
  __shared__ unsigned short ob[32][136];   // epilogue bf16
  __shared__ int snb[EDGE_CAP];
  __shared__ unsigned rps[33];
  int tid = threadIdx.x;
  int c2 = tid & 63, grp = tid >> 6;       // 8 groups x 64 col-pairs x 4 rows
  bool isP = blockIdx.x < NBP;
  const unsigned short* xdst_in = isP ? xp_in : xl_in;
  const unsigned short* xsrc_in = isP ? xl_in : xp_in;
  unsigned short* xout = isP ? xp_out : xl_out;
  unsigned short* xsum = isP ? xp_sum : xl_sum;
  const unsigned* rowptr = isP ? rowptrP : rowptrL;
  const int* eidx = isP ? idxP : idxL;
  const unsigned short* lut_i = isP ? lut_lp : lut_pl;
  const unsigned short* wcat = isP ? wcat_lp : wcat_pl;
  const float* bias = isP ? bias_lp : bias_pl;
  int ndst = isP ? NPn : NLn;
  int n0 = (isP ? blockIdx.x : (blockIdx.x - NBP)) * 32;

  if (tid < 33){
    int idx = n0 + tid; if (idx > ndst) idx = ndst;
    rps[tid] = rowptr[idx];
  }
  __syncthreads();
  int r00 = (int)rps[0], rEnd = (int)rps[32];
  int eblk = rEnd - r00;
  bool fits = (eblk <= EDGE_CAP);
  if (fits){
    for (int p = tid; p < eblk; p += 512) snb[p] = eidx[r00 + p];
  }
  __syncthreads();

  const unsigned short* lutc = lut_i + 2*c2;
  const unsigned short* xc = xsrc_in + 2*c2;
  for (int m = grp*4; m < grp*4+4; m++){
    int n = n0 + m;
    float al0=0.f,ah0=0.f,al1=0.f,ah1=0.f,al2=0.f,ah2=0.f,al3=0.f,ah3=0.f;
    int dg = 1;
    if (n < ndst){
      *(unsigned*)&ab[m][2*c2] = *(const unsigned*)&xdst_in[(size_t)n*128 + 2*c2];
      int r0 = (int)rps[m], r1 = (int)rps[m+1];
      dg = r1 - r0;
      int p = r0;
      for (; p + 3 < r1; p += 4){
        int v0,v1,v2,v3;
        if (fits){
          v0 = snb[p-r00]; v1 = snb[p-r00+1]; v2 = snb[p-r00+2]; v3 = snb[p-r00+3];
        } else {
          v0 = eidx[p]; v1 = eidx[p+1]; v2 = eidx[p+2]; v3 = eidx[p+3];
        }
        unsigned l0 = *(const unsigned*)&lutc[(size_t)((unsigned)v0 >> 18)*128];
        unsigned x0 = *(const unsigned*)&xc[(size_t)(v0 & 0x3FFFF)*128];
        unsigned l1 = *(const unsigned*)&lutc[(size_t)((unsigned)v1 >> 18)*128];
        unsigned x1 = *(const unsigned*)&xc[(size_t)(v1 & 0x3FFFF)*128];
        unsigned l2 = *(const unsigned*)&lutc[(size_t)((unsigned)v2 >> 18)*128];
        unsigned x2 = *(const unsigned*)&xc[(size_t)(v2 & 0x3FFFF)*128];
        unsigned l3 = *(const unsigned*)&lutc[(size_t)((unsigned)v3 >> 18)*128];
        unsigned x3 = *(const unsigned*)&xc[(size_t)(v3 & 0x3FFFF)*128];
        al0 += bflo(l0)*bflo(x0); ah0 += bfhi(l0)*bfhi(x0);
        al1 += bflo(l1)*bflo(x1); ah1 += bfhi(l1)*bfhi(x1);
        al2 += bflo(l2)*bflo(x2); ah2 += bfhi(l2)*bfhi(x2);
        al3 += bflo(l3)*bflo(x3); ah3 += bfhi(l3)*bfhi(x3);
      }
      for (; p < r1; p++){
        int v0 = fits ? snb[p-r00] : eidx[p];
        unsigned l0 = *(const unsigned*)&lutc[(size_t)((unsigned)v0 >> 18)*128];
        unsigned x0 = *(const unsigned*)&xc[(size_t)(v0 & 0x3FFFF)*128];
        al0 += bflo(l0)*bflo(x0); ah0 += bfhi(l0)*bfhi(x0);
      }
    } else {
      *(unsigned*)&ab[m][2*c2] = 0u;
    }
    float inv = 1.f / (float)(dg > 1 ? dg : 1);
    float alo = ((al0+al1)+(al2+al3)) * inv;
    float ahi = ((ah0+ah1)+(ah2+ah3)) * inv;
    *(unsigned*)&ab[m][128 + 2*c2] = (unsigned)f2bf(alo) | ((unsigned)f2bf(ahi) << 16);
  }
  __syncthreads();

  int wave = tid >> 6, lane = tid & 63, quad = lane >> 4, l15 = lane & 15;
  int mt = wave & 1, nh = wave >> 1;       // nh in [0,4)
  int arow = mt*16 + l15;
  float4v acc[2] = {{0,0,0,0},{0,0,0,0}};
  for (int k0 = 0; k0 < 256; k0 += 32){
    short8 A = *(const short8*)&ab[arow][k0 + quad*8];
    #pragma unroll
    for (int nt=0;nt<2;nt++){
      short8 B = *(const short8*)&wcat[(size_t)(nh*32 + nt*16 + l15)*256 + k0 + quad*8];
      acc[nt] = __builtin_amdgcn_mfma_f32_16x16x32_bf16(A, B, acc[nt], 0, 0, 0);
    }
  }
  #pragma unroll
  for (int nt=0;nt<2;nt++){
    int col = nh*32 + nt*16 + l15;
    float bc = bias[col];
    #pragma unroll
    for (int r=0;r<4;r++){
      int row = mt*16 + quad*4 + r;
      float v = acc[nt][r] + bc;
      ob[row][col] = f2bf((v > 0.f) ? v : 0.01f*v);    // leaky_relu
    }
  }
  __syncthreads();
  for (int m = grp*4; m < grp*4+4; m++){
    int n = n0 + m;
    if (n < ndst){
      unsigned vb = *(unsigned*)&ob[m][2*c2];
      size_t off = (size_t)n*128 + 2*c2;
      *(unsigned*)&xout[off] = vb;
      if (first){
        *(unsigned*)&xsum[off] = vb;
      } else {
        unsigned so = *(unsigned*)&xsum[off];
        float lo = bflo(so) + bflo(vb);
        float hi = bfhi(so) + bfhi(vb);
        *(unsigned*)&xsum[off] = (unsigned)f2bf(lo) | ((unsigned)f2bf(hi) << 16);
      }
    }
  }
}

// ---- merged MFMA hproj: blocks [0,NBL): ligand (+b1); [NBL,NBL+NBP): protein
__global__ __launch_bounds__(256) void k_hproj2(
    const unsigned short* __restrict__ xl_s, const unsigned short* __restrict__ xp_s,
    const unsigned short* __restrict__ w1t, const float* __restrict__ b1,
    unsigned* __restrict__ h_l, unsigned* __restrict__ h_p){
  __shared__ unsigned short hb[32][528];
  bool isL = blockIdx.x < NBL;
  const unsigned short* xs = isL ? xl_s : xp_s;
  const unsigned short* wt = isL ? w1t : w1t + 65536;
  unsigned* hout = isL ? h_l : h_p;
  int nn = isL ? NLn : NPn;
  int n0 = (isL ? blockIdx.x : blockIdx.x - NBL)*32;
  int tid = threadIdx.x;
  int wave = tid >> 6, lane = tid & 63, quad = lane >> 4, l15 = lane & 15;
  int mt = wave & 1, nh = wave >> 1;
  int an = n0 + mt*16 + l15; if (an >= nn) an = nn - 1;
  const unsigned short* aptr = xs + (size_t)an*128;
  float4v acc[16];
  #pragma unroll
  for (int i=0;i<16;i++) acc[i] = (float4v){0,0,0,0};
  for (int k0 = 0; k0 < 128; k0 += 32){
    short8 A = *(const short8*)&aptr[k0 + quad*8];
    #pragma unroll
    for (int nt=0;nt<16;nt++){
      short8 B = *(const short8*)&wt[(size_t)(nh*256 + nt*16 + l15)*128 + k0 + quad*8];
      acc[nt] = __builtin_amdgcn_mfma_f32_16x16x32_bf16(A, B, acc[nt], 0, 0, 0);
    }
  }
  #pragma unroll
  for (int nt=0;nt<16;nt++){
    int col = nh*256 + nt*16 + l15;
    float bv = isL ? b1[col] : 0.f;
    #pragma unroll
    for (int r=0;r<4;r++) hb[mt*16 + quad*4 + r][col] = f2bf(acc[nt][r] + bv);
  }
  __syncthreads();
  for (int m=0;m<32;m++){
    int n = n0 + m;
    if (n < nn){
      unsigned pack = (unsigned)hb[m][2*tid] | ((unsigned)hb[m][2*tid+1] << 16);
      hout[(size_t)n*256 + tid] = pack;
    }
  }
}

// ---- readout v10: persistent + reg-resident B + cross-tile pipeline. ----
__global__ __launch_bounds__(512) void k_readout4(
    const unsigned* __restrict__ hl, const unsigned* __restrict__ hp,
    const uint4* __restrict__ edgeL, const float* __restrict__ vvec,
    const unsigned short* __restrict__ w2t, const float* __restrict__ b2,
    const unsigned short* __restrict__ wmt, const float* __restrict__ bm,
    float* __restrict__ outw, unsigned* __restrict__ mmax){
  __shared__ __align__(16) unsigned short lds[37120];   // 2x16384 hbuf + msb
  unsigned short (*msb)[136] = (unsigned short(*)[136])(lds + 32768);
  int tid = threadIdx.x, lane = tid & 63, wave = tid >> 6;
  int quad = lane >> 4, l15 = lane & 15;
  int ns = wave*16;                // this wave's N-strip for both GEMMs

  // XCD-chunked tile mapping
  int wg = (blockIdx.x & 7)*128 + (blockIdx.x >> 3);   // bijective [0,1024)
  int nt_tot = En/32;
  int t0 = wg*16;
  int t1 = t0 + 16; if (t1 > nt_tot) t1 = nt_tot;
  if (t0 >= t1) return;

  // ---- register-resident B: w2t strip (64 VGPR) + wmt strip (16 VGPR) ----
  short8 Bk[16];
  #pragma unroll
  for (int kk=0;kk<16;kk++)
    Bk[kk] = *(const short8*)&w2t[(size_t)(ns + l15)*512 + kk*32 + quad*8];
  short8 Bm[4];
  #pragma unroll
  for (int kk=0;kk<4;kk++)
    Bm[kk] = *(const short8*)&wmt[(size_t)(ns + l15)*128 + kk*32 + quad*8];
  float b2c0 = b2[ns + l15];
  float bm0  = bm[ns + l15];

  // vvec for chunk `lane`: h columns [8*lane, 8*lane+8)
  float4v vva = *(const float4v*)&vvec[lane*8];
  float4v vvb = *(const float4v*)&vvec[lane*8 + 4];
  int sw = lane & 31;
  const uint4* hl4 = (const uint4*)hl;   // one h row = 64 uint4
  const uint4* hp4 = (const uint4*)hp;
  const unsigned* e32 = (const unsigned*)edgeL;

  int si_prev = -1;
  uint4 ua = {0,0,0,0};
  int lm = wave*16 + (lane & 15);        // metadata dword index for this wave
  int le = lane & 31;                    // epilogue edge index

  #define H_EDGE(UA, UB, DD, I, WB)                                          \
    {                                                                        \
      unsigned o0,o1,o2,o3; float hx,hy;                                     \
      hx = fmaxf(bflo(UA.x)+bflo(UB.x)+(DD)*vva.x, 0.f);                     \
      hy = fmaxf(bfhi(UA.x)+bfhi(UB.x)+(DD)*vva.y, 0.f);                     \
      o0 = (unsigned)f2bf(hx) | ((unsigned)f2bf(hy) << 16);                  \
      hx = fmaxf(bflo(UA.y)+bflo(UB.y)+(DD)*vva.z, 0.f);                     \
      hy = fmaxf(bfhi(UA.y)+bfhi(UB.y)+(DD)*vva.w, 0.f);                     \
      o1 = (unsigned)f2bf(hx) | ((unsigned)f2bf(hy) << 16);                  \
      hx = fmaxf(bflo(UA.z)+bflo(UB.z)+(DD)*vvb.x, 0.f);                     \
      hy = fmaxf(bfhi(UA.z)+bfhi(UB.z)+(DD)*vvb.y, 0.f);                     \
      o2 = (unsigned)f2bf(hx) | ((unsigned)f2bf(hy) << 16);                  \
      hx = fmaxf(bflo(UA.w)+bflo(UB.w)+(DD)*vvb.z, 0.f);                     \
      hy = fmaxf(bfhi(UA.w)+bfhi(UB.w)+(DD)*vvb.w, 0.f);                     \
      o3 = (unsigned)f2bf(hx) | ((unsigned)f2bf(hy) << 16);                  \
      uint4 ov; ov.x=o0; ov.y=o1; ov.z=o2; ov.w=o3;                          \
      *(uint4*)&lds[(WB) + lane*256 + (((I) ^ sw) << 3)] = ov;               \
    }

  // ---- prologue: tile t0 -> hbuf0; load md1/br1 for t0+1 ----
  unsigned md1 = 0; int br_cur = 0, br1 = 0;
  {
    unsigned md0 = e32[(size_t)t0*128 + lm];
    br_cur = (int)e32[((size_t)(t0*32 + le))*4 + 3];
    #pragma unroll
    for (int ii=0; ii<4; ii++){
      int si = __builtin_amdgcn_readfirstlane(__shfl((int)md0, ii*4));
      int di = __builtin_amdgcn_readfirstlane(__shfl((int)md0, ii*4 + 1));
      float dd = __uint_as_float((unsigned)__builtin_amdgcn_readfirstlane(__shfl((int)md0, ii*4 + 2)));
      if (si != si_prev){ ua = hl4[(size_t)si*64 + lane]; si_prev = si; }
      uint4 ub = hp4[(size_t)di*64 + lane];
      H_EDGE(ua, ub, dd, wave*4 + ii, 0)
    }
    if (t0 + 1 < t1){
      md1 = e32[(size_t)(t0+1)*128 + lm];
      br1 = (int)e32[((size_t)((t0+1)*32 + le))*4 + 3];
    }
    __syncthreads();
  }

  int cur = 0;
  unsigned md2 = md1; int br2 = br1;
  for (int t = t0; t < t1; ++t){
    bool pf = (t + 1 < t1);
    // issue next-next metadata
    if (t + 2 < t1){
      md2 = e32[(size_t)(t+2)*128 + lm];
      br2 = (int)e32[((size_t)((t+2)*32 + le))*4 + 3];
    }
    // issue hp gathers + deduped hl for tile t+1 (consumed after GEMM2)
    uint4 ub0, ub1, ub2, ub3;
    if (pf){
      int d0 = __builtin_amdgcn_readfirstlane(__shfl((int)md1, 1));
      int d1 = __builtin_amdgcn_readfirstlane(__shfl((int)md1, 5));
      int d2 = __builtin_amdgcn_readfirstlane(__shfl((int)md1, 9));
      int d3 = __builtin_amdgcn_readfirstlane(__shfl((int)md1, 13));
      ub0 = hp4[(size_t)d0*64 + lane];
      ub1 = hp4[(size_t)d1*64 + lane];
      ub2 = hp4[(size_t)d2*64 + lane];
      ub3 = hp4[(size_t)d3*64 + lane];
      int s0 = __builtin_amdgcn_readfirstlane(__shfl((int)md1, 0));
      if (s0 != si_prev){ ua = hl4[(size_t)s0*64 + lane]; si_prev = s0; }
    }

    int rb = cur ? 16384 : 0;
    // GEMM1: m[32,128] = h[32,512] @ W2^T + b2  (B from registers)
    float4v acc[2] = {{0,0,0,0},{0,0,0,0}};
    #pragma unroll
    for (int kk = 0; kk < 16; kk++){
      int kcc = kk*4 + quad;
      int sw2 = kcc & 31;
      short8 A0 = *(const short8*)&lds[rb + kcc*256 + ((l15 ^ sw2) << 3)];
      short8 A1 = *(const short8*)&lds[rb + kcc*256 + (((16 + l15) ^ sw2) << 3)];
      acc[0] = __builtin_amdgcn_mfma_f32_16x16x32_bf16(A0, Bk[kk], acc[0], 0, 0, 0);
      acc[1] = __builtin_amdgcn_mfma_f32_16x16x32_bf16(A1, Bk[kk], acc[1], 0, 0, 0);
    }
    float mreg[2][4];
    #pragma unroll
    for (int mt=0;mt<2;mt++){
      int col = ns + l15;
      #pragma unroll
      for (int r=0;r<4;r++){
        float mv = acc[mt][r] + b2c0;
        mreg[mt][r] = mv;
        msb[mt*16 + quad*4 + r][col] = f2bf(mv);
      }
    }
    __syncthreads();    // barrier A: msb visible

    // GEMM2: t = tanh(m@Wm^T + bm); flush sum(t*m), max(m) per batch
    float4v acc2[2] = {{0,0,0,0},{0,0,0,0}};
    #pragma unroll
    for (int kk = 0; kk < 4; kk++){
      short8 A0 = *(const short8*)&msb[l15][kk*32 + quad*8];
      short8 A1 = *(const short8*)&msb[16 + l15][kk*32 + quad*8];
      acc2[0] = __builtin_amdgcn_mfma_f32_16x16x32_bf16(A0, Bm[kk], acc2[0], 0, 0, 0);
      acc2[1] = __builtin_amdgcn_mfma_f32_16x16x32_bf16(A1, Bm[kk], acc2[1], 0, 0, 0);
    }
    {
      int b0 = __shfl(br_cur, 0);
      bool uni = (b0 == __shfl(br_cur, 31));
      int col = ns + l15;
      if (uni){
        float s = 0.f, mx = -3.402823466e38f;
        #pragma unroll
        for (int mt=0;mt<2;mt++){
          #pragma unroll
          for (int r=0;r<4;r++){
            float mv = mreg[mt][r];
            float tt = tanh_fast(acc2[mt][r] + bm0);
            s += tt*mv; mx = fmaxf(mx, mv);
          }
        }
        s += __shfl_xor(s, 16); s += __shfl_xor(s, 32);
        mx = fmaxf(mx, __shfl_xor(mx, 16)); mx = fmaxf(mx, __shfl_xor(mx, 32));
        if (quad == 0){
          atomicAdd(&outw[b0*256 + col], s);
          atomicMax(&mmax[b0*128 + col], encf(mx));
        }
      } else {
        #pragma unroll
        for (int mt=0;mt<2;mt++){
          #pragma unroll
          for (int r=0;r<4;r++){
            int row = mt*16 + quad*4 + r;
            int b = __shfl(br_cur, row);
            float mv = mreg[mt][r];
            float tt = tanh_fast(acc2[mt][r] + bm0);
            atomicAdd(&outw[b*256 + col], tt*mv);
            atomicMax(&mmax[b*128 + col], encf(mv));
          }
        }
      }
    }

    // consume prefetched gathers -> h(t+1) into the other hbuf
    if (pf){
      int wb = cur ? 0 : 16384;
      #pragma unroll
      for (int ii=0; ii<4; ii++){
        int si = __builtin_amdgcn_readfirstlane(__shfl((int)md1, ii*4));
        float dd = __uint_as_float((unsigned)__builtin_amdgcn_readfirstlane(__shfl((int)md1, ii*4 + 2)));
        if (si != si_prev){ ua = hl4[(size_t)si*64 + lane]; si_prev = si; }
        uint4 ub = (ii==0) ? ub0 : (ii==1) ? ub1 : (ii==2) ? ub2 : ub3;
        H_EDGE(ua, ub, dd, wave*4 + ii, wb)
      }
    }
    __syncthreads();    // barrier B: hbuf[cur^1] + msb reads complete

    md1 = md2; br_cur = br1; br1 = br2;
    cur ^= 1;
  }
  #undef H_EDGE
}

__global__ __launch_bounds__(256) void k_final(const unsigned* __restrict__ mmax,
    float* __restrict__ out){
  int gid = blockIdx.x*256 + threadIdx.x;   // 32768 = 256*128
  unsigned enc = mmax[gid];
  float v;
  if (enc == 0u) v = 0.f;
  else if (enc & 0x80000000u) v = __uint_as_float(enc & 0x7FFFFFFFu);
  else v = __uint_as_float(~enc);
  int g = gid >> 7, cc = gid & 127;
  out[g*256 + 128 + cc] = v;
}

extern "C" void kernel_launch(void* const* d_in, const int* in_sizes, int n_in,
                              void* d_out, int out_size, void* d_ws, size_t ws_size,
                              hipStream_t stream) {
  const float* x_l    = (const float*)d_in[0];
  const float* x_p    = (const float*)d_in[1];
  const float* ea     = (const float*)d_in[2];
  const int*   esrc   = (const int*)d_in[3];
  const int*   edst   = (const int*)d_in[4];
  const int*   lbatch = (const int*)d_in[5];
  const float* W_node = (const float*)d_in[6];
  const float* W_el   = (const float*)d_in[7];
  const float* Wb     = (const float*)d_in[8];
  const float* bb     = (const float*)d_in[9];
  const float* Wn     = (const float*)d_in[10];
  const float* Ws     = (const float*)d_in[11];
  const float* bconv  = (const float*)d_in[12];
  const float* W1     = (const float*)d_in[13];
  const float* b1     = (const float*)d_in[14];
  const float* W2     = (const float*)d_in[15];
  const float* b2     = (const float*)d_in[16];
  const float* Wm     = (const float*)d_in[17];
  const float* bm     = (const float*)d_in[18];

  // ---- workspace layout (decimal offsets), peak 267,354,496 B ----
  char* w = (char*)d_ws;
  unsigned short* xl0 = (unsigned short*)(w + 0);
  unsigned short* xl1 = (unsigned short*)(w + 12800000);
  unsigned short* xp0 = (unsigned short*)(w + 25600000);
  unsigned short* xp1 = (unsigned short*)(w + 64000000);
  int*      idxP  = (int*)(w + 102400000);
  int*      idxL  = (int*)(w + 104400000);
  unsigned short* lut = (unsigned short*)(w + 106400000);   // 6.29e6 B
  unsigned* h_l   = (unsigned*)(w + 0);
  unsigned* h_p   = (unsigned*)(w + 51200000);
  unsigned short* xl_s = (unsigned short*)(w + 204800000);
  unsigned short* xp_s = (unsigned short*)(w + 217600000);
  unsigned short* wcat = (unsigned short*)(w + 256000000);
  unsigned short* w1t  = (unsigned short*)(w + 256393216);
  unsigned short* w2t  = (unsigned short*)(w + 256655360);
  unsigned short* wmt  = (unsigned short*)(w + 256786432);
  float*    vvec  = (float*)(w + 256819200);
  unsigned* mmax  = (unsigned*)(w + 256821248);
  unsigned* bsumL = (unsigned*)(w + 256952320);
  unsigned* bsumP = (unsigned*)(w + 256953344);
  unsigned* rowptrL = (unsigned*)(w + 256954368);
  unsigned* cursorL = (unsigned*)(w + 257154432);
  unsigned* rowptrP = (unsigned*)(w + 257354432);
  unsigned* cursorP = (unsigned*)(w + 257954496);
  unsigned* cntL    = (unsigned*)(w + 258554496);
  unsigned* cntP    = (unsigned*)(w + 258754496);
  uint4*    edgeL   = (uint4*)(w + 259354496);   // {src, dst, bits(d), batch}

  float* out = (float*)d_out;

  k_prep<<<14470, 256, 0, stream>>>(
      (unsigned*)(w + 258554496), mmax, (unsigned*)d_out,
      W_el, W1, vvec, W2, w2t, Wm, wmt, Ws, Wn, wcat, w1t, Wb, bb, lut);
  k_embed<<<NBL + NBP, 256, 0, stream>>>(x_l, x_p, W_node, xl0, xp0);

  k_count<<<1954, 256, 0, stream>>>(esrc, edst, cntL, cntP);
  k_cs2<<<196, 256, 0, stream>>>(cntL, rowptrL, bsumL, cntP, rowptrP, bsumP);
  k_sb2<<<2, 256, 0, stream>>>(bsumL, bsumP);
  k_ao2<<<782, 256, 0, stream>>>(rowptrL, cursorL, bsumL, rowptrP, cursorP, bsumP);
  k_place<<<1954, 256, 0, stream>>>(esrc, edst, ea, lbatch, cursorL, cursorP,
                                    edgeL, idxL, idxP);

  unsigned short *xlc = xl0, *xln = xl1, *xpc = xp0, *xpn = xp1;
  for (int l = 0; l < 3; ++l){
    int ilp = 2*l, ipl = 2*l + 1;
    k_conv2<<<NBP + NBL, 512, 0, stream>>>(
        xpc, xlc, xpn, xln, xp_s, xl_s,
        rowptrP, idxP, rowptrL, idxL,
        lut + (size_t)ilp*524288, wcat + ilp*32768, bconv + ilp*128,
        lut + (size_t)ipl*524288, wcat + ipl*32768, bconv + ipl*128,
        (l == 0) ? 1 : 0);
    unsigned short* t;
    t = xlc; xlc = xln; xln = t;
    t = xpc; xpc = xpn; xpn = t;
  }

  // b1 folded into h_l (ligand part); protein part no bias
  k_hproj2<<<NBL + NBP, 256, 0, stream>>>(xl_s, xp_s, w1t, b1, h_l, h_p);

  k_readout4<<<1024, 512, 0, stream>>>(h_l, h_p, edgeL, vvec,
                                       w2t, b2, wmt, bm, out, mmax);
  k_final<<<128, 256, 0, stream>>>(mmax, out);
}

// Round 10
// 1224.378 us; speedup vs baseline: 1.4790x; 1.0156x over previous
//
#include <hip/hip_runtime.h>
#include <hip/hip_bf16.h>

// HeteroNet on MI355X — round 22.
// R21 (conv2 512thr) 1287->1243us; conv2 ~170/launch, aggregate 510us = 41%.
// Remaining conv2 cost: (1) all 1563 heavy L-blocks (320 edges) scheduled
// AFTER 4688 light P-blocks (105 edges) -> all-heavy tail; (2) 4-unroll = 8
// loads in flight vs ~40-edge serial chains.
// R22: (a) bijective L/P grid interleave (bid&3==3 -> L, +bid6250->L1562);
//      (b) gather unroll 8 (16 loads in flight), launch_bounds(512,8)
//      pins VGPR<=64 for 32 waves/CU. All else unchanged.

#define NLn 50000
#define NPn 150000
#define En  500000
#define NBL 1563   // ceil(NLn/32)
#define NBP 4688   // ceil(NPn/32)

typedef __attribute__((ext_vector_type(8))) short short8;
typedef __attribute__((ext_vector_type(4))) float float4v;

__device__ __forceinline__ float bf2f(unsigned short u){ return __uint_as_float(((unsigned)u) << 16); }
__device__ __forceinline__ float bflo(unsigned u){ return __uint_as_float(u << 16); }
__device__ __forceinline__ float bfhi(unsigned u){ return __uint_as_float(u & 0xffff0000u); }
__device__ __forceinline__ unsigned short f2bf(float f){
  __hip_bfloat16 h = __float2bfloat16(f);
  return *reinterpret_cast<unsigned short*>(&h);
}
// order-preserving float->uint; enc(v)>0 for all finite v, so 0 == "empty segment"
__device__ __forceinline__ unsigned encf(float f){
  unsigned u = __float_as_uint(f);
  return (u & 0x80000000u) ? ~u : (u | 0x80000000u);
}
__device__ __forceinline__ float tanh_fast(float x){
  return 1.f - 2.f/(__expf(2.f*x) + 1.f);
}

// ---- k_embed: X @ W_node -> bf16, 32 rows/block, register-tiled ----
__global__ __launch_bounds__(256) void k_embed(
    const float* __restrict__ Xl, const float* __restrict__ Xp,
    const float* __restrict__ Wnode,
    unsigned short* __restrict__ xl0, unsigned short* __restrict__ xp0){
  __shared__ float xs[1408];   // 32 rows x 44 fp32
  int b = blockIdx.x, tid = threadIdx.x;
  bool isL = b < NBL;
  const float* X = isL ? Xl : Xp;
  unsigned short* out = isL ? xl0 : xp0;
  int n = isL ? NLn : NPn;
  int n0 = (isL ? b : b - NBL) * 32;
  int nrows = n - n0; if (nrows > 32) nrows = 32;
  int nflt = nrows * 44;                            // multiple of 4
  const float4* Xv = (const float4*)(X + (size_t)n0*44);
  for (int j = tid; j*4 < nflt; j += 256){
    float4 v = Xv[j];
    xs[j*4+0]=v.x; xs[j*4+1]=v.y; xs[j*4+2]=v.z; xs[j*4+3]=v.w;
  }
  __syncthreads();
  int c = tid & 127, half = tid >> 7;
  float acc[16];
  #pragma unroll
  for (int r=0;r<16;r++) acc[r]=0.f;
  const float* xrow = xs + half*16*44;
  #pragma unroll 4
  for (int k=0;k<44;k++){
    float w = Wnode[k*128 + c];
    #pragma unroll
    for (int r=0;r<16;r++) acc[r] += xrow[r*44 + k] * w;
  }
  int rbase = n0 + half*16;
  #pragma unroll
  for (int r=0;r<16;r++){
    int nn = rbase + r;
    if (nn < n) out[(size_t)nn*128 + c] = f2bf(acc[r]);
  }
}

// ---- k_prep: zeros + weight transforms + LUT (embed split out) ----
__global__ __launch_bounds__(256) void k_prep(
    unsigned* __restrict__ cntz, unsigned* __restrict__ mmaxz, unsigned* __restrict__ outz,
    const float* __restrict__ Wel, const float* __restrict__ W1, float* __restrict__ vvec,
    const float* __restrict__ W2, unsigned short* __restrict__ w2t,
    const float* __restrict__ Wm, unsigned short* __restrict__ wmt,
    const float* __restrict__ Ws, const float* __restrict__ Wn,
    unsigned short* __restrict__ wcat, unsigned short* __restrict__ w1t,
    const float* __restrict__ Wb, const float* __restrict__ bb,
    unsigned short* __restrict__ lut){
  int b = blockIdx.x, tid = threadIdx.x;
  if (b < 196){
    for (long i = (long)b*256 + tid; i < 200000; i += 196*256) cntz[i] = 0u;
  } else if (b < 324){
    mmaxz[(b-196)*256 + tid] = 0u;
  } else if (b < 580){
    outz[(b-324)*256 + tid] = 0u;
  } else if (b < 582){
    int j = (b-580)*256 + tid;
    float s = 0.f;
    #pragma unroll
    for (int r=0;r<8;r++) s += Wel[r]*W1[(256+r)*512 + j];
    vvec[j] = s;
  } else if (b < 838){
    int gid = (b-582)*256 + tid;                       // 65536
    int n = gid >> 9, k = gid & 511;
    w2t[n*512 + k] = f2bf(W2[k*128 + n]);
  } else if (b < 902){
    int gid = (b-838)*256 + tid;                       // 16384
    int n = gid >> 7, k = gid & 127;
    wmt[n*128 + k] = f2bf(Wm[k*128 + n]);
  } else if (b < 1670){
    int gid = (b-902)*256 + tid;                       // 196608
    int i = gid >> 15, rem = gid & 32767;
    int n = rem >> 8, k = rem & 255;
    float v = (k < 128) ? Ws[i*16384 + k*128 + n] : Wn[i*16384 + (k-128)*128 + n];
    wcat[gid] = f2bf(v);
  } else if (b < 2182){
    int gid = (b-1670)*256 + tid;                      // 131072
    int part = gid >> 16, rem = gid & 65535;
    int n = rem >> 7, k = rem & 127;
    w1t[gid] = f2bf(W1[(part*128 + k)*512 + n]);
  } else {
    int gid = (b-2182)*256 + tid;                      // 3145728
    int c = gid & 127, bin = (gid >> 7) & 4095, i = gid >> 19;
    float d = ((float)bin + 0.5f) * 0.001220703125f;   // *5/4096
    float s = bb[i*128 + c];
    #pragma unroll
    for (int j=0;j<8;j++){
      float a = (d - 0.7142857143f*(float)j) * 1.6f;
      s += __expf(-a*a) * Wb[i*1024 + j*128 + c];
    }
    lut[gid] = f2bf(s / (1.f + __expf(-s)));
  }
}

// ---- CSR construction ----
__global__ __launch_bounds__(256) void k_count(const int* __restrict__ esrc,
    const int* __restrict__ edst, unsigned* __restrict__ cntL, unsigned* __restrict__ cntP){
  int e = blockIdx.x*256 + threadIdx.x;
  if (e >= En) return;
  atomicAdd(&cntL[esrc[e]], 1u);
  atomicAdd(&cntP[edst[e]], 1u);
}
__global__ __launch_bounds__(256) void k_cs2(const unsigned* __restrict__ cntL,
    unsigned* __restrict__ rowptrL, unsigned* __restrict__ bsumL,
    const unsigned* __restrict__ cntP, unsigned* __restrict__ rowptrP,
    unsigned* __restrict__ bsumP){
  bool isL = blockIdx.x < 49;
  const unsigned* cnt = isL ? cntL : cntP;
  unsigned* rowptr = isL ? rowptrL : rowptrP;
  unsigned* bsum = isL ? bsumL : bsumP;
  int n = isL ? NLn : NPn;
  int lb = isL ? blockIdx.x : blockIdx.x - 49;
  __shared__ unsigned ts[256];
  int tid = threadIdx.x;
  int base = lb*1024 + tid*4;
  unsigned v[4], run = 0;
  #pragma unroll
  for (int j=0;j<4;j++){ v[j] = run; run += (base+j < n) ? cnt[base+j] : 0u; }
  ts[tid] = run; __syncthreads();
  for (int off=1; off<256; off<<=1){
    unsigned t = (tid>=off) ? ts[tid-off] : 0u; __syncthreads();
    ts[tid] += t; __syncthreads();
  }
  unsigned excl = ts[tid] - run;
  #pragma unroll
  for (int j=0;j<4;j++) if (base+j < n) rowptr[base+j] = excl + v[j];
  if (tid == 255) bsum[lb] = ts[255];
}
__global__ void k_sb2(unsigned* __restrict__ bsumL, unsigned* __restrict__ bsumP){
  unsigned* bsum = blockIdx.x ? bsumP : bsumL;
  int nc = blockIdx.x ? 147 : 49;
  __shared__ unsigned ts[256];
  int tid = threadIdx.x;
  unsigned x = (tid < nc) ? bsum[tid] : 0u;
  ts[tid] = x; __syncthreads();
  for (int off=1; off<256; off<<=1){
    unsigned t = (tid>=off) ? ts[tid-off] : 0u; __syncthreads();
    ts[tid] += t; __syncthreads();
  }
  if (tid < nc) bsum[tid] = ts[tid] - x;
}
__global__ __launch_bounds__(256) void k_ao2(
    unsigned* __restrict__ rowptrL, unsigned* __restrict__ cursorL,
    const unsigned* __restrict__ bsumL,
    unsigned* __restrict__ rowptrP, unsigned* __restrict__ cursorP,
    const unsigned* __restrict__ bsumP){
  bool isL = blockIdx.x < 196;
  unsigned* rowptr = isL ? rowptrL : rowptrP;
  unsigned* cursor = isL ? cursorL : cursorP;
  const unsigned* bsum = isL ? bsumL : bsumP;
  int n = isL ? NLn : NPn;
  int i = (isL ? blockIdx.x : blockIdx.x - 196)*256 + threadIdx.x;
  if (i < n){
    unsigned r = rowptr[i] + bsum[i>>10];
    rowptr[i] = r; cursor[i] = r;
  }
  if (i == 0) rowptr[n] = En;
}
__global__ __launch_bounds__(256) void k_place(const int* __restrict__ esrc,
    const int* __restrict__ edst, const float* __restrict__ ea,
    const int* __restrict__ lbatch, unsigned* __restrict__ curL,
    unsigned* __restrict__ curP, uint4* __restrict__ edgeL,
    int* __restrict__ idxL, int* __restrict__ idxP){
  int e = blockIdx.x*256 + threadIdx.x;
  if (e >= En) return;
  int s = esrc[e], d = edst[e];
  float dd = ea[e];
  int bin = (int)(dd * 819.2f);
  bin = (bin < 0) ? 0 : ((bin > 4095) ? 4095 : bin);
  unsigned pl = atomicAdd(&curL[s], 1u);
  uint4 er; er.x = (unsigned)s; er.y = (unsigned)d;
  er.z = __float_as_uint(dd); er.w = (unsigned)lbatch[s];
  edgeL[pl] = er;
  idxL[pl] = d | (bin << 18);
  unsigned pp = atomicAdd(&curP[d], 1u);
  idxP[pp] = s | (bin << 18);
}

// ---- fused dual-direction conv, dword gather, 512 threads, unroll-8,
//      bijective L/P grid interleave for tail balance ----
#define EDGE_CAP 1024
__global__ __launch_bounds__(512, 8) void k_conv2(
    const unsigned short* __restrict__ xp_in, const unsigned short* __restrict__ xl_in,
    unsigned short* __restrict__ xp_out, unsigned short* __restrict__ xl_out,
    unsigned short* __restrict__ xp_sum, unsigned short* __restrict__ xl_sum,
    const unsigned* __restrict__ rowptrP, const int* __restrict__ idxP,
    const unsigned* __restrict__ rowptrL, const int* __restrict__ idxL,
    const unsigned short* __restrict__ lut_lp,
    const unsigned short* __restrict__ wcat_lp, const float* __restrict__ bias_lp,
    const unsigned short* __restrict__ lut_pl,
    const unsigned short* __restrict__ wcat_pl, const float* __restrict__ bias_pl,
    int first){
  __shared__ unsigned short ab[32][264];   // [m][k]: k<128 x_dst, k>=128 agg (bf16)
  __shared__ unsigned short ob[32][136];   // epilogue bf16
  __shared__ int snb[EDGE_CAP];
  __shared__ unsigned rps[33];
  int tid = threadIdx.x;
  int c2 = tid & 63, grp = tid >> 6;       // 8 groups x 64 col-pairs x 4 rows
  // bijective L/P interleave: heavy L-blocks spread through the grid
  int bid = blockIdx.x;
  bool isP; int pb;
  if ((bid & 3) == 3){ isP = false; pb = bid >> 2; }
  else if (bid == 6250){ isP = false; pb = 1562; }
  else { isP = true; pb = (bid >> 2)*3 + (bid & 3); }
  const unsigned short* xdst_in = isP ? xp_in : xl_in;
  const unsigned short* xsrc_in = isP ? xl_in : xp_in;
  unsigned short* xout = isP ? xp_out : xl_out;
  unsigned short* xsum = isP ? xp_sum : xl_sum;
  const unsigned* rowptr = isP ? rowptrP : rowptrL;
  const int* eidx = isP ? idxP : idxL;
  const unsigned short* lut_i = isP ? lut_lp : lut_pl;
  const unsigned short* wcat = isP ? wcat_lp : wcat_pl;
  const float* bias = isP ? bias_lp : bias_pl;
  int ndst = isP ? NPn : NLn;
  int n0 = pb * 32;

  if (tid < 33){
    int idx = n0 + tid; if (idx > ndst) idx = ndst;
    rps[tid] = rowptr[idx];
  }
  __syncthreads();
  int r00 = (int)rps[0], rEnd = (int)rps[32];
  int eblk = rEnd - r00;
  bool fits = (eblk <= EDGE_CAP);
  if (fits){
    for (int p = tid; p < eblk; p += 512) snb[p] = eidx[r00 + p];
  }
  __syncthreads();

  const unsigned short* lutc = lut_i + 2*c2;
  const unsigned short* xc = xsrc_in + 2*c2;
  for (int m = grp*4; m < grp*4+4; m++){
    int n = n0 + m;
    float al0=0.f,ah0=0.f,al1=0.f,ah1=0.f,al2=0.f,ah2=0.f,al3=0.f,ah3=0.f;
    int dg = 1;
    if (n < ndst){
      *(unsigned*)&ab[m][2*c2] = *(const unsigned*)&xdst_in[(size_t)n*128 + 2*c2];
      int r0 = (int)rps[m], r1 = (int)rps[m+1];
      dg = r1 - r0;
      int p = r0;
      for (; p + 7 < r1; p += 8){
        int v[8];
        #pragma unroll
        for (int j=0;j<8;j++) v[j] = fits ? snb[p-r00+j] : eidx[p+j];
        unsigned lv[8], xv[8];
        #pragma unroll
        for (int j=0;j<8;j++){
          lv[j] = *(const unsigned*)&lutc[(size_t)((unsigned)v[j] >> 18)*128];
          xv[j] = *(const unsigned*)&xc[(size_t)(v[j] & 0x3FFFF)*128];
        }
        #pragma unroll
        for (int j=0;j<8;j++){
          switch (j & 3){
            case 0: al0 += bflo(lv[j])*bflo(xv[j]); ah0 += bfhi(lv[j])*bfhi(xv[j]); break;
            case 1: al1 += bflo(lv[j])*bflo(xv[j]); ah1 += bfhi(lv[j])*bfhi(xv[j]); break;
            case 2: al2 += bflo(lv[j])*bflo(xv[j]); ah2 += bfhi(lv[j])*bfhi(xv[j]); break;
            default: al3 += bflo(lv[j])*bflo(xv[j]); ah3 += bfhi(lv[j])*bfhi(xv[j]); break;
          }
        }
      }
      for (; p + 3 < r1; p += 4){
        int v0,v1,v2,v3;
        if (fits){
          v0 = snb[p-r00]; v1 = snb[p-r00+1]; v2 = snb[p-r00+2]; v3 = snb[p-r00+3];
        } else {
          v0 = eidx[p]; v1 = eidx[p+1]; v2 = eidx[p+2]; v3 = eidx[p+3];
        }
        unsigned l0 = *(const unsigned*)&lutc[(size_t)((unsigned)v0 >> 18)*128];
        unsigned x0 = *(const unsigned*)&xc[(size_t)(v0 & 0x3FFFF)*128];
        unsigned l1 = *(const unsigned*)&lutc[(size_t)((unsigned)v1 >> 18)*128];
        unsigned x1 = *(const unsigned*)&xc[(size_t)(v1 & 0x3FFFF)*128];
        unsigned l2 = *(const unsigned*)&lutc[(size_t)((unsigned)v2 >> 18)*128];
        unsigned x2 = *(const unsigned*)&xc[(size_t)(v2 & 0x3FFFF)*128];
        unsigned l3 = *(const unsigned*)&lutc[(size_t)((unsigned)v3 >> 18)*128];
        unsigned x3 = *(const unsigned*)&xc[(size_t)(v3 & 0x3FFFF)*128];
        al0 += bflo(l0)*bflo(x0); ah0 += bfhi(l0)*bfhi(x0);
        al1 += bflo(l1)*bflo(x1); ah1 += bfhi(l1)*bfhi(x1);
        al2 += bflo(l2)*bflo(x2); ah2 += bfhi(l2)*bfhi(x2);
        al3 += bflo(l3)*bflo(x3); ah3 += bfhi(l3)*bfhi(x3);
      }
      for (; p < r1; p++){
        int v0 = fits ? snb[p-r00] : eidx[p];
        unsigned l0 = *(const unsigned*)&lutc[(size_t)((unsigned)v0 >> 18)*128];
        unsigned x0 = *(const unsigned*)&xc[(size_t)(v0 & 0x3FFFF)*128];
        al0 += bflo(l0)*bflo(x0); ah0 += bfhi(l0)*bfhi(x0);
      }
    } else {
      *(unsigned*)&ab[m][2*c2] = 0u;
    }
    float inv = 1.f / (float)(dg > 1 ? dg : 1);
    float alo = ((al0+al1)+(al2+al3)) * inv;
    float ahi = ((ah0+ah1)+(ah2+ah3)) * inv;
    *(unsigned*)&ab[m][128 + 2*c2] = (unsigned)f2bf(alo) | ((unsigned)f2bf(ahi) << 16);
  }
  __syncthreads();

  int wave = tid >> 6, lane = tid & 63, quad = lane >> 4, l15 = lane & 15;
  int mt = wave & 1, nh = wave >> 1;       // nh in [0,4)
  int arow = mt*16 + l15;
  float4v acc[2] = {{0,0,0,0},{0,0,0,0}};
  for (int k0 = 0; k0 < 256; k0 += 32){
    short8 A = *(const short8*)&ab[arow][k0 + quad*8];
    #pragma unroll
    for (int nt=0;nt<2;nt++){
      short8 B = *(const short8*)&wcat[(size_t)(nh*32 + nt*16 + l15)*256 + k0 + quad*8];
      acc[nt] = __builtin_amdgcn_mfma_f32_16x16x32_bf16(A, B, acc[nt], 0, 0, 0);
    }
  }
  #pragma unroll
  for (int nt=0;nt<2;nt++){
    int col = nh*32 + nt*16 + l15;
    float bc = bias[col];
    #pragma unroll
    for (int r=0;r<4;r++){
      int row = mt*16 + quad*4 + r;
      float v = acc[nt][r] + bc;
      ob[row][col] = f2bf((v > 0.f) ? v : 0.01f*v);    // leaky_relu
    }
  }
  __syncthreads();
  for (int m = grp*4; m < grp*4+4; m++){
    int n = n0 + m;
    if (n < ndst){
      unsigned vb = *(unsigned*)&ob[m][2*c2];
      size_t off = (size_t)n*128 + 2*c2;
      *(unsigned*)&xout[off] = vb;
      if (first){
        *(unsigned*)&xsum[off] = vb;
      } else {
        unsigned so = *(unsigned*)&xsum[off];
        float lo = bflo(so) + bflo(vb);
        float hi = bfhi(so) + bfhi(vb);
        *(unsigned*)&xsum[off] = (unsigned)f2bf(lo) | ((unsigned)f2bf(hi) << 16);
      }
    }
  }
}

// ---- merged MFMA hproj: blocks [0,NBL): ligand (+b1); [NBL,NBL+NBP): protein
__global__ __launch_bounds__(256) void k_hproj2(
    const unsigned short* __restrict__ xl_s, const unsigned short* __restrict__ xp_s,
    const unsigned short* __restrict__ w1t, const float* __restrict__ b1,
    unsigned* __restrict__ h_l, unsigned* __restrict__ h_p){
  __shared__ unsigned short hb[32][528];
  bool isL = blockIdx.x < NBL;
  const unsigned short* xs = isL ? xl_s : xp_s;
  const unsigned short* wt = isL ? w1t : w1t + 65536;
  unsigned* hout = isL ? h_l : h_p;
  int nn = isL ? NLn : NPn;
  int n0 = (isL ? blockIdx.x : blockIdx.x - NBL)*32;
  int tid = threadIdx.x;
  int wave = tid >> 6, lane = tid & 63, quad = lane >> 4, l15 = lane & 15;
  int mt = wave & 1, nh = wave >> 1;
  int an = n0 + mt*16 + l15; if (an >= nn) an = nn - 1;
  const unsigned short* aptr = xs + (size_t)an*128;
  float4v acc[16];
  #pragma unroll
  for (int i=0;i<16;i++) acc[i] = (float4v){0,0,0,0};
  for (int k0 = 0; k0 < 128; k0 += 32){
    short8 A = *(const short8*)&aptr[k0 + quad*8];
    #pragma unroll
    for (int nt=0;nt<16;nt++){
      short8 B = *(const short8*)&wt[(size_t)(nh*256 + nt*16 + l15)*128 + k0 + quad*8];
      acc[nt] = __builtin_amdgcn_mfma_f32_16x16x32_bf16(A, B, acc[nt], 0, 0, 0);
    }
  }
  #pragma unroll
  for (int nt=0;nt<16;nt++){
    int col = nh*256 + nt*16 + l15;
    float bv = isL ? b1[col] : 0.f;
    #pragma unroll
    for (int r=0;r<4;r++) hb[mt*16 + quad*4 + r][col] = f2bf(acc[nt][r] + bv);
  }
  __syncthreads();
  for (int m=0;m<32;m++){
    int n = n0 + m;
    if (n < nn){
      unsigned pack = (unsigned)hb[m][2*tid] | ((unsigned)hb[m][2*tid+1] << 16);
      hout[(size_t)n*256 + tid] = pack;
    }
  }
}

// ---- readout v10: persistent + reg-resident B + cross-tile pipeline. ----
__global__ __launch_bounds__(512) void k_readout4(
    const unsigned* __restrict__ hl, const unsigned* __restrict__ hp,
    const uint4* __restrict__ edgeL, const float* __restrict__ vvec,
    const unsigned short* __restrict__ w2t, const float* __restrict__ b2,
    const unsigned short* __restrict__ wmt, const float* __restrict__ bm,
    float* __restrict__ outw, unsigned* __restrict__ mmax){
  __shared__ __align__(16) unsigned short lds[37120];   // 2x16384 hbuf + msb
  unsigned short (*msb)[136] = (unsigned short(*)[136])(lds + 32768);
  int tid = threadIdx.x, lane = tid & 63, wave = tid >> 6;
  int quad = lane >> 4, l15 = lane & 15;
  int ns = wave*16;                // this wave's N-strip for both GEMMs

  // XCD-chunked tile mapping
  int wg = (blockIdx.x & 7)*128 + (blockIdx.x >> 3);   // bijective [0,1024)
  int nt_tot = En/32;
  int t0 = wg*16;
  int t1 = t0 + 16; if (t1 > nt_tot) t1 = nt_tot;
  if (t0 >= t1) return;

  // ---- register-resident B: w2t strip (64 VGPR) + wmt strip (16 VGPR) ----
  short8 Bk[16];
  #pragma unroll
  for (int kk=0;kk<16;kk++)
    Bk[kk] = *(const short8*)&w2t[(size_t)(ns + l15)*512 + kk*32 + quad*8];
  short8 Bm[4];
  #pragma unroll
  for (int kk=0;kk<4;kk++)
    Bm[kk] = *(const short8*)&wmt[(size_t)(ns + l15)*128 + kk*32 + quad*8];
  float b2c0 = b2[ns + l15];
  float bm0  = bm[ns + l15];

  // vvec for chunk `lane`: h columns [8*lane, 8*lane+8)
  float4v vva = *(const float4v*)&vvec[lane*8];
  float4v vvb = *(const float4v*)&vvec[lane*8 + 4];
  int sw = lane & 31;
  const uint4* hl4 = (const uint4*)hl;   // one h row = 64 uint4
  const uint4* hp4 = (const uint4*)hp;
  const unsigned* e32 = (const unsigned*)edgeL;

  int si_prev = -1;
  uint4 ua = {0,0,0,0};
  int lm = wave*16 + (lane & 15);        // metadata dword index for this wave
  int le = lane & 31;                    // epilogue edge index

  #define H_EDGE(UA, UB, DD, I, WB)                                          \
    {                                                                        \
      unsigned o0,o1,o2,o3; float hx,hy;                                     \
      hx = fmaxf(bflo(UA.x)+bflo(UB.x)+(DD)*vva.x, 0.f);                     \
      hy = fmaxf(bfhi(UA.x)+bfhi(UB.x)+(DD)*vva.y, 0.f);                     \
      o0 = (unsigned)f2bf(hx) | ((unsigned)f2bf(hy) << 16);                  \
      hx = fmaxf(bflo(UA.y)+bflo(UB.y)+(DD)*vva.z, 0.f);                     \
      hy = fmaxf(bfhi(UA.y)+bfhi(UB.y)+(DD)*vva.w, 0.f);                     \
      o1 = (unsigned)f2bf(hx) | ((unsigned)f2bf(hy) << 16);                  \
      hx = fmaxf(bflo(UA.z)+bflo(UB.z)+(DD)*vvb.x, 0.f);                     \
      hy = fmaxf(bfhi(UA.z)+bfhi(UB.z)+(DD)*vvb.y, 0.f);                     \
      o2 = (unsigned)f2bf(hx) | ((unsigned)f2bf(hy) << 16);                  \
      hx = fmaxf(bflo(UA.w)+bflo(UB.w)+(DD)*vvb.z, 0.f);                     \
      hy = fmaxf(bfhi(UA.w)+bfhi(UB.w)+(DD)*vvb.w, 0.f);                     \
      o3 = (unsigned)f2bf(hx) | ((unsigned)f2bf(hy) << 16);                  \
      uint4 ov; ov.x=o0; ov.y=o1; ov.z=o2; ov.w=o3;                          \
      *(uint4*)&lds[(WB) + lane*256 + (((I) ^ sw) << 3)] = ov;               \
    }

  // ---- prologue: tile t0 -> hbuf0; load md1/br1 for t0+1 ----
  unsigned md1 = 0; int br_cur = 0, br1 = 0;
  {
    unsigned md0 = e32[(size_t)t0*128 + lm];
    br_cur = (int)e32[((size_t)(t0*32 + le))*4 + 3];
    #pragma unroll
    for (int ii=0; ii<4; ii++){
      int si = __builtin_amdgcn_readfirstlane(__shfl((int)md0, ii*4));
      int di = __builtin_amdgcn_readfirstlane(__shfl((int)md0, ii*4 + 1));
      float dd = __uint_as_float((unsigned)__builtin_amdgcn_readfirstlane(__shfl((int)md0, ii*4 + 2)));
      if (si != si_prev){ ua = hl4[(size_t)si*64 + lane]; si_prev = si; }
      uint4 ub = hp4[(size_t)di*64 + lane];
      H_EDGE(ua, ub, dd, wave*4 + ii, 0)
    }
    if (t0 + 1 < t1){
      md1 = e32[(size_t)(t0+1)*128 + lm];
      br1 = (int)e32[((size_t)((t0+1)*32 + le))*4 + 3];
    }
    __syncthreads();
  }

  int cur = 0;
  unsigned md2 = md1; int br2 = br1;
  for (int t = t0; t < t1; ++t){
    bool pf = (t + 1 < t1);
    // issue next-next metadata
    if (t + 2 < t1){
      md2 = e32[(size_t)(t+2)*128 + lm];
      br2 = (int)e32[((size_t)((t+2)*32 + le))*4 + 3];
    }
    // issue hp gathers + deduped hl for tile t+1 (consumed after GEMM2)
    uint4 ub0, ub1, ub2, ub3;
    if (pf){
      int d0 = __builtin_amdgcn_readfirstlane(__shfl((int)md1, 1));
      int d1 = __builtin_amdgcn_readfirstlane(__shfl((int)md1, 5));
      int d2 = __builtin_amdgcn_readfirstlane(__shfl((int)md1, 9));
      int d3 = __builtin_amdgcn_readfirstlane(__shfl((int)md1, 13));
      ub0 = hp4[(size_t)d0*64 + lane];
      ub1 = hp4[(size_t)d1*64 + lane];
      ub2 = hp4[(size_t)d2*64 + lane];
      ub3 = hp4[(size_t)d3*64 + lane];
      int s0 = __builtin_amdgcn_readfirstlane(__shfl((int)md1, 0));
      if (s0 != si_prev){ ua = hl4[(size_t)s0*64 + lane]; si_prev = s0; }
    }

    int rb = cur ? 16384 : 0;
    // GEMM1: m[32,128] = h[32,512] @ W2^T + b2  (B from registers)
    float4v acc[2] = {{0,0,0,0},{0,0,0,0}};
    #pragma unroll
    for (int kk = 0; kk < 16; kk++){
      int kcc = kk*4 + quad;
      int sw2 = kcc & 31;
      short8 A0 = *(const short8*)&lds[rb + kcc*256 + ((l15 ^ sw2) << 3)];
      short8 A1 = *(const short8*)&lds[rb + kcc*256 + (((16 + l15) ^ sw2) << 3)];
      acc[0] = __builtin_amdgcn_mfma_f32_16x16x32_bf16(A0, Bk[kk], acc[0], 0, 0, 0);
      acc[1] = __builtin_amdgcn_mfma_f32_16x16x32_bf16(A1, Bk[kk], acc[1], 0, 0, 0);
    }
    float mreg[2][4];
    #pragma unroll
    for (int mt=0;mt<2;mt++){
      int col = ns + l15;
      #pragma unroll
      for (int r=0;r<4;r++){
        float mv = acc[mt][r] + b2c0;
        mreg[mt][r] = mv;
        msb[mt*16 + quad*4 + r][col] = f2bf(mv);
      }
    }
    __syncthreads();    // barrier A: msb visible

    // GEMM2: t = tanh(m@Wm^T + bm); flush sum(t*m), max(m) per batch
    float4v acc2[2] = {{0,0,0,0},{0,0,0,0}};
    #pragma unroll
    for (int kk = 0; kk < 4; kk++){
      short8 A0 = *(const short8*)&msb[l15][kk*32 + quad*8];
      short8 A1 = *(const short8*)&msb[16 + l15][kk*32 + quad*8];
      acc2[0] = __builtin_amdgcn_mfma_f32_16x16x32_bf16(A0, Bm[kk], acc2[0], 0, 0, 0);
      acc2[1] = __builtin_amdgcn_mfma_f32_16x16x32_bf16(A1, Bm[kk], acc2[1], 0, 0, 0);
    }
    {
      int b0 = __shfl(br_cur, 0);
      bool uni = (b0 == __shfl(br_cur, 31));
      int col = ns + l15;
      if (uni){
        float s = 0.f, mx = -3.402823466e38f;
        #pragma unroll
        for (int mt=0;mt<2;mt++){
          #pragma unroll
          for (int r=0;r<4;r++){
            float mv = mreg[mt][r];
            float tt = tanh_fast(acc2[mt][r] + bm0);
            s += tt*mv; mx = fmaxf(mx, mv);
          }
        }
        s += __shfl_xor(s, 16); s += __shfl_xor(s, 32);
        mx = fmaxf(mx, __shfl_xor(mx, 16)); mx = fmaxf(mx, __shfl_xor(mx, 32));
        if (quad == 0){
          atomicAdd(&outw[b0*256 + col], s);
          atomicMax(&mmax[b0*128 + col], encf(mx));
        }
      } else {
        #pragma unroll
        for (int mt=0;mt<2;mt++){
          #pragma unroll
          for (int r=0;r<4;r++){
            int row = mt*16 + quad*4 + r;
            int b = __shfl(br_cur, row);
            float mv = mreg[mt][r];
            float tt = tanh_fast(acc2[mt][r] + bm0);
            atomicAdd(&outw[b*256 + col], tt*mv);
            atomicMax(&mmax[b*128 + col], encf(mv));
          }
        }
      }
    }

    // consume prefetched gathers -> h(t+1) into the other hbuf
    if (pf){
      int wb = cur ? 0 : 16384;
      #pragma unroll
      for (int ii=0; ii<4; ii++){
        int si = __builtin_amdgcn_readfirstlane(__shfl((int)md1, ii*4));
        float dd = __uint_as_float((unsigned)__builtin_amdgcn_readfirstlane(__shfl((int)md1, ii*4 + 2)));
        if (si != si_prev){ ua = hl4[(size_t)si*64 + lane]; si_prev = si; }
        uint4 ub = (ii==0) ? ub0 : (ii==1) ? ub1 : (ii==2) ? ub2 : ub3;
        H_EDGE(ua, ub, dd, wave*4 + ii, wb)
      }
    }
    __syncthreads();    // barrier B: hbuf[cur^1] + msb reads complete

    md1 = md2; br_cur = br1; br1 = br2;
    cur ^= 1;
  }
  #undef H_EDGE
}

__global__ __launch_bounds__(256) void k_final(const unsigned* __restrict__ mmax,
    float* __restrict__ out){
  int gid = blockIdx.x*256 + threadIdx.x;   // 32768 = 256*128
  unsigned enc = mmax[gid];
  float v;
  if (enc == 0u) v = 0.f;
  else if (enc & 0x80000000u) v = __uint_as_float(enc & 0x7FFFFFFFu);
  else v = __uint_as_float(~enc);
  int g = gid >> 7, cc = gid & 127;
  out[g*256 + 128 + cc] = v;
}

extern "C" void kernel_launch(void* const* d_in, const int* in_sizes, int n_in,
                              void* d_out, int out_size, void* d_ws, size_t ws_size,
                              hipStream_t stream) {
  const float* x_l    = (const float*)d_in[0];
  const float* x_p    = (const float*)d_in[1];
  const float* ea     = (const float*)d_in[2];
  const int*   esrc   = (const int*)d_in[3];
  const int*   edst   = (const int*)d_in[4];
  const int*   lbatch = (const int*)d_in[5];
  const float* W_node = (const float*)d_in[6];
  const float* W_el   = (const float*)d_in[7];
  const float* Wb     = (const float*)d_in[8];
  const float* bb     = (const float*)d_in[9];
  const float* Wn     = (const float*)d_in[10];
  const float* Ws     = (const float*)d_in[11];
  const float* bconv  = (const float*)d_in[12];
  const float* W1     = (const float*)d_in[13];
  const float* b1     = (const float*)d_in[14];
  const float* W2     = (const float*)d_in[15];
  const float* b2     = (const float*)d_in[16];
  const float* Wm     = (const float*)d_in[17];
  const float* bm     = (const float*)d_in[18];

  // ---- workspace layout (decimal offsets), peak 267,354,496 B ----
  char* w = (char*)d_ws;
  unsigned short* xl0 = (unsigned short*)(w + 0);
  unsigned short* xl1 = (unsigned short*)(w + 12800000);
  unsigned short* xp0 = (unsigned short*)(w + 25600000);
  unsigned short* xp1 = (unsigned short*)(w + 64000000);
  int*      idxP  = (int*)(w + 102400000);
  int*      idxL  = (int*)(w + 104400000);
  unsigned short* lut = (unsigned short*)(w + 106400000);   // 6.29e6 B
  unsigned* h_l   = (unsigned*)(w + 0);
  unsigned* h_p   = (unsigned*)(w + 51200000);
  unsigned short* xl_s = (unsigned short*)(w + 204800000);
  unsigned short* xp_s = (unsigned short*)(w + 217600000);
  unsigned short* wcat = (unsigned short*)(w + 256000000);
  unsigned short* w1t  = (unsigned short*)(w + 256393216);
  unsigned short* w2t  = (unsigned short*)(w + 256655360);
  unsigned short* wmt  = (unsigned short*)(w + 256786432);
  float*    vvec  = (float*)(w + 256819200);
  unsigned* mmax  = (unsigned*)(w + 256821248);
  unsigned* bsumL = (unsigned*)(w + 256952320);
  unsigned* bsumP = (unsigned*)(w + 256953344);
  unsigned* rowptrL = (unsigned*)(w + 256954368);
  unsigned* cursorL = (unsigned*)(w + 257154432);
  unsigned* rowptrP = (unsigned*)(w + 257354432);
  unsigned* cursorP = (unsigned*)(w + 257954496);
  unsigned* cntL    = (unsigned*)(w + 258554496);
  unsigned* cntP    = (unsigned*)(w + 258754496);
  uint4*    edgeL   = (uint4*)(w + 259354496);   // {src, dst, bits(d), batch}

  float* out = (float*)d_out;

  k_prep<<<14470, 256, 0, stream>>>(
      (unsigned*)(w + 258554496), mmax, (unsigned*)d_out,
      W_el, W1, vvec, W2, w2t, Wm, wmt, Ws, Wn, wcat, w1t, Wb, bb, lut);
  k_embed<<<NBL + NBP, 256, 0, stream>>>(x_l, x_p, W_node, xl0, xp0);

  k_count<<<1954, 256, 0, stream>>>(esrc, edst, cntL, cntP);
  k_cs2<<<196, 256, 0, stream>>>(cntL, rowptrL, bsumL, cntP, rowptrP, bsumP);
  k_sb2<<<2, 256, 0, stream>>>(bsumL, bsumP);
  k_ao2<<<782, 256, 0, stream>>>(rowptrL, cursorL, bsumL, rowptrP, cursorP, bsumP);
  k_place<<<1954, 256, 0, stream>>>(esrc, edst, ea, lbatch, cursorL, cursorP,
                                    edgeL, idxL, idxP);

  unsigned short *xlc = xl0, *xln = xl1, *xpc = xp0, *xpn = xp1;
  for (int l = 0; l < 3; ++l){
    int ilp = 2*l, ipl = 2*l + 1;
    k_conv2<<<NBP + NBL, 512, 0, stream>>>(
        xpc, xlc, xpn, xln, xp_s, xl_s,
        rowptrP, idxP, rowptrL, idxL,
        lut + (size_t)ilp*524288, wcat + ilp*32768, bconv + ilp*128,
        lut + (size_t)ipl*524288, wcat + ipl*32768, bconv + ipl*128,
        (l == 0) ? 1 : 0);
    unsigned short* t;
    t = xlc; xlc = xln; xln = t;
    t = xpc; xpc = xpn; xpn = t;
  }

  // b1 folded into h_l (ligand part); protein part no bias
  k_hproj2<<<NBL + NBP, 256, 0, stream>>>(xl_s, xp_s, w1t, b1, h_l, h_p);

  k_readout4<<<1024, 512, 0, stream>>>(h_l, h_p, edgeL, vvec,
                                       w2t, b2, wmt, bm, out, mmax);
  k_final<<<128, 256, 0, stream>>>(mmax, out);
}

// Round 11
// 1095.429 us; speedup vs baseline: 1.6531x; 1.1177x over previous
//
#include <hip/hip_runtime.h>
#include <hip/hip_bf16.h>

// HeteroNet on MI355X — round 23.
// R22: conv2 accepted at ~155/launch (~1.3x L3 gather floor). Remaining
// invisible-time targets by arithmetic: (1) prep LUT branch — 3.1M entries
// x 8 expf, but gaussians depend only on (bin,j) and 128 threads/bin
// recompute them; (2) hproj2 — every 32-row block re-streams its 128KB
// B-panel: 800MB w1t traffic (same pathology R17 fixed in readout).
// R23: (a) LUT gaussian factorization via LDS (8 exp -> 1 exp/entry);
//      (b) k_hproj3: persistent 1024x512 blocks, Bk[4][4] reg-resident
//      (64 VGPR), w1t traffic 800MB -> 131MB.

#define NLn 50000
#define NPn 150000
#define En  500000
#define NBL 1563   // ceil(NLn/32)
#define NBP 4688   // ceil(NPn/32)

typedef __attribute__((ext_vector_type(8))) short short8;
typedef __attribute__((ext_vector_type(4))) float float4v;

__device__ __forceinline__ float bf2f(unsigned short u){ return __uint_as_float(((unsigned)u) << 16); }
__device__ __forceinline__ float bflo(unsigned u){ return __uint_as_float(u << 16); }
__device__ __forceinline__ float bfhi(unsigned u){ return __uint_as_float(u & 0xffff0000u); }
__device__ __forceinline__ unsigned short f2bf(float f){
  __hip_bfloat16 h = __float2bfloat16(f);
  return *reinterpret_cast<unsigned short*>(&h);
}
// order-preserving float->uint; enc(v)>0 for all finite v, so 0 == "empty segment"
__device__ __forceinline__ unsigned encf(float f){
  unsigned u = __float_as_uint(f);
  return (u & 0x80000000u) ? ~u : (u | 0x80000000u);
}
__device__ __forceinline__ float tanh_fast(float x){
  return 1.f - 2.f/(__expf(2.f*x) + 1.f);
}

// ---- k_embed: X @ W_node -> bf16, 32 rows/block, register-tiled ----
__global__ __launch_bounds__(256) void k_embed(
    const float* __restrict__ Xl, const float* __restrict__ Xp,
    const float* __restrict__ Wnode,
    unsigned short* __restrict__ xl0, unsigned short* __restrict__ xp0){
  __shared__ float xs[1408];   // 32 rows x 44 fp32
  int b = blockIdx.x, tid = threadIdx.x;
  bool isL = b < NBL;
  const float* X = isL ? Xl : Xp;
  unsigned short* out = isL ? xl0 : xp0;
  int n = isL ? NLn : NPn;
  int n0 = (isL ? b : b - NBL) * 32;
  int nrows = n - n0; if (nrows > 32) nrows = 32;
  int nflt = nrows * 44;                            // multiple of 4
  const float4* Xv = (const float4*)(X + (size_t)n0*44);
  for (int j = tid; j*4 < nflt; j += 256){
    float4 v = Xv[j];
    xs[j*4+0]=v.x; xs[j*4+1]=v.y; xs[j*4+2]=v.z; xs[j*4+3]=v.w;
  }
  __syncthreads();
  int c = tid & 127, half = tid >> 7;
  float acc[16];
  #pragma unroll
  for (int r=0;r<16;r++) acc[r]=0.f;
  const float* xrow = xs + half*16*44;
  #pragma unroll 4
  for (int k=0;k<44;k++){
    float w = Wnode[k*128 + c];
    #pragma unroll
    for (int r=0;r<16;r++) acc[r] += xrow[r*44 + k] * w;
  }
  int rbase = n0 + half*16;
  #pragma unroll
  for (int r=0;r<16;r++){
    int nn = rbase + r;
    if (nn < n) out[(size_t)nn*128 + c] = f2bf(acc[r]);
  }
}

// ---- k_prep: zeros + weight transforms + LUT (gaussian-factored) ----
__global__ __launch_bounds__(256) void k_prep(
    unsigned* __restrict__ cntz, unsigned* __restrict__ mmaxz, unsigned* __restrict__ outz,
    const float* __restrict__ Wel, const float* __restrict__ W1, float* __restrict__ vvec,
    const float* __restrict__ W2, unsigned short* __restrict__ w2t,
    const float* __restrict__ Wm, unsigned short* __restrict__ wmt,
    const float* __restrict__ Ws, const float* __restrict__ Wn,
    unsigned short* __restrict__ wcat, unsigned short* __restrict__ w1t,
    const float* __restrict__ Wb, const float* __restrict__ bb,
    unsigned short* __restrict__ lut){
  __shared__ float gw[16];   // 2 bins x 8 gaussians (LUT branch only)
  int b = blockIdx.x, tid = threadIdx.x;
  if (b < 196){
    for (long i = (long)b*256 + tid; i < 200000; i += 196*256) cntz[i] = 0u;
  } else if (b < 324){
    mmaxz[(b-196)*256 + tid] = 0u;
  } else if (b < 580){
    outz[(b-324)*256 + tid] = 0u;
  } else if (b < 582){
    int j = (b-580)*256 + tid;
    float s = 0.f;
    #pragma unroll
    for (int r=0;r<8;r++) s += Wel[r]*W1[(256+r)*512 + j];
    vvec[j] = s;
  } else if (b < 838){
    int gid = (b-582)*256 + tid;                       // 65536
    int n = gid >> 9, k = gid & 511;
    w2t[n*512 + k] = f2bf(W2[k*128 + n]);
  } else if (b < 902){
    int gid = (b-838)*256 + tid;                       // 16384
    int n = gid >> 7, k = gid & 127;
    wmt[n*128 + k] = f2bf(Wm[k*128 + n]);
  } else if (b < 1670){
    int gid = (b-902)*256 + tid;                       // 196608
    int i = gid >> 15, rem = gid & 32767;
    int n = rem >> 8, k = rem & 255;
    float v = (k < 128) ? Ws[i*16384 + k*128 + n] : Wn[i*16384 + (k-128)*128 + n];
    wcat[gid] = f2bf(v);
  } else if (b < 2182){
    int gid = (b-1670)*256 + tid;                      // 131072
    int part = gid >> 16, rem = gid & 65535;
    int n = rem >> 7, k = rem & 127;
    w1t[gid] = f2bf(W1[(part*128 + k)*512 + n]);
  } else {
    int gid0 = (b-2182)*256;                           // 3145728 total
    int c = tid & 127, half = tid >> 7;
    int bin0 = (gid0 >> 7) & 4095;                     // even; block covers bin0, bin0+1
    int i = gid0 >> 19;                                // constant per block
    if (tid < 16){
      int bn = bin0 + (tid >> 3), j = tid & 7;
      float d = ((float)bn + 0.5f) * 0.001220703125f;  // *5/4096
      float a = (d - 0.7142857143f*(float)j) * 1.6f;
      gw[tid] = __expf(-a*a);
    }
    __syncthreads();
    float s = bb[i*128 + c];
    const float* g = gw + half*8;
    #pragma unroll
    for (int j=0;j<8;j++) s += g[j] * Wb[i*1024 + j*128 + c];
    lut[gid0 + tid] = f2bf(s / (1.f + __expf(-s)));
  }
}

// ---- CSR construction ----
__global__ __launch_bounds__(256) void k_count(const int* __restrict__ esrc,
    const int* __restrict__ edst, unsigned* __restrict__ cntL, unsigned* __restrict__ cntP){
  int e = blockIdx.x*256 + threadIdx.x;
  if (e >= En) return;
  atomicAdd(&cntL[esrc[e]], 1u);
  atomicAdd(&cntP[edst[e]], 1u);
}
__global__ __launch_bounds__(256) void k_cs2(const unsigned* __restrict__ cntL,
    unsigned* __restrict__ rowptrL, unsigned* __restrict__ bsumL,
    const unsigned* __restrict__ cntP, unsigned* __restrict__ rowptrP,
    unsigned* __restrict__ bsumP){
  bool isL = blockIdx.x < 49;
  const unsigned* cnt = isL ? cntL : cntP;
  unsigned* rowptr = isL ? rowptrL : rowptrP;
  unsigned* bsum = isL ? bsumL : bsumP;
  int n = isL ? NLn : NPn;
  int lb = isL ? blockIdx.x : blockIdx.x - 49;
  __shared__ unsigned ts[256];
  int tid = threadIdx.x;
  int base = lb*1024 + tid*4;
  unsigned v[4], run = 0;
  #pragma unroll
  for (int j=0;j<4;j++){ v[j] = run; run += (base+j < n) ? cnt[base+j] : 0u; }
  ts[tid] = run; __syncthreads();
  for (int off=1; off<256; off<<=1){
    unsigned t = (tid>=off) ? ts[tid-off] : 0u; __syncthreads();
    ts[tid] += t; __syncthreads();
  }
  unsigned excl = ts[tid] - run;
  #pragma unroll
  for (int j=0;j<4;j++) if (base+j < n) rowptr[base+j] = excl + v[j];
  if (tid == 255) bsum[lb] = ts[255];
}
__global__ void k_sb2(unsigned* __restrict__ bsumL, unsigned* __restrict__ bsumP){
  unsigned* bsum = blockIdx.x ? bsumP : bsumL;
  int nc = blockIdx.x ? 147 : 49;
  __shared__ unsigned ts[256];
  int tid = threadIdx.x;
  unsigned x = (tid < nc) ? bsum[tid] : 0u;
  ts[tid] = x; __syncthreads();
  for (int off=1; off<256; off<<=1){
    unsigned t = (tid>=off) ? ts[tid-off] : 0u; __syncthreads();
    ts[tid] += t; __syncthreads();
  }
  if (tid < nc) bsum[tid] = ts[tid] - x;
}
__global__ __launch_bounds__(256) void k_ao2(
    unsigned* __restrict__ rowptrL, unsigned* __restrict__ cursorL,
    const unsigned* __restrict__ bsumL,
    unsigned* __restrict__ rowptrP, unsigned* __restrict__ cursorP,
    const unsigned* __restrict__ bsumP){
  bool isL = blockIdx.x < 196;
  unsigned* rowptr = isL ? rowptrL : rowptrP;
  unsigned* cursor = isL ? cursorL : cursorP;
  const unsigned* bsum = isL ? bsumL : bsumP;
  int n = isL ? NLn : NPn;
  int i = (isL ? blockIdx.x : blockIdx.x - 196)*256 + threadIdx.x;
  if (i < n){
    unsigned r = rowptr[i] + bsum[i>>10];
    rowptr[i] = r; cursor[i] = r;
  }
  if (i == 0) rowptr[n] = En;
}
__global__ __launch_bounds__(256) void k_place(const int* __restrict__ esrc,
    const int* __restrict__ edst, const float* __restrict__ ea,
    const int* __restrict__ lbatch, unsigned* __restrict__ curL,
    unsigned* __restrict__ curP, uint4* __restrict__ edgeL,
    int* __restrict__ idxL, int* __restrict__ idxP){
  int e = blockIdx.x*256 + threadIdx.x;
  if (e >= En) return;
  int s = esrc[e], d = edst[e];
  float dd = ea[e];
  int bin = (int)(dd * 819.2f);
  bin = (bin < 0) ? 0 : ((bin > 4095) ? 4095 : bin);
  unsigned pl = atomicAdd(&curL[s], 1u);
  uint4 er; er.x = (unsigned)s; er.y = (unsigned)d;
  er.z = __float_as_uint(dd); er.w = (unsigned)lbatch[s];
  edgeL[pl] = er;
  idxL[pl] = d | (bin << 18);
  unsigned pp = atomicAdd(&curP[d], 1u);
  idxP[pp] = s | (bin << 18);
}

// ---- fused dual-direction conv, dword gather, 512 threads, unroll-8,
//      bijective L/P grid interleave for tail balance ----
#define EDGE_CAP 1024
__global__ __launch_bounds__(512, 8) void k_conv2(
    const unsigned short* __restrict__ xp_in, const unsigned short* __restrict__ xl_in,
    unsigned short* __restrict__ xp_out, unsigned short* __restrict__ xl_out,
    unsigned short* __restrict__ xp_sum, unsigned short* __restrict__ xl_sum,
    const unsigned* __restrict__ rowptrP, const int* __restrict__ idxP,
    const unsigned* __restrict__ rowptrL, const int* __restrict__ idxL,
    const unsigned short* __restrict__ lut_lp,
    const unsigned short* __restrict__ wcat_lp, const float* __restrict__ bias_lp,
    const unsigned short* __restrict__ lut_pl,
    const unsigned short* __restrict__ wcat_pl, const float* __restrict__ bias_pl,
    int first){
  __shared__ unsigned short ab[32][264];   // [m][k]: k<128 x_dst, k>=128 agg (bf16)
  __shared__ unsigned short ob[32][136];   // epilogue bf16
  __shared__ int snb[EDGE_CAP];
  __shared__ unsigned rps[33];
  int tid = threadIdx.x;
  int c2 = tid & 63, grp = tid >> 6;       // 8 groups x 64 col-pairs x 4 rows
  // bijective L/P interleave: heavy L-blocks spread through the grid
  int bid = blockIdx.x;
  bool isP; int pb;
  if ((bid & 3) == 3){ isP = false; pb = bid >> 2; }
  else if (bid == 6250){ isP = false; pb = 1562; }
  else { isP = true; pb = (bid >> 2)*3 + (bid & 3); }
  const unsigned short* xdst_in = isP ? xp_in : xl_in;
  const unsigned short* xsrc_in = isP ? xl_in : xp_in;
  unsigned short* xout = isP ? xp_out : xl_out;
  unsigned short* xsum = isP ? xp_sum : xl_sum;
  const unsigned* rowptr = isP ? rowptrP : rowptrL;
  const int* eidx = isP ? idxP : idxL;
  const unsigned short* lut_i = isP ? lut_lp : lut_pl;
  const unsigned short* wcat = isP ? wcat_lp : wcat_pl;
  const float* bias = isP ? bias_lp : bias_pl;
  int ndst = isP ? NPn : NLn;
  int n0 = pb * 32;

  if (tid < 33){
    int idx = n0 + tid; if (idx > ndst) idx = ndst;
    rps[tid] = rowptr[idx];
  }
  __syncthreads();
  int r00 = (int)rps[0], rEnd = (int)rps[32];
  int eblk = rEnd - r00;
  bool fits = (eblk <= EDGE_CAP);
  if (fits){
    for (int p = tid; p < eblk; p += 512) snb[p] = eidx[r00 + p];
  }
  __syncthreads();

  const unsigned short* lutc = lut_i + 2*c2;
  const unsigned short* xc = xsrc_in + 2*c2;
  for (int m = grp*4; m < grp*4+4; m++){
    int n = n0 + m;
    float al0=0.f,ah0=0.f,al1=0.f,ah1=0.f,al2=0.f,ah2=0.f,al3=0.f,ah3=0.f;
    int dg = 1;
    if (n < ndst){
      *(unsigned*)&ab[m][2*c2] = *(const unsigned*)&xdst_in[(size_t)n*128 + 2*c2];
      int r0 = (int)rps[m], r1 = (int)rps[m+1];
      dg = r1 - r0;
      int p = r0;
      for (; p + 7 < r1; p += 8){
        int v[8];
        #pragma unroll
        for (int j=0;j<8;j++) v[j] = fits ? snb[p-r00+j] : eidx[p+j];
        unsigned lv[8], xv[8];
        #pragma unroll
        for (int j=0;j<8;j++){
          lv[j] = *(const unsigned*)&lutc[(size_t)((unsigned)v[j] >> 18)*128];
          xv[j] = *(const unsigned*)&xc[(size_t)(v[j] & 0x3FFFF)*128];
        }
        #pragma unroll
        for (int j=0;j<8;j++){
          switch (j & 3){
            case 0: al0 += bflo(lv[j])*bflo(xv[j]); ah0 += bfhi(lv[j])*bfhi(xv[j]); break;
            case 1: al1 += bflo(lv[j])*bflo(xv[j]); ah1 += bfhi(lv[j])*bfhi(xv[j]); break;
            case 2: al2 += bflo(lv[j])*bflo(xv[j]); ah2 += bfhi(lv[j])*bfhi(xv[j]); break;
            default: al3 += bflo(lv[j])*bflo(xv[j]); ah3 += bfhi(lv[j])*bfhi(xv[j]); break;
          }
        }
      }
      for (; p + 3 < r1; p += 4){
        int v0,v1,v2,v3;
        if (fits){
          v0 = snb[p-r00]; v1 = snb[p-r00+1]; v2 = snb[p-r00+2]; v3 = snb[p-r00+3];
        } else {
          v0 = eidx[p]; v1 = eidx[p+1]; v2 = eidx[p+2]; v3 = eidx[p+3];
        }
        unsigned l0 = *(const unsigned*)&lutc[(size_t)((unsigned)v0 >> 18)*128];
        unsigned x0 = *(const unsigned*)&xc[(size_t)(v0 & 0x3FFFF)*128];
        unsigned l1 = *(const unsigned*)&lutc[(size_t)((unsigned)v1 >> 18)*128];
        unsigned x1 = *(const unsigned*)&xc[(size_t)(v1 & 0x3FFFF)*128];
        unsigned l2 = *(const unsigned*)&lutc[(size_t)((unsigned)v2 >> 18)*128];
        unsigned x2 = *(const unsigned*)&xc[(size_t)(v2 & 0x3FFFF)*128];
        unsigned l3 = *(const unsigned*)&lutc[(size_t)((unsigned)v3 >> 18)*128];
        unsigned x3 = *(const unsigned*)&xc[(size_t)(v3 & 0x3FFFF)*128];
        al0 += bflo(l0)*bflo(x0); ah0 += bfhi(l0)*bfhi(x0);
        al1 += bflo(l1)*bflo(x1); ah1 += bfhi(l1)*bfhi(x1);
        al2 += bflo(l2)*bflo(x2); ah2 += bfhi(l2)*bfhi(x2);
        al3 += bflo(l3)*bflo(x3); ah3 += bfhi(l3)*bfhi(x3);
      }
      for (; p < r1; p++){
        int v0 = fits ? snb[p-r00] : eidx[p];
        unsigned l0 = *(const unsigned*)&lutc[(size_t)((unsigned)v0 >> 18)*128];
        unsigned x0 = *(const unsigned*)&xc[(size_t)(v0 & 0x3FFFF)*128];
        al0 += bflo(l0)*bflo(x0); ah0 += bfhi(l0)*bfhi(x0);
      }
    } else {
      *(unsigned*)&ab[m][2*c2] = 0u;
    }
    float inv = 1.f / (float)(dg > 1 ? dg : 1);
    float alo = ((al0+al1)+(al2+al3)) * inv;
    float ahi = ((ah0+ah1)+(ah2+ah3)) * inv;
    *(unsigned*)&ab[m][128 + 2*c2] = (unsigned)f2bf(alo) | ((unsigned)f2bf(ahi) << 16);
  }
  __syncthreads();

  int wave = tid >> 6, lane = tid & 63, quad = lane >> 4, l15 = lane & 15;
  int mt = wave & 1, nh = wave >> 1;       // nh in [0,4)
  int arow = mt*16 + l15;
  float4v acc[2] = {{0,0,0,0},{0,0,0,0}};
  for (int k0 = 0; k0 < 256; k0 += 32){
    short8 A = *(const short8*)&ab[arow][k0 + quad*8];
    #pragma unroll
    for (int nt=0;nt<2;nt++){
      short8 B = *(const short8*)&wcat[(size_t)(nh*32 + nt*16 + l15)*256 + k0 + quad*8];
      acc[nt] = __builtin_amdgcn_mfma_f32_16x16x32_bf16(A, B, acc[nt], 0, 0, 0);
    }
  }
  #pragma unroll
  for (int nt=0;nt<2;nt++){
    int col = nh*32 + nt*16 + l15;
    float bc = bias[col];
    #pragma unroll
    for (int r=0;r<4;r++){
      int row = mt*16 + quad*4 + r;
      float v = acc[nt][r] + bc;
      ob[row][col] = f2bf((v > 0.f) ? v : 0.01f*v);    // leaky_relu
    }
  }
  __syncthreads();
  for (int m = grp*4; m < grp*4+4; m++){
    int n = n0 + m;
    if (n < ndst){
      unsigned vb = *(unsigned*)&ob[m][2*c2];
      size_t off = (size_t)n*128 + 2*c2;
      *(unsigned*)&xout[off] = vb;
      if (first){
        *(unsigned*)&xsum[off] = vb;
      } else {
        unsigned so = *(unsigned*)&xsum[off];
        float lo = bflo(so) + bflo(vb);
        float hi = bfhi(so) + bfhi(vb);
        *(unsigned*)&xsum[off] = (unsigned)f2bf(lo) | ((unsigned)f2bf(hi) << 16);
      }
    }
  }
}

// ---- hproj v3: persistent, register-resident B. 1024 blocks x 512 thr;
//      blocks [0,256): ligand (+b1), [256,1024): protein. Per wave: N-strip
//      of 64 cols, Bk[4][4] short8 = 64 VGPR loaded once; ~6 tiles/block.
//      w1t traffic 800MB -> 131MB.
__global__ __launch_bounds__(512) void k_hproj3(
    const unsigned short* __restrict__ xl_s, const unsigned short* __restrict__ xp_s,
    const unsigned short* __restrict__ w1t, const float* __restrict__ b1,
    unsigned* __restrict__ h_l, unsigned* __restrict__ h_p){
  __shared__ unsigned short hb[32][528];
  int tid = threadIdx.x, lane = tid & 63, wave = tid >> 6;
  int quad = lane >> 4, l15 = lane & 15;
  bool isL = blockIdx.x < 256;
  const unsigned short* xs = isL ? xl_s : xp_s;
  const unsigned short* wt = isL ? w1t : w1t + 65536;
  unsigned* hout = isL ? h_l : h_p;
  int nn = isL ? NLn : NPn;
  int ntile = isL ? NBL : NBP;
  int wg = isL ? blockIdx.x : blockIdx.x - 256;
  int stride = isL ? 256 : 768;

  // register-resident B: wave's N-strip = cols [wave*64, wave*64+64)
  short8 Bk[4][4];
  float bv[4];
  #pragma unroll
  for (int nt=0;nt<4;nt++){
    int row = wave*64 + nt*16 + l15;
    #pragma unroll
    for (int kk=0;kk<4;kk++)
      Bk[nt][kk] = *(const short8*)&wt[(size_t)row*128 + kk*32 + quad*8];
    bv[nt] = isL ? b1[row] : 0.f;
  }

  for (int t = wg; t < ntile; t += stride){
    int n0 = t*32;
    int a0r = n0 + l15;      if (a0r >= nn) a0r = nn-1;
    int a1r = n0 + 16 + l15; if (a1r >= nn) a1r = nn-1;
    float4v acc[2][4];
    #pragma unroll
    for (int m2=0;m2<2;m2++)
      #pragma unroll
      for (int nt=0;nt<4;nt++) acc[m2][nt] = (float4v){0,0,0,0};
    #pragma unroll
    for (int kk=0;kk<4;kk++){
      short8 A0 = *(const short8*)&xs[(size_t)a0r*128 + kk*32 + quad*8];
      short8 A1 = *(const short8*)&xs[(size_t)a1r*128 + kk*32 + quad*8];
      #pragma unroll
      for (int nt=0;nt<4;nt++){
        acc[0][nt] = __builtin_amdgcn_mfma_f32_16x16x32_bf16(A0, Bk[nt][kk], acc[0][nt], 0, 0, 0);
        acc[1][nt] = __builtin_amdgcn_mfma_f32_16x16x32_bf16(A1, Bk[nt][kk], acc[1][nt], 0, 0, 0);
      }
    }
    #pragma unroll
    for (int m2=0;m2<2;m2++){
      #pragma unroll
      for (int nt=0;nt<4;nt++){
        int col = wave*64 + nt*16 + l15;
        #pragma unroll
        for (int r=0;r<4;r++)
          hb[m2*16 + quad*4 + r][col] = f2bf(acc[m2][nt][r] + bv[nt]);
      }
    }
    __syncthreads();
    for (int idx = tid; idx < 8192; idx += 512){
      int m = idx >> 8, d = idx & 255;
      int n = n0 + m;
      if (n < nn){
        unsigned pack = (unsigned)hb[m][2*d] | ((unsigned)hb[m][2*d+1] << 16);
        hout[(size_t)n*256 + d] = pack;
      }
    }
    __syncthreads();
  }
}

// ---- readout v10: persistent + reg-resident B + cross-tile pipeline. ----
__global__ __launch_bounds__(512) void k_readout4(
    const unsigned* __restrict__ hl, const unsigned* __restrict__ hp,
    const uint4* __restrict__ edgeL, const float* __restrict__ vvec,
    const unsigned short* __restrict__ w2t, const float* __restrict__ b2,
    const unsigned short* __restrict__ wmt, const float* __restrict__ bm,
    float* __restrict__ outw, unsigned* __restrict__ mmax){
  __shared__ __align__(16) unsigned short lds[37120];   // 2x16384 hbuf + msb
  unsigned short (*msb)[136] = (unsigned short(*)[136])(lds + 32768);
  int tid = threadIdx.x, lane = tid & 63, wave = tid >> 6;
  int quad = lane >> 4, l15 = lane & 15;
  int ns = wave*16;                // this wave's N-strip for both GEMMs

  // XCD-chunked tile mapping
  int wg = (blockIdx.x & 7)*128 + (blockIdx.x >> 3);   // bijective [0,1024)
  int nt_tot = En/32;
  int t0 = wg*16;
  int t1 = t0 + 16; if (t1 > nt_tot) t1 = nt_tot;
  if (t0 >= t1) return;

  // ---- register-resident B: w2t strip (64 VGPR) + wmt strip (16 VGPR) ----
  short8 Bk[16];
  #pragma unroll
  for (int kk=0;kk<16;kk++)
    Bk[kk] = *(const short8*)&w2t[(size_t)(ns + l15)*512 + kk*32 + quad*8];
  short8 Bm[4];
  #pragma unroll
  for (int kk=0;kk<4;kk++)
    Bm[kk] = *(const short8*)&wmt[(size_t)(ns + l15)*128 + kk*32 + quad*8];
  float b2c0 = b2[ns + l15];
  float bm0  = bm[ns + l15];

  // vvec for chunk `lane`: h columns [8*lane, 8*lane+8)
  float4v vva = *(const float4v*)&vvec[lane*8];
  float4v vvb = *(const float4v*)&vvec[lane*8 + 4];
  int sw = lane & 31;
  const uint4* hl4 = (const uint4*)hl;   // one h row = 64 uint4
  const uint4* hp4 = (const uint4*)hp;
  const unsigned* e32 = (const unsigned*)edgeL;

  int si_prev = -1;
  uint4 ua = {0,0,0,0};
  int lm = wave*16 + (lane & 15);        // metadata dword index for this wave
  int le = lane & 31;                    // epilogue edge index

  #define H_EDGE(UA, UB, DD, I, WB)                                          \
    {                                                                        \
      unsigned o0,o1,o2,o3; float hx,hy;                                     \
      hx = fmaxf(bflo(UA.x)+bflo(UB.x)+(DD)*vva.x, 0.f);                     \
      hy = fmaxf(bfhi(UA.x)+bfhi(UB.x)+(DD)*vva.y, 0.f);                     \
      o0 = (unsigned)f2bf(hx) | ((unsigned)f2bf(hy) << 16);                  \
      hx = fmaxf(bflo(UA.y)+bflo(UB.y)+(DD)*vva.z, 0.f);                     \
      hy = fmaxf(bfhi(UA.y)+bfhi(UB.y)+(DD)*vva.w, 0.f);                     \
      o1 = (unsigned)f2bf(hx) | ((unsigned)f2bf(hy) << 16);                  \
      hx = fmaxf(bflo(UA.z)+bflo(UB.z)+(DD)*vvb.x, 0.f);                     \
      hy = fmaxf(bfhi(UA.z)+bfhi(UB.z)+(DD)*vvb.y, 0.f);                     \
      o2 = (unsigned)f2bf(hx) | ((unsigned)f2bf(hy) << 16);                  \
      hx = fmaxf(bflo(UA.w)+bflo(UB.w)+(DD)*vvb.z, 0.f);                     \
      hy = fmaxf(bfhi(UA.w)+bfhi(UB.w)+(DD)*vvb.w, 0.f);                     \
      o3 = (unsigned)f2bf(hx) | ((unsigned)f2bf(hy) << 16);                  \
      uint4 ov; ov.x=o0; ov.y=o1; ov.z=o2; ov.w=o3;                          \
      *(uint4*)&lds[(WB) + lane*256 + (((I) ^ sw) << 3)] = ov;               \
    }

  // ---- prologue: tile t0 -> hbuf0; load md1/br1 for t0+1 ----
  unsigned md1 = 0; int br_cur = 0, br1 = 0;
  {
    unsigned md0 = e32[(size_t)t0*128 + lm];
    br_cur = (int)e32[((size_t)(t0*32 + le))*4 + 3];
    #pragma unroll
    for (int ii=0; ii<4; ii++){
      int si = __builtin_amdgcn_readfirstlane(__shfl((int)md0, ii*4));
      int di = __builtin_amdgcn_readfirstlane(__shfl((int)md0, ii*4 + 1));
      float dd = __uint_as_float((unsigned)__builtin_amdgcn_readfirstlane(__shfl((int)md0, ii*4 + 2)));
      if (si != si_prev){ ua = hl4[(size_t)si*64 + lane]; si_prev = si; }
      uint4 ub = hp4[(size_t)di*64 + lane];
      H_EDGE(ua, ub, dd, wave*4 + ii, 0)
    }
    if (t0 + 1 < t1){
      md1 = e32[(size_t)(t0+1)*128 + lm];
      br1 = (int)e32[((size_t)((t0+1)*32 + le))*4 + 3];
    }
    __syncthreads();
  }

  int cur = 0;
  unsigned md2 = md1; int br2 = br1;
  for (int t = t0; t < t1; ++t){
    bool pf = (t + 1 < t1);
    // issue next-next metadata
    if (t + 2 < t1){
      md2 = e32[(size_t)(t+2)*128 + lm];
      br2 = (int)e32[((size_t)((t+2)*32 + le))*4 + 3];
    }
    // issue hp gathers + deduped hl for tile t+1 (consumed after GEMM2)
    uint4 ub0, ub1, ub2, ub3;
    if (pf){
      int d0 = __builtin_amdgcn_readfirstlane(__shfl((int)md1, 1));
      int d1 = __builtin_amdgcn_readfirstlane(__shfl((int)md1, 5));
      int d2 = __builtin_amdgcn_readfirstlane(__shfl((int)md1, 9));
      int d3 = __builtin_amdgcn_readfirstlane(__shfl((int)md1, 13));
      ub0 = hp4[(size_t)d0*64 + lane];
      ub1 = hp4[(size_t)d1*64 + lane];
      ub2 = hp4[(size_t)d2*64 + lane];
      ub3 = hp4[(size_t)d3*64 + lane];
      int s0 = __builtin_amdgcn_readfirstlane(__shfl((int)md1, 0));
      if (s0 != si_prev){ ua = hl4[(size_t)s0*64 + lane]; si_prev = s0; }
    }

    int rb = cur ? 16384 : 0;
    // GEMM1: m[32,128] = h[32,512] @ W2^T + b2  (B from registers)
    float4v acc[2] = {{0,0,0,0},{0,0,0,0}};
    #pragma unroll
    for (int kk = 0; kk < 16; kk++){
      int kcc = kk*4 + quad;
      int sw2 = kcc & 31;
      short8 A0 = *(const short8*)&lds[rb + kcc*256 + ((l15 ^ sw2) << 3)];
      short8 A1 = *(const short8*)&lds[rb + kcc*256 + (((16 + l15) ^ sw2) << 3)];
      acc[0] = __builtin_amdgcn_mfma_f32_16x16x32_bf16(A0, Bk[kk], acc[0], 0, 0, 0);
      acc[1] = __builtin_amdgcn_mfma_f32_16x16x32_bf16(A1, Bk[kk], acc[1], 0, 0, 0);
    }
    float mreg[2][4];
    #pragma unroll
    for (int mt=0;mt<2;mt++){
      int col = ns + l15;
      #pragma unroll
      for (int r=0;r<4;r++){
        float mv = acc[mt][r] + b2c0;
        mreg[mt][r] = mv;
        msb[mt*16 + quad*4 + r][col] = f2bf(mv);
      }
    }
    __syncthreads();    // barrier A: msb visible

    // GEMM2: t = tanh(m@Wm^T + bm); flush sum(t*m), max(m) per batch
    float4v acc2[2] = {{0,0,0,0},{0,0,0,0}};
    #pragma unroll
    for (int kk = 0; kk < 4; kk++){
      short8 A0 = *(const short8*)&msb[l15][kk*32 + quad*8];
      short8 A1 = *(const short8*)&msb[16 + l15][kk*32 + quad*8];
      acc2[0] = __builtin_amdgcn_mfma_f32_16x16x32_bf16(A0, Bm[kk], acc2[0], 0, 0, 0);
      acc2[1] = __builtin_amdgcn_mfma_f32_16x16x32_bf16(A1, Bm[kk], acc2[1], 0, 0, 0);
    }
    {
      int b0 = __shfl(br_cur, 0);
      bool uni = (b0 == __shfl(br_cur, 31));
      int col = ns + l15;
      if (uni){
        float s = 0.f, mx = -3.402823466e38f;
        #pragma unroll
        for (int mt=0;mt<2;mt++){
          #pragma unroll
          for (int r=0;r<4;r++){
            float mv = mreg[mt][r];
            float tt = tanh_fast(acc2[mt][r] + bm0);
            s += tt*mv; mx = fmaxf(mx, mv);
          }
        }
        s += __shfl_xor(s, 16); s += __shfl_xor(s, 32);
        mx = fmaxf(mx, __shfl_xor(mx, 16)); mx = fmaxf(mx, __shfl_xor(mx, 32));
        if (quad == 0){
          atomicAdd(&outw[b0*256 + col], s);
          atomicMax(&mmax[b0*128 + col], encf(mx));
        }
      } else {
        #pragma unroll
        for (int mt=0;mt<2;mt++){
          #pragma unroll
          for (int r=0;r<4;r++){
            int row = mt*16 + quad*4 + r;
            int b = __shfl(br_cur, row);
            float mv = mreg[mt][r];
            float tt = tanh_fast(acc2[mt][r] + bm0);
            atomicAdd(&outw[b*256 + col], tt*mv);
            atomicMax(&mmax[b*128 + col], encf(mv));
          }
        }
      }
    }

    // consume prefetched gathers -> h(t+1) into the other hbuf
    if (pf){
      int wb = cur ? 0 : 16384;
      #pragma unroll
      for (int ii=0; ii<4; ii++){
        int si = __builtin_amdgcn_readfirstlane(__shfl((int)md1, ii*4));
        float dd = __uint_as_float((unsigned)__builtin_amdgcn_readfirstlane(__shfl((int)md1, ii*4 + 2)));
        if (si != si_prev){ ua = hl4[(size_t)si*64 + lane]; si_prev = si; }
        uint4 ub = (ii==0) ? ub0 : (ii==1) ? ub1 : (ii==2) ? ub2 : ub3;
        H_EDGE(ua, ub, dd, wave*4 + ii, wb)
      }
    }
    __syncthreads();    // barrier B: hbuf[cur^1] + msb reads complete

    md1 = md2; br_cur = br1; br1 = br2;
    cur ^= 1;
  }
  #undef H_EDGE
}

__global__ __launch_bounds__(256) void k_final(const unsigned* __restrict__ mmax,
    float* __restrict__ out){
  int gid = blockIdx.x*256 + threadIdx.x;   // 32768 = 256*128
  unsigned enc = mmax[gid];
  float v;
  if (enc == 0u) v = 0.f;
  else if (enc & 0x80000000u) v = __uint_as_float(enc & 0x7FFFFFFFu);
  else v = __uint_as_float(~enc);
  int g = gid >> 7, cc = gid & 127;
  out[g*256 + 128 + cc] = v;
}

extern "C" void kernel_launch(void* const* d_in, const int* in_sizes, int n_in,
                              void* d_out, int out_size, void* d_ws, size_t ws_size,
                              hipStream_t stream) {
  const float* x_l    = (const float*)d_in[0];
  const float* x_p    = (const float*)d_in[1];
  const float* ea     = (const float*)d_in[2];
  const int*   esrc   = (const int*)d_in[3];
  const int*   edst   = (const int*)d_in[4];
  const int*   lbatch = (const int*)d_in[5];
  const float* W_node = (const float*)d_in[6];
  const float* W_el   = (const float*)d_in[7];
  const float* Wb     = (const float*)d_in[8];
  const float* bb     = (const float*)d_in[9];
  const float* Wn     = (const float*)d_in[10];
  const float* Ws     = (const float*)d_in[11];
  const float* bconv  = (const float*)d_in[12];
  const float* W1     = (const float*)d_in[13];
  const float* b1     = (const float*)d_in[14];
  const float* W2     = (const float*)d_in[15];
  const float* b2     = (const float*)d_in[16];
  const float* Wm     = (const float*)d_in[17];
  const float* bm     = (const float*)d_in[18];

  // ---- workspace layout (decimal offsets), peak 267,354,496 B ----
  char* w = (char*)d_ws;
  unsigned short* xl0 = (unsigned short*)(w + 0);
  unsigned short* xl1 = (unsigned short*)(w + 12800000);
  unsigned short* xp0 = (unsigned short*)(w + 25600000);
  unsigned short* xp1 = (unsigned short*)(w + 64000000);
  int*      idxP  = (int*)(w + 102400000);
  int*      idxL  = (int*)(w + 104400000);
  unsigned short* lut = (unsigned short*)(w + 106400000);   // 6.29e6 B
  unsigned* h_l   = (unsigned*)(w + 0);
  unsigned* h_p   = (unsigned*)(w + 51200000);
  unsigned short* xl_s = (unsigned short*)(w + 204800000);
  unsigned short* xp_s = (unsigned short*)(w + 217600000);
  unsigned short* wcat = (unsigned short*)(w + 256000000);
  unsigned short* w1t  = (unsigned short*)(w + 256393216);
  unsigned short* w2t  = (unsigned short*)(w + 256655360);
  unsigned short* wmt  = (unsigned short*)(w + 256786432);
  float*    vvec  = (float*)(w + 256819200);
  unsigned* mmax  = (unsigned*)(w + 256821248);
  unsigned* bsumL = (unsigned*)(w + 256952320);
  unsigned* bsumP = (unsigned*)(w + 256953344);
  unsigned* rowptrL = (unsigned*)(w + 256954368);
  unsigned* cursorL = (unsigned*)(w + 257154432);
  unsigned* rowptrP = (unsigned*)(w + 257354432);
  unsigned* cursorP = (unsigned*)(w + 257954496);
  unsigned* cntL    = (unsigned*)(w + 258554496);
  unsigned* cntP    = (unsigned*)(w + 258754496);
  uint4*    edgeL   = (uint4*)(w + 259354496);   // {src, dst, bits(d), batch}

  float* out = (float*)d_out;

  k_prep<<<14470, 256, 0, stream>>>(
      (unsigned*)(w + 258554496), mmax, (unsigned*)d_out,
      W_el, W1, vvec, W2, w2t, Wm, wmt, Ws, Wn, wcat, w1t, Wb, bb, lut);
  k_embed<<<NBL + NBP, 256, 0, stream>>>(x_l, x_p, W_node, xl0, xp0);

  k_count<<<1954, 256, 0, stream>>>(esrc, edst, cntL, cntP);
  k_cs2<<<196, 256, 0, stream>>>(cntL, rowptrL, bsumL, cntP, rowptrP, bsumP);
  k_sb2<<<2, 256, 0, stream>>>(bsumL, bsumP);
  k_ao2<<<782, 256, 0, stream>>>(rowptrL, cursorL, bsumL, rowptrP, cursorP, bsumP);
  k_place<<<1954, 256, 0, stream>>>(esrc, edst, ea, lbatch, cursorL, cursorP,
                                    edgeL, idxL, idxP);

  unsigned short *xlc = xl0, *xln = xl1, *xpc = xp0, *xpn = xp1;
  for (int l = 0; l < 3; ++l){
    int ilp = 2*l, ipl = 2*l + 1;
    k_conv2<<<NBP + NBL, 512, 0, stream>>>(
        xpc, xlc, xpn, xln, xp_s, xl_s,
        rowptrP, idxP, rowptrL, idxL,
        lut + (size_t)ilp*524288, wcat + ilp*32768, bconv + ilp*128,
        lut + (size_t)ipl*524288, wcat + ipl*32768, bconv + ipl*128,
        (l == 0) ? 1 : 0);
    unsigned short* t;
    t = xlc; xlc = xln; xln = t;
    t = xpc; xpc = xpn; xpn = t;
  }

  // b1 folded into h_l (ligand part); protein part no bias
  k_hproj3<<<1024, 512, 0, stream>>>(xl_s, xp_s, w1t, b1, h_l, h_p);

  k_readout4<<<1024, 512, 0, stream>>>(h_l, h_p, edgeL, vvec,
                                       w2t, b2, wmt, bm, out, mmax);
  k_final<<<128, 256, 0, stream>>>(mmax, out);
}

// Round 12
// 1078.671 us; speedup vs baseline: 1.6787x; 1.0155x over previous
//
#include <hip/hip_runtime.h>
#include <hip/hip_bf16.h>

// HeteroNet on MI355X — round 24.
// R23: 1224->1095us (prep LUT factorization + persistent hproj3 confirmed).
// readout4 272us is the top dispatch; VALU 40% top pipe. A block's 16 tiles
// = 512 CSR-contiguous edges ~= ONE graph -> per-tile epilogue flush is 16x
// redundant. Pipeline has T5's wave role-split (setprio applicable).
// R24 (readout only): (a) register-accumulated epilogue, flush on batch
// change / non-uni / end (~14/16 of shfl-reduces+atomics removed);
// (b) s_setprio(1) around MFMA clusters (T5).

#define NLn 50000
#define NPn 150000
#define En  500000
#define NBL 1563   // ceil(NLn/32)
#define NBP 4688   // ceil(NPn/32)

typedef __attribute__((ext_vector_type(8))) short short8;
typedef __attribute__((ext_vector_type(4))) float float4v;

__device__ __forceinline__ float bf2f(unsigned short u){ return __uint_as_float(((unsigned)u) << 16); }
__device__ __forceinline__ float bflo(unsigned u){ return __uint_as_float(u << 16); }
__device__ __forceinline__ float bfhi(unsigned u){ return __uint_as_float(u & 0xffff0000u); }
__device__ __forceinline__ unsigned short f2bf(float f){
  __hip_bfloat16 h = __float2bfloat16(f);
  return *reinterpret_cast<unsigned short*>(&h);
}
// order-preserving float->uint; enc(v)>0 for all finite v, so 0 == "empty segment"
__device__ __forceinline__ unsigned encf(float f){
  unsigned u = __float_as_uint(f);
  return (u & 0x80000000u) ? ~u : (u | 0x80000000u);
}
__device__ __forceinline__ float tanh_fast(float x){
  return 1.f - 2.f/(__expf(2.f*x) + 1.f);
}

// ---- k_embed: X @ W_node -> bf16, 32 rows/block, register-tiled ----
__global__ __launch_bounds__(256) void k_embed(
    const float* __restrict__ Xl, const float* __restrict__ Xp,
    const float* __restrict__ Wnode,
    unsigned short* __restrict__ xl0, unsigned short* __restrict__ xp0){
  __shared__ float xs[1408];   // 32 rows x 44 fp32
  int b = blockIdx.x, tid = threadIdx.x;
  bool isL = b < NBL;
  const float* X = isL ? Xl : Xp;
  unsigned short* out = isL ? xl0 : xp0;
  int n = isL ? NLn : NPn;
  int n0 = (isL ? b : b - NBL) * 32;
  int nrows = n - n0; if (nrows > 32) nrows = 32;
  int nflt = nrows * 44;                            // multiple of 4
  const float4* Xv = (const float4*)(X + (size_t)n0*44);
  for (int j = tid; j*4 < nflt; j += 256){
    float4 v = Xv[j];
    xs[j*4+0]=v.x; xs[j*4+1]=v.y; xs[j*4+2]=v.z; xs[j*4+3]=v.w;
  }
  __syncthreads();
  int c = tid & 127, half = tid >> 7;
  float acc[16];
  #pragma unroll
  for (int r=0;r<16;r++) acc[r]=0.f;
  const float* xrow = xs + half*16*44;
  #pragma unroll 4
  for (int k=0;k<44;k++){
    float w = Wnode[k*128 + c];
    #pragma unroll
    for (int r=0;r<16;r++) acc[r] += xrow[r*44 + k] * w;
  }
  int rbase = n0 + half*16;
  #pragma unroll
  for (int r=0;r<16;r++){
    int nn = rbase + r;
    if (nn < n) out[(size_t)nn*128 + c] = f2bf(acc[r]);
  }
}

// ---- k_prep: zeros + weight transforms + LUT (gaussian-factored) ----
__global__ __launch_bounds__(256) void k_prep(
    unsigned* __restrict__ cntz, unsigned* __restrict__ mmaxz, unsigned* __restrict__ outz,
    const float* __restrict__ Wel, const float* __restrict__ W1, float* __restrict__ vvec,
    const float* __restrict__ W2, unsigned short* __restrict__ w2t,
    const float* __restrict__ Wm, unsigned short* __restrict__ wmt,
    const float* __restrict__ Ws, const float* __restrict__ Wn,
    unsigned short* __restrict__ wcat, unsigned short* __restrict__ w1t,
    const float* __restrict__ Wb, const float* __restrict__ bb,
    unsigned short* __restrict__ lut){
  __shared__ float gw[16];   // 2 bins x 8 gaussians (LUT branch only)
  int b = blockIdx.x, tid = threadIdx.x;
  if (b < 196){
    for (long i = (long)b*256 + tid; i < 200000; i += 196*256) cntz[i] = 0u;
  } else if (b < 324){
    mmaxz[(b-196)*256 + tid] = 0u;
  } else if (b < 580){
    outz[(b-324)*256 + tid] = 0u;
  } else if (b < 582){
    int j = (b-580)*256 + tid;
    float s = 0.f;
    #pragma unroll
    for (int r=0;r<8;r++) s += Wel[r]*W1[(256+r)*512 + j];
    vvec[j] = s;
  } else if (b < 838){
    int gid = (b-582)*256 + tid;                       // 65536
    int n = gid >> 9, k = gid & 511;
    w2t[n*512 + k] = f2bf(W2[k*128 + n]);
  } else if (b < 902){
    int gid = (b-838)*256 + tid;                       // 16384
    int n = gid >> 7, k = gid & 127;
    wmt[n*128 + k] = f2bf(Wm[k*128 + n]);
  } else if (b < 1670){
    int gid = (b-902)*256 + tid;                       // 196608
    int i = gid >> 15, rem = gid & 32767;
    int n = rem >> 8, k = rem & 255;
    float v = (k < 128) ? Ws[i*16384 + k*128 + n] : Wn[i*16384 + (k-128)*128 + n];
    wcat[gid] = f2bf(v);
  } else if (b < 2182){
    int gid = (b-1670)*256 + tid;                      // 131072
    int part = gid >> 16, rem = gid & 65535;
    int n = rem >> 7, k = rem & 127;
    w1t[gid] = f2bf(W1[(part*128 + k)*512 + n]);
  } else {
    int gid0 = (b-2182)*256;                           // 3145728 total
    int c = tid & 127, half = tid >> 7;
    int bin0 = (gid0 >> 7) & 4095;                     // even; block covers bin0, bin0+1
    int i = gid0 >> 19;                                // constant per block
    if (tid < 16){
      int bn = bin0 + (tid >> 3), j = tid & 7;
      float d = ((float)bn + 0.5f) * 0.001220703125f;  // *5/4096
      float a = (d - 0.7142857143f*(float)j) * 1.6f;
      gw[tid] = __expf(-a*a);
    }
    __syncthreads();
    float s = bb[i*128 + c];
    const float* g = gw + half*8;
    #pragma unroll
    for (int j=0;j<8;j++) s += g[j] * Wb[i*1024 + j*128 + c];
    lut[gid0 + tid] = f2bf(s / (1.f + __expf(-s)));
  }
}

// ---- CSR construction ----
__global__ __launch_bounds__(256) void k_count(const int* __restrict__ esrc,
    const int* __restrict__ edst, unsigned* __restrict__ cntL, unsigned* __restrict__ cntP){
  int e = blockIdx.x*256 + threadIdx.x;
  if (e >= En) return;
  atomicAdd(&cntL[esrc[e]], 1u);
  atomicAdd(&cntP[edst[e]], 1u);
}
__global__ __launch_bounds__(256) void k_cs2(const unsigned* __restrict__ cntL,
    unsigned* __restrict__ rowptrL, unsigned* __restrict__ bsumL,
    const unsigned* __restrict__ cntP, unsigned* __restrict__ rowptrP,
    unsigned* __restrict__ bsumP){
  bool isL = blockIdx.x < 49;
  const unsigned* cnt = isL ? cntL : cntP;
  unsigned* rowptr = isL ? rowptrL : rowptrP;
  unsigned* bsum = isL ? bsumL : bsumP;
  int n = isL ? NLn : NPn;
  int lb = isL ? blockIdx.x : blockIdx.x - 49;
  __shared__ unsigned ts[256];
  int tid = threadIdx.x;
  int base = lb*1024 + tid*4;
  unsigned v[4], run = 0;
  #pragma unroll
  for (int j=0;j<4;j++){ v[j] = run; run += (base+j < n) ? cnt[base+j] : 0u; }
  ts[tid] = run; __syncthreads();
  for (int off=1; off<256; off<<=1){
    unsigned t = (tid>=off) ? ts[tid-off] : 0u; __syncthreads();
    ts[tid] += t; __syncthreads();
  }
  unsigned excl = ts[tid] - run;
  #pragma unroll
  for (int j=0;j<4;j++) if (base+j < n) rowptr[base+j] = excl + v[j];
  if (tid == 255) bsum[lb] = ts[255];
}
__global__ void k_sb2(unsigned* __restrict__ bsumL, unsigned* __restrict__ bsumP){
  unsigned* bsum = blockIdx.x ? bsumP : bsumL;
  int nc = blockIdx.x ? 147 : 49;
  __shared__ unsigned ts[256];
  int tid = threadIdx.x;
  unsigned x = (tid < nc) ? bsum[tid] : 0u;
  ts[tid] = x; __syncthreads();
  for (int off=1; off<256; off<<=1){
    unsigned t = (tid>=off) ? ts[tid-off] : 0u; __syncthreads();
    ts[tid] += t; __syncthreads();
  }
  if (tid < nc) bsum[tid] = ts[tid] - x;
}
__global__ __launch_bounds__(256) void k_ao2(
    unsigned* __restrict__ rowptrL, unsigned* __restrict__ cursorL,
    const unsigned* __restrict__ bsumL,
    unsigned* __restrict__ rowptrP, unsigned* __restrict__ cursorP,
    const unsigned* __restrict__ bsumP){
  bool isL = blockIdx.x < 196;
  unsigned* rowptr = isL ? rowptrL : rowptrP;
  unsigned* cursor = isL ? cursorL : cursorP;
  const unsigned* bsum = isL ? bsumL : bsumP;
  int n = isL ? NLn : NPn;
  int i = (isL ? blockIdx.x : blockIdx.x - 196)*256 + threadIdx.x;
  if (i < n){
    unsigned r = rowptr[i] + bsum[i>>10];
    rowptr[i] = r; cursor[i] = r;
  }
  if (i == 0) rowptr[n] = En;
}
__global__ __launch_bounds__(256) void k_place(const int* __restrict__ esrc,
    const int* __restrict__ edst, const float* __restrict__ ea,
    const int* __restrict__ lbatch, unsigned* __restrict__ curL,
    unsigned* __restrict__ curP, uint4* __restrict__ edgeL,
    int* __restrict__ idxL, int* __restrict__ idxP){
  int e = blockIdx.x*256 + threadIdx.x;
  if (e >= En) return;
  int s = esrc[e], d = edst[e];
  float dd = ea[e];
  int bin = (int)(dd * 819.2f);
  bin = (bin < 0) ? 0 : ((bin > 4095) ? 4095 : bin);
  unsigned pl = atomicAdd(&curL[s], 1u);
  uint4 er; er.x = (unsigned)s; er.y = (unsigned)d;
  er.z = __float_as_uint(dd); er.w = (unsigned)lbatch[s];
  edgeL[pl] = er;
  idxL[pl] = d | (bin << 18);
  unsigned pp = atomicAdd(&curP[d], 1u);
  idxP[pp] = s | (bin << 18);
}

// ---- fused dual-direction conv, dword gather, 512 threads, unroll-8,
//      bijective L/P grid interleave for tail balance ----
#define EDGE_CAP 1024
__global__ __launch_bounds__(512, 8) void k_conv2(
    const unsigned short* __restrict__ xp_in, const unsigned short* __restrict__ xl_in,
    unsigned short* __restrict__ xp_out, unsigned short* __restrict__ xl_out,
    unsigned short* __restrict__ xp_sum, unsigned short* __restrict__ xl_sum,
    const unsigned* __restrict__ rowptrP, const int* __restrict__ idxP,
    const unsigned* __restrict__ rowptrL, const int* __restrict__ idxL,
    const unsigned short* __restrict__ lut_lp,
    const unsigned short* __restrict__ wcat_lp, const float* __restrict__ bias_lp,
    const unsigned short* __restrict__ lut_pl,
    const unsigned short* __restrict__ wcat_pl, const float* __restrict__ bias_pl,
    int first){
  __shared__ unsigned short ab[32][264];   // [m][k]: k<128 x_dst, k>=128 agg (bf16)
  __shared__ unsigned short ob[32][136];   // epilogue bf16
  __shared__ int snb[EDGE_CAP];
  __shared__ unsigned rps[33];
  int tid = threadIdx.x;
  int c2 = tid & 63, grp = tid >> 6;       // 8 groups x 64 col-pairs x 4 rows
  // bijective L/P interleave: heavy L-blocks spread through the grid
  int bid = blockIdx.x;
  bool isP; int pb;
  if ((bid & 3) == 3){ isP = false; pb = bid >> 2; }
  else if (bid == 6250){ isP = false; pb = 1562; }
  else { isP = true; pb = (bid >> 2)*3 + (bid & 3); }
  const unsigned short* xdst_in = isP ? xp_in : xl_in;
  const unsigned short* xsrc_in = isP ? xl_in : xp_in;
  unsigned short* xout = isP ? xp_out : xl_out;
  unsigned short* xsum = isP ? xp_sum : xl_sum;
  const unsigned* rowptr = isP ? rowptrP : rowptrL;
  const int* eidx = isP ? idxP : idxL;
  const unsigned short* lut_i = isP ? lut_lp : lut_pl;
  const unsigned short* wcat = isP ? wcat_lp : wcat_pl;
  const float* bias = isP ? bias_lp : bias_pl;
  int ndst = isP ? NPn : NLn;
  int n0 = pb * 32;

  if (tid < 33){
    int idx = n0 + tid; if (idx > ndst) idx = ndst;
    rps[tid] = rowptr[idx];
  }
  __syncthreads();
  int r00 = (int)rps[0], rEnd = (int)rps[32];
  int eblk = rEnd - r00;
  bool fits = (eblk <= EDGE_CAP);
  if (fits){
    for (int p = tid; p < eblk; p += 512) snb[p] = eidx[r00 + p];
  }
  __syncthreads();

  const unsigned short* lutc = lut_i + 2*c2;
  const unsigned short* xc = xsrc_in + 2*c2;
  for (int m = grp*4; m < grp*4+4; m++){
    int n = n0 + m;
    float al0=0.f,ah0=0.f,al1=0.f,ah1=0.f,al2=0.f,ah2=0.f,al3=0.f,ah3=0.f;
    int dg = 1;
    if (n < ndst){
      *(unsigned*)&ab[m][2*c2] = *(const unsigned*)&xdst_in[(size_t)n*128 + 2*c2];
      int r0 = (int)rps[m], r1 = (int)rps[m+1];
      dg = r1 - r0;
      int p = r0;
      for (; p + 7 < r1; p += 8){
        int v[8];
        #pragma unroll
        for (int j=0;j<8;j++) v[j] = fits ? snb[p-r00+j] : eidx[p+j];
        unsigned lv[8], xv[8];
        #pragma unroll
        for (int j=0;j<8;j++){
          lv[j] = *(const unsigned*)&lutc[(size_t)((unsigned)v[j] >> 18)*128];
          xv[j] = *(const unsigned*)&xc[(size_t)(v[j] & 0x3FFFF)*128];
        }
        #pragma unroll
        for (int j=0;j<8;j++){
          switch (j & 3){
            case 0: al0 += bflo(lv[j])*bflo(xv[j]); ah0 += bfhi(lv[j])*bfhi(xv[j]); break;
            case 1: al1 += bflo(lv[j])*bflo(xv[j]); ah1 += bfhi(lv[j])*bfhi(xv[j]); break;
            case 2: al2 += bflo(lv[j])*bflo(xv[j]); ah2 += bfhi(lv[j])*bfhi(xv[j]); break;
            default: al3 += bflo(lv[j])*bflo(xv[j]); ah3 += bfhi(lv[j])*bfhi(xv[j]); break;
          }
        }
      }
      for (; p + 3 < r1; p += 4){
        int v0,v1,v2,v3;
        if (fits){
          v0 = snb[p-r00]; v1 = snb[p-r00+1]; v2 = snb[p-r00+2]; v3 = snb[p-r00+3];
        } else {
          v0 = eidx[p]; v1 = eidx[p+1]; v2 = eidx[p+2]; v3 = eidx[p+3];
        }
        unsigned l0 = *(const unsigned*)&lutc[(size_t)((unsigned)v0 >> 18)*128];
        unsigned x0 = *(const unsigned*)&xc[(size_t)(v0 & 0x3FFFF)*128];
        unsigned l1 = *(const unsigned*)&lutc[(size_t)((unsigned)v1 >> 18)*128];
        unsigned x1 = *(const unsigned*)&xc[(size_t)(v1 & 0x3FFFF)*128];
        unsigned l2 = *(const unsigned*)&lutc[(size_t)((unsigned)v2 >> 18)*128];
        unsigned x2 = *(const unsigned*)&xc[(size_t)(v2 & 0x3FFFF)*128];
        unsigned l3 = *(const unsigned*)&lutc[(size_t)((unsigned)v3 >> 18)*128];
        unsigned x3 = *(const unsigned*)&xc[(size_t)(v3 & 0x3FFFF)*128];
        al0 += bflo(l0)*bflo(x0); ah0 += bfhi(l0)*bfhi(x0);
        al1 += bflo(l1)*bflo(x1); ah1 += bfhi(l1)*bfhi(x1);
        al2 += bflo(l2)*bflo(x2); ah2 += bfhi(l2)*bfhi(x2);
        al3 += bflo(l3)*bflo(x3); ah3 += bfhi(l3)*bfhi(x3);
      }
      for (; p < r1; p++){
        int v0 = fits ? snb[p-r00] : eidx[p];
        unsigned l0 = *(const unsigned*)&lutc[(size_t)((unsigned)v0 >> 18)*128];
        unsigned x0 = *(const unsigned*)&xc[(size_t)(v0 & 0x3FFFF)*128];
        al0 += bflo(l0)*bflo(x0); ah0 += bfhi(l0)*bfhi(x0);
      }
    } else {
      *(unsigned*)&ab[m][2*c2] = 0u;
    }
    float inv = 1.f / (float)(dg > 1 ? dg : 1);
    float alo = ((al0+al1)+(al2+al3)) * inv;
    float ahi = ((ah0+ah1)+(ah2+ah3)) * inv;
    *(unsigned*)&ab[m][128 + 2*c2] = (unsigned)f2bf(alo) | ((unsigned)f2bf(ahi) << 16);
  }
  __syncthreads();

  int wave = tid >> 6, lane = tid & 63, quad = lane >> 4, l15 = lane & 15;
  int mt = wave & 1, nh = wave >> 1;       // nh in [0,4)
  int arow = mt*16 + l15;
  float4v acc[2] = {{0,0,0,0},{0,0,0,0}};
  for (int k0 = 0; k0 < 256; k0 += 32){
    short8 A = *(const short8*)&ab[arow][k0 + quad*8];
    #pragma unroll
    for (int nt=0;nt<2;nt++){
      short8 B = *(const short8*)&wcat[(size_t)(nh*32 + nt*16 + l15)*256 + k0 + quad*8];
      acc[nt] = __builtin_amdgcn_mfma_f32_16x16x32_bf16(A, B, acc[nt], 0, 0, 0);
    }
  }
  #pragma unroll
  for (int nt=0;nt<2;nt++){
    int col = nh*32 + nt*16 + l15;
    float bc = bias[col];
    #pragma unroll
    for (int r=0;r<4;r++){
      int row = mt*16 + quad*4 + r;
      float v = acc[nt][r] + bc;
      ob[row][col] = f2bf((v > 0.f) ? v : 0.01f*v);    // leaky_relu
    }
  }
  __syncthreads();
  for (int m = grp*4; m < grp*4+4; m++){
    int n = n0 + m;
    if (n < ndst){
      unsigned vb = *(unsigned*)&ob[m][2*c2];
      size_t off = (size_t)n*128 + 2*c2;
      *(unsigned*)&xout[off] = vb;
      if (first){
        *(unsigned*)&xsum[off] = vb;
      } else {
        unsigned so = *(unsigned*)&xsum[off];
        float lo = bflo(so) + bflo(vb);
        float hi = bfhi(so) + bfhi(vb);
        *(unsigned*)&xsum[off] = (unsigned)f2bf(lo) | ((unsigned)f2bf(hi) << 16);
      }
    }
  }
}

// ---- hproj v3: persistent, register-resident B. 1024 blocks x 512 thr;
//      blocks [0,256): ligand (+b1), [256,1024): protein. ----
__global__ __launch_bounds__(512) void k_hproj3(
    const unsigned short* __restrict__ xl_s, const unsigned short* __restrict__ xp_s,
    const unsigned short* __restrict__ w1t, const float* __restrict__ b1,
    unsigned* __restrict__ h_l, unsigned* __restrict__ h_p){
  __shared__ unsigned short hb[32][528];
  int tid = threadIdx.x, lane = tid & 63, wave = tid >> 6;
  int quad = lane >> 4, l15 = lane & 15;
  bool isL = blockIdx.x < 256;
  const unsigned short* xs = isL ? xl_s : xp_s;
  const unsigned short* wt = isL ? w1t : w1t + 65536;
  unsigned* hout = isL ? h_l : h_p;
  int nn = isL ? NLn : NPn;
  int ntile = isL ? NBL : NBP;
  int wg = isL ? blockIdx.x : blockIdx.x - 256;
  int stride = isL ? 256 : 768;

  // register-resident B: wave's N-strip = cols [wave*64, wave*64+64)
  short8 Bk[4][4];
  float bv[4];
  #pragma unroll
  for (int nt=0;nt<4;nt++){
    int row = wave*64 + nt*16 + l15;
    #pragma unroll
    for (int kk=0;kk<4;kk++)
      Bk[nt][kk] = *(const short8*)&wt[(size_t)row*128 + kk*32 + quad*8];
    bv[nt] = isL ? b1[row] : 0.f;
  }

  for (int t = wg; t < ntile; t += stride){
    int n0 = t*32;
    int a0r = n0 + l15;      if (a0r >= nn) a0r = nn-1;
    int a1r = n0 + 16 + l15; if (a1r >= nn) a1r = nn-1;
    float4v acc[2][4];
    #pragma unroll
    for (int m2=0;m2<2;m2++)
      #pragma unroll
      for (int nt=0;nt<4;nt++) acc[m2][nt] = (float4v){0,0,0,0};
    #pragma unroll
    for (int kk=0;kk<4;kk++){
      short8 A0 = *(const short8*)&xs[(size_t)a0r*128 + kk*32 + quad*8];
      short8 A1 = *(const short8*)&xs[(size_t)a1r*128 + kk*32 + quad*8];
      #pragma unroll
      for (int nt=0;nt<4;nt++){
        acc[0][nt] = __builtin_amdgcn_mfma_f32_16x16x32_bf16(A0, Bk[nt][kk], acc[0][nt], 0, 0, 0);
        acc[1][nt] = __builtin_amdgcn_mfma_f32_16x16x32_bf16(A1, Bk[nt][kk], acc[1][nt], 0, 0, 0);
      }
    }
    #pragma unroll
    for (int m2=0;m2<2;m2++){
      #pragma unroll
      for (int nt=0;nt<4;nt++){
        int col = wave*64 + nt*16 + l15;
        #pragma unroll
        for (int r=0;r<4;r++)
          hb[m2*16 + quad*4 + r][col] = f2bf(acc[m2][nt][r] + bv[nt]);
      }
    }
    __syncthreads();
    for (int idx = tid; idx < 8192; idx += 512){
      int m = idx >> 8, d = idx & 255;
      int n = n0 + m;
      if (n < nn){
        unsigned pack = (unsigned)hb[m][2*d] | ((unsigned)hb[m][2*d+1] << 16);
        hout[(size_t)n*256 + d] = pack;
      }
    }
    __syncthreads();
  }
}

// ---- readout v11: persistent + reg-resident B + cross-tile pipeline +
//      register-accumulated epilogue (flush on batch change) + setprio. ----
__global__ __launch_bounds__(512) void k_readout4(
    const unsigned* __restrict__ hl, const unsigned* __restrict__ hp,
    const uint4* __restrict__ edgeL, const float* __restrict__ vvec,
    const unsigned short* __restrict__ w2t, const float* __restrict__ b2,
    const unsigned short* __restrict__ wmt, const float* __restrict__ bm,
    float* __restrict__ outw, unsigned* __restrict__ mmax){
  __shared__ __align__(16) unsigned short lds[37120];   // 2x16384 hbuf + msb
  unsigned short (*msb)[136] = (unsigned short(*)[136])(lds + 32768);
  int tid = threadIdx.x, lane = tid & 63, wave = tid >> 6;
  int quad = lane >> 4, l15 = lane & 15;
  int ns = wave*16;                // this wave's N-strip for both GEMMs

  // XCD-chunked tile mapping
  int wg = (blockIdx.x & 7)*128 + (blockIdx.x >> 3);   // bijective [0,1024)
  int nt_tot = En/32;
  int t0 = wg*16;
  int t1 = t0 + 16; if (t1 > nt_tot) t1 = nt_tot;
  if (t0 >= t1) return;

  // ---- register-resident B: w2t strip (64 VGPR) + wmt strip (16 VGPR) ----
  short8 Bk[16];
  #pragma unroll
  for (int kk=0;kk<16;kk++)
    Bk[kk] = *(const short8*)&w2t[(size_t)(ns + l15)*512 + kk*32 + quad*8];
  short8 Bm[4];
  #pragma unroll
  for (int kk=0;kk<4;kk++)
    Bm[kk] = *(const short8*)&wmt[(size_t)(ns + l15)*128 + kk*32 + quad*8];
  float b2c0 = b2[ns + l15];
  float bm0  = bm[ns + l15];
  int col = ns + l15;              // this thread's output column (fixed)

  // vvec for chunk `lane`: h columns [8*lane, 8*lane+8)
  float4v vva = *(const float4v*)&vvec[lane*8];
  float4v vvb = *(const float4v*)&vvec[lane*8 + 4];
  int sw = lane & 31;
  const uint4* hl4 = (const uint4*)hl;   // one h row = 64 uint4
  const uint4* hp4 = (const uint4*)hp;
  const unsigned* e32 = (const unsigned*)edgeL;

  int si_prev = -1;
  uint4 ua = {0,0,0,0};
  int lm = wave*16 + (lane & 15);        // metadata dword index for this wave
  int le = lane & 31;                    // epilogue edge index

  // register-accumulated epilogue state
  float sacc = 0.f, mxacc = -3.402823466e38f;
  int cur_b = -1;

  #define H_EDGE(UA, UB, DD, I, WB)                                          \
    {                                                                        \
      unsigned o0,o1,o2,o3; float hx,hy;                                     \
      hx = fmaxf(bflo(UA.x)+bflo(UB.x)+(DD)*vva.x, 0.f);                     \
      hy = fmaxf(bfhi(UA.x)+bfhi(UB.x)+(DD)*vva.y, 0.f);                     \
      o0 = (unsigned)f2bf(hx) | ((unsigned)f2bf(hy) << 16);                  \
      hx = fmaxf(bflo(UA.y)+bflo(UB.y)+(DD)*vva.z, 0.f);                     \
      hy = fmaxf(bfhi(UA.y)+bfhi(UB.y)+(DD)*vva.w, 0.f);                     \
      o1 = (unsigned)f2bf(hx) | ((unsigned)f2bf(hy) << 16);                  \
      hx = fmaxf(bflo(UA.z)+bflo(UB.z)+(DD)*vvb.x, 0.f);                     \
      hy = fmaxf(bfhi(UA.z)+bfhi(UB.z)+(DD)*vvb.y, 0.f);                     \
      o2 = (unsigned)f2bf(hx) | ((unsigned)f2bf(hy) << 16);                  \
      hx = fmaxf(bflo(UA.w)+bflo(UB.w)+(DD)*vvb.z, 0.f);                     \
      hy = fmaxf(bfhi(UA.w)+bfhi(UB.w)+(DD)*vvb.w, 0.f);                     \
      o3 = (unsigned)f2bf(hx) | ((unsigned)f2bf(hy) << 16);                  \
      uint4 ov; ov.x=o0; ov.y=o1; ov.z=o2; ov.w=o3;                          \
      *(uint4*)&lds[(WB) + lane*256 + (((I) ^ sw) << 3)] = ov;               \
    }

  // flush accumulated (s, mx) for batch cur_b
  #define FLUSH_ACC()                                                        \
    {                                                                        \
      float fs = sacc, fx = mxacc;                                           \
      fs += __shfl_xor(fs, 16); fs += __shfl_xor(fs, 32);                    \
      fx = fmaxf(fx, __shfl_xor(fx, 16)); fx = fmaxf(fx, __shfl_xor(fx, 32));\
      if (quad == 0){                                                        \
        atomicAdd(&outw[cur_b*256 + col], fs);                               \
        atomicMax(&mmax[cur_b*128 + col], encf(fx));                         \
      }                                                                      \
      sacc = 0.f; mxacc = -3.402823466e38f;                                  \
    }

  // ---- prologue: tile t0 -> hbuf0; load md1/br1 for t0+1 ----
  unsigned md1 = 0; int br_cur = 0, br1 = 0;
  {
    unsigned md0 = e32[(size_t)t0*128 + lm];
    br_cur = (int)e32[((size_t)(t0*32 + le))*4 + 3];
    #pragma unroll
    for (int ii=0; ii<4; ii++){
      int si = __builtin_amdgcn_readfirstlane(__shfl((int)md0, ii*4));
      int di = __builtin_amdgcn_readfirstlane(__shfl((int)md0, ii*4 + 1));
      float dd = __uint_as_float((unsigned)__builtin_amdgcn_readfirstlane(__shfl((int)md0, ii*4 + 2)));
      if (si != si_prev){ ua = hl4[(size_t)si*64 + lane]; si_prev = si; }
      uint4 ub = hp4[(size_t)di*64 + lane];
      H_EDGE(ua, ub, dd, wave*4 + ii, 0)
    }
    if (t0 + 1 < t1){
      md1 = e32[(size_t)(t0+1)*128 + lm];
      br1 = (int)e32[((size_t)((t0+1)*32 + le))*4 + 3];
    }
    __syncthreads();
  }

  int cur = 0;
  unsigned md2 = md1; int br2 = br1;
  for (int t = t0; t < t1; ++t){
    bool pf = (t + 1 < t1);
    // issue next-next metadata
    if (t + 2 < t1){
      md2 = e32[(size_t)(t+2)*128 + lm];
      br2 = (int)e32[((size_t)((t+2)*32 + le))*4 + 3];
    }
    // issue hp gathers + deduped hl for tile t+1 (consumed after GEMM2)
    uint4 ub0, ub1, ub2, ub3;
    if (pf){
      int d0 = __builtin_amdgcn_readfirstlane(__shfl((int)md1, 1));
      int d1 = __builtin_amdgcn_readfirstlane(__shfl((int)md1, 5));
      int d2 = __builtin_amdgcn_readfirstlane(__shfl((int)md1, 9));
      int d3 = __builtin_amdgcn_readfirstlane(__shfl((int)md1, 13));
      ub0 = hp4[(size_t)d0*64 + lane];
      ub1 = hp4[(size_t)d1*64 + lane];
      ub2 = hp4[(size_t)d2*64 + lane];
      ub3 = hp4[(size_t)d3*64 + lane];
      int s0 = __builtin_amdgcn_readfirstlane(__shfl((int)md1, 0));
      if (s0 != si_prev){ ua = hl4[(size_t)s0*64 + lane]; si_prev = s0; }
    }

    int rb = cur ? 16384 : 0;
    // GEMM1: m[32,128] = h[32,512] @ W2^T + b2  (B from registers)
    float4v acc[2] = {{0,0,0,0},{0,0,0,0}};
    __builtin_amdgcn_s_setprio(1);
    #pragma unroll
    for (int kk = 0; kk < 16; kk++){
      int kcc = kk*4 + quad;
      int sw2 = kcc & 31;
      short8 A0 = *(const short8*)&lds[rb + kcc*256 + ((l15 ^ sw2) << 3)];
      short8 A1 = *(const short8*)&lds[rb + kcc*256 + (((16 + l15) ^ sw2) << 3)];
      acc[0] = __builtin_amdgcn_mfma_f32_16x16x32_bf16(A0, Bk[kk], acc[0], 0, 0, 0);
      acc[1] = __builtin_amdgcn_mfma_f32_16x16x32_bf16(A1, Bk[kk], acc[1], 0, 0, 0);
    }
    __builtin_amdgcn_s_setprio(0);
    float mreg[2][4];
    #pragma unroll
    for (int mt=0;mt<2;mt++){
      #pragma unroll
      for (int r=0;r<4;r++){
        float mv = acc[mt][r] + b2c0;
        mreg[mt][r] = mv;
        msb[mt*16 + quad*4 + r][col] = f2bf(mv);
      }
    }
    __syncthreads();    // barrier A: msb visible

    // GEMM2: t = tanh(m@Wm^T + bm); accumulate sum(t*m), max(m) per batch
    float4v acc2[2] = {{0,0,0,0},{0,0,0,0}};
    __builtin_amdgcn_s_setprio(1);
    #pragma unroll
    for (int kk = 0; kk < 4; kk++){
      short8 A0 = *(const short8*)&msb[l15][kk*32 + quad*8];
      short8 A1 = *(const short8*)&msb[16 + l15][kk*32 + quad*8];
      acc2[0] = __builtin_amdgcn_mfma_f32_16x16x32_bf16(A0, Bm[kk], acc2[0], 0, 0, 0);
      acc2[1] = __builtin_amdgcn_mfma_f32_16x16x32_bf16(A1, Bm[kk], acc2[1], 0, 0, 0);
    }
    __builtin_amdgcn_s_setprio(0);
    {
      int b0 = __shfl(br_cur, 0);
      bool uni = (b0 == __shfl(br_cur, 31));
      if (uni){
        if (cur_b != b0){
          if (cur_b >= 0) FLUSH_ACC()
          cur_b = b0;
        }
        #pragma unroll
        for (int mt=0;mt<2;mt++){
          #pragma unroll
          for (int r=0;r<4;r++){
            float mv = mreg[mt][r];
            float tt = tanh_fast(acc2[mt][r] + bm0);
            sacc += tt*mv; mxacc = fmaxf(mxacc, mv);
          }
        }
      } else {
        if (cur_b >= 0){ FLUSH_ACC() cur_b = -1; }
        #pragma unroll
        for (int mt=0;mt<2;mt++){
          #pragma unroll
          for (int r=0;r<4;r++){
            int row = mt*16 + quad*4 + r;
            int b = __shfl(br_cur, row);
            float mv = mreg[mt][r];
            float tt = tanh_fast(acc2[mt][r] + bm0);
            atomicAdd(&outw[b*256 + col], tt*mv);
            atomicMax(&mmax[b*128 + col], encf(mv));
          }
        }
      }
    }

    // consume prefetched gathers -> h(t+1) into the other hbuf
    if (pf){
      int wb = cur ? 0 : 16384;
      #pragma unroll
      for (int ii=0; ii<4; ii++){
        int si = __builtin_amdgcn_readfirstlane(__shfl((int)md1, ii*4));
        float dd = __uint_as_float((unsigned)__builtin_amdgcn_readfirstlane(__shfl((int)md1, ii*4 + 2)));
        if (si != si_prev){ ua = hl4[(size_t)si*64 + lane]; si_prev = si; }
        uint4 ub = (ii==0) ? ub0 : (ii==1) ? ub1 : (ii==2) ? ub2 : ub3;
        H_EDGE(ua, ub, dd, wave*4 + ii, wb)
      }
    }
    __syncthreads();    // barrier B: hbuf[cur^1] + msb reads complete

    md1 = md2; br_cur = br1; br1 = br2;
    cur ^= 1;
  }
  // final flush of accumulated epilogue state
  if (cur_b >= 0) FLUSH_ACC()
  #undef FLUSH_ACC
  #undef H_EDGE
}

__global__ __launch_bounds__(256) void k_final(const unsigned* __restrict__ mmax,
    float* __restrict__ out){
  int gid = blockIdx.x*256 + threadIdx.x;   // 32768 = 256*128
  unsigned enc = mmax[gid];
  float v;
  if (enc == 0u) v = 0.f;
  else if (enc & 0x80000000u) v = __uint_as_float(enc & 0x7FFFFFFFu);
  else v = __uint_as_float(~enc);
  int g = gid >> 7, cc = gid & 127;
  out[g*256 + 128 + cc] = v;
}

extern "C" void kernel_launch(void* const* d_in, const int* in_sizes, int n_in,
                              void* d_out, int out_size, void* d_ws, size_t ws_size,
                              hipStream_t stream) {
  const float* x_l    = (const float*)d_in[0];
  const float* x_p    = (const float*)d_in[1];
  const float* ea     = (const float*)d_in[2];
  const int*   esrc   = (const int*)d_in[3];
  const int*   edst   = (const int*)d_in[4];
  const int*   lbatch = (const int*)d_in[5];
  const float* W_node = (const float*)d_in[6];
  const float* W_el   = (const float*)d_in[7];
  const float* Wb     = (const float*)d_in[8];
  const float* bb     = (const float*)d_in[9];
  const float* Wn     = (const float*)d_in[10];
  const float* Ws     = (const float*)d_in[11];
  const float* bconv  = (const float*)d_in[12];
  const float* W1     = (const float*)d_in[13];
  const float* b1     = (const float*)d_in[14];
  const float* W2     = (const float*)d_in[15];
  const float* b2     = (const float*)d_in[16];
  const float* Wm     = (const float*)d_in[17];
  const float* bm     = (const float*)d_in[18];

  // ---- workspace layout (decimal offsets), peak 267,354,496 B ----
  char* w = (char*)d_ws;
  unsigned short* xl0 = (unsigned short*)(w + 0);
  unsigned short* xl1 = (unsigned short*)(w + 12800000);
  unsigned short* xp0 = (unsigned short*)(w + 25600000);
  unsigned short* xp1 = (unsigned short*)(w + 64000000);
  int*      idxP  = (int*)(w + 102400000);
  int*      idxL  = (int*)(w + 104400000);
  unsigned short* lut = (unsigned short*)(w + 106400000);   // 6.29e6 B
  unsigned* h_l   = (unsigned*)(w + 0);
  unsigned* h_p   = (unsigned*)(w + 51200000);
  unsigned short* xl_s = (unsigned short*)(w + 204800000);
  unsigned short* xp_s = (unsigned short*)(w + 217600000);
  unsigned short* wcat = (unsigned short*)(w + 256000000);
  unsigned short* w1t  = (unsigned short*)(w + 256393216);
  unsigned short* w2t  = (unsigned short*)(w + 256655360);
  unsigned short* wmt  = (unsigned short*)(w + 256786432);
  float*    vvec  = (float*)(w + 256819200);
  unsigned* mmax  = (unsigned*)(w + 256821248);
  unsigned* bsumL = (unsigned*)(w + 256952320);
  unsigned* bsumP = (unsigned*)(w + 256953344);
  unsigned* rowptrL = (unsigned*)(w + 256954368);
  unsigned* cursorL = (unsigned*)(w + 257154432);
  unsigned* rowptrP = (unsigned*)(w + 257354432);
  unsigned* cursorP = (unsigned*)(w + 257954496);
  unsigned* cntL    = (unsigned*)(w + 258554496);
  unsigned* cntP    = (unsigned*)(w + 258754496);
  uint4*    edgeL   = (uint4*)(w + 259354496);   // {src, dst, bits(d), batch}

  float* out = (float*)d_out;

  k_prep<<<14470, 256, 0, stream>>>(
      (unsigned*)(w + 258554496), mmax, (unsigned*)d_out,
      W_el, W1, vvec, W2, w2t, Wm, wmt, Ws, Wn, wcat, w1t, Wb, bb, lut);
  k_embed<<<NBL + NBP, 256, 0, stream>>>(x_l, x_p, W_node, xl0, xp0);

  k_count<<<1954, 256, 0, stream>>>(esrc, edst, cntL, cntP);
  k_cs2<<<196, 256, 0, stream>>>(cntL, rowptrL, bsumL, cntP, rowptrP, bsumP);
  k_sb2<<<2, 256, 0, stream>>>(bsumL, bsumP);
  k_ao2<<<782, 256, 0, stream>>>(rowptrL, cursorL, bsumL, rowptrP, cursorP, bsumP);
  k_place<<<1954, 256, 0, stream>>>(esrc, edst, ea, lbatch, cursorL, cursorP,
                                    edgeL, idxL, idxP);

  unsigned short *xlc = xl0, *xln = xl1, *xpc = xp0, *xpn = xp1;
  for (int l = 0; l < 3; ++l){
    int ilp = 2*l, ipl = 2*l + 1;
    k_conv2<<<NBP + NBL, 512, 0, stream>>>(
        xpc, xlc, xpn, xln, xp_s, xl_s,
        rowptrP, idxP, rowptrL, idxL,
        lut + (size_t)ilp*524288, wcat + ilp*32768, bconv + ilp*128,
        lut + (size_t)ipl*524288, wcat + ipl*32768, bconv + ipl*128,
        (l == 0) ? 1 : 0);
    unsigned short* t;
    t = xlc; xlc = xln; xln = t;
    t = xpc; xpc = xpn; xpn = t;
  }

  // b1 folded into h_l (ligand part); protein part no bias
  k_hproj3<<<1024, 512, 0, stream>>>(xl_s, xp_s, w1t, b1, h_l, h_p);

  k_readout4<<<1024, 512, 0, stream>>>(h_l, h_p, edgeL, vvec,
                                       w2t, b2, wmt, bm, out, mmax);
  k_final<<<128, 256, 0, stream>>>(mmax, out);
}